// Round 1
// baseline (1291.740 us; speedup 1.0000x reference)
//
#include <hip/hip_runtime.h>

// MHA: out = softmax((qWq^T)(kWk^T)^T/sqrt(128)) (vWv^T) Wo^T + bo
// B=4 T=2048 E=2048 H=16 D=128. All GEMMs via bf16 MFMA (fp32 accum).

typedef __attribute__((ext_vector_type(4))) float f32x4;
typedef __attribute__((ext_vector_type(2))) float f32x2;
typedef __attribute__((ext_vector_type(8))) __bf16 bf16x8;
typedef __attribute__((ext_vector_type(4))) unsigned int u32x4;
typedef __attribute__((ext_vector_type(8))) unsigned short u16x8;
typedef __attribute__((ext_vector_type(4))) unsigned short u16x4;

#define DEVI static __device__ __forceinline__

DEVI unsigned short f2bf(float f) {            // RNE fp32 -> bf16
  union { float f; unsigned u; } x; x.f = f;
  unsigned u = x.u;
  return (unsigned short)((u + 0x7fffu + ((u >> 16) & 1u)) >> 16);
}
DEVI unsigned int pack2(float lo, float hi) {
  return (unsigned int)f2bf(lo) | ((unsigned int)f2bf(hi) << 16);
}
DEVI u32x4 pack8(const f32x4 a, const f32x4 b) {
  u32x4 r;
  r[0] = pack2(a[0], a[1]); r[1] = pack2(a[2], a[3]);
  r[2] = pack2(b[0], b[1]); r[3] = pack2(b[2], b[3]);
  return r;
}

// ---------------------------------------------------------------------------
// Kernel 1: fused QKV projection. z in {0,1,2} selects (q,Wq,Q)/(k,Wk,K)/(v,Wv,V).
// C[i,j] = sum_e A[i,e]*W[j,e]; C stored bf16 in [B,H,T,D] layout.
// 128x128 tile, BK=32, 4 waves (2x2), each wave 4x4 frags of 16x16x32.
// ---------------------------------------------------------------------------
__global__ __launch_bounds__(256) void qkv_gemm(
    const float* __restrict__ A0, const float* __restrict__ A1, const float* __restrict__ A2,
    const float* __restrict__ W0, const float* __restrict__ W1, const float* __restrict__ W2,
    unsigned short* __restrict__ O0, unsigned short* __restrict__ O1, unsigned short* __restrict__ O2)
{
  __shared__ unsigned short As[128 * 32];
  __shared__ unsigned short Bs[128 * 32];
  const int z = blockIdx.z;
  const float* A = z == 0 ? A0 : (z == 1 ? A1 : A2);
  const float* W = z == 0 ? W0 : (z == 1 ? W1 : W2);
  unsigned short* O = z == 0 ? O0 : (z == 1 ? O1 : O2);

  const int tid = threadIdx.x;
  const int lane = tid & 63;
  const int wave = tid >> 6;
  const int wm = wave >> 1, wn = wave & 1;
  const int bm = blockIdx.x >> 4, bn = blockIdx.x & 15;

  // staging: thread -> (row, half-row of 16 fp32)
  const int srow = tid >> 1;
  const int shalf = tid & 1;
  const float* Ap = A + (size_t)(bm * 128 + srow) * 2048 + shalf * 16;
  const float* Wp = W + (size_t)(bn * 128 + srow) * 2048 + shalf * 16;
  const int ssw = (srow >> 1) & 3;                       // chunk swizzle
  const int aoff0 = srow * 32 + (((shalf * 2 + 0) ^ ssw) << 3);
  const int aoff1 = srow * 32 + (((shalf * 2 + 1) ^ ssw) << 3);

  const int frow = lane & 15;
  const int fk = lane >> 4;

  f32x4 acc[4][4];
#pragma unroll
  for (int m = 0; m < 4; m++)
#pragma unroll
    for (int n = 0; n < 4; n++) acc[m][n] = (f32x4)(0.0f);

  for (int kk = 0; kk < 2048; kk += 32) {
    f32x4 a0 = *(const f32x4*)(Ap + kk);
    f32x4 a1 = *(const f32x4*)(Ap + kk + 4);
    f32x4 a2 = *(const f32x4*)(Ap + kk + 8);
    f32x4 a3 = *(const f32x4*)(Ap + kk + 12);
    f32x4 b0 = *(const f32x4*)(Wp + kk);
    f32x4 b1 = *(const f32x4*)(Wp + kk + 4);
    f32x4 b2 = *(const f32x4*)(Wp + kk + 8);
    f32x4 b3 = *(const f32x4*)(Wp + kk + 12);
    __syncthreads();                     // prior iteration's LDS reads done
    *(u32x4*)(As + aoff0) = pack8(a0, a1);
    *(u32x4*)(As + aoff1) = pack8(a2, a3);
    *(u32x4*)(Bs + aoff0) = pack8(b0, b1);
    *(u32x4*)(Bs + aoff1) = pack8(b2, b3);
    __syncthreads();
    bf16x8 af[4], bfr[4];
#pragma unroll
    for (int m = 0; m < 4; m++) {
      int r = wm * 64 + m * 16 + frow;
      af[m] = *(const bf16x8*)(As + r * 32 + ((fk ^ ((r >> 1) & 3)) << 3));
    }
#pragma unroll
    for (int n = 0; n < 4; n++) {
      int r = wn * 64 + n * 16 + frow;
      bfr[n] = *(const bf16x8*)(Bs + r * 32 + ((fk ^ ((r >> 1) & 3)) << 3));
    }
#pragma unroll
    for (int m = 0; m < 4; m++)
#pragma unroll
      for (int n = 0; n < 4; n++)
        acc[m][n] = __builtin_amdgcn_mfma_f32_16x16x32_bf16(af[m], bfr[n], acc[m][n], 0, 0, 0);
  }

  // epilogue: C/D layout col=lane&15, row=(lane>>4)*4+j. Pair cols via shfl -> u32 stores.
  const bool evenlane = (lane & 1) == 0;
#pragma unroll
  for (int m = 0; m < 4; m++) {
    int rowg = bm * 128 + wm * 64 + m * 16 + (lane >> 4) * 4;
#pragma unroll
    for (int n = 0; n < 4; n += 2) {
#pragma unroll
      for (int j = 0; j < 4; j++) {
        float v0 = acc[m][n][j], v1 = acc[m][n + 1][j];
        float p0 = __shfl_xor(v0, 1);
        float p1 = __shfl_xor(v1, 1);
        int row = rowg + j;
        int b = row >> 11, t = row & 2047;
        int colbase = bn * 128 + wn * 64;
        int col = evenlane ? (colbase + n * 16 + (lane & 15))
                           : (colbase + (n + 1) * 16 + (lane & 15) - 1);
        unsigned int wv = evenlane ? pack2(v0, p0) : pack2(p1, v1);
        int h = col >> 7, d = col & 127;
        *(unsigned int*)(O + (((size_t)(b * 16 + h) * 2048 + t) << 7) + d) = wv;
      }
    }
  }
}

// ---------------------------------------------------------------------------
// Kernel 2: flash attention. 64 (b,h) pairs x 32 Q-tiles of 64 rows.
// 4 waves, wave w owns q-rows w*16..w*16+15. KV tiles of 64 keys.
// ---------------------------------------------------------------------------
__global__ __launch_bounds__(256) void attn(
    const unsigned short* __restrict__ Qw, const unsigned short* __restrict__ Kw,
    const unsigned short* __restrict__ Vw, unsigned short* __restrict__ attout)
{
  __shared__ unsigned short Qs[64 * 128];   // [q][d] swizzled, 16KB
  __shared__ unsigned short Ks[64 * 128];   // [key][d] swizzled, 16KB
  __shared__ unsigned short Vs[128 * 64];   // V^T [d][key] swizzled, 16KB
  __shared__ unsigned short Ps[64 * 64];    // P [q][key] swizzled, 8KB

  const int bh = blockIdx.x >> 5;
  const int qtile = blockIdx.x & 31;
  const int b = bh >> 4, h = bh & 15;
  const unsigned short* Qbase = Qw + (size_t)bh * 2048 * 128 + qtile * 64 * 128;
  const unsigned short* Kbase = Kw + (size_t)bh * 2048 * 128;
  const unsigned short* Vbase = Vw + (size_t)bh * 2048 * 128;
  const int tid = threadIdx.x, lane = tid & 63, wave = tid >> 6;

  // stage Q once (row stride 256B = 16 chunks; swizzle ch ^ (row&15))
#pragma unroll
  for (int p = 0; p < 4; p++) {
    int row = p * 16 + (tid >> 4);
    int ch = tid & 15;
    *(u32x4*)(Qs + row * 128 + ((ch ^ (row & 15)) << 3)) =
        *(const u32x4*)(Qbase + row * 128 + ch * 8);
  }

  f32x4 o[8];
#pragma unroll
  for (int n = 0; n < 8; n++) o[n] = (f32x4)(0.0f);
  float m_r[4] = {-INFINITY, -INFINITY, -INFINITY, -INFINITY};
  float l_r[4] = {0.f, 0.f, 0.f, 0.f};
  const float SC = 0.12751721769f;  // log2(e)/sqrt(128)

  const int frow = lane & 15;
  const int fk = lane >> 4;

  for (int kt = 0; kt < 32; kt++) {
    const unsigned short* Kt = Kbase + kt * 64 * 128;
    const unsigned short* Vt = Vbase + kt * 64 * 128;
    __syncthreads();          // prior tile's LDS reads done
    // stage K
#pragma unroll
    for (int p = 0; p < 4; p++) {
      int row = p * 16 + (tid >> 4);
      int ch = tid & 15;
      *(u32x4*)(Ks + row * 128 + ((ch ^ (row & 15)) << 3)) =
          *(const u32x4*)(Kt + row * 128 + ch * 8);
    }
    // stage V transposed: thread -> 4 keys x 8 d
    {
      int k4 = (tid >> 4) * 4;
      int d8 = (tid & 15) * 8;
      u16x8 vr0 = *(const u16x8*)(Vt + (k4 + 0) * 128 + d8);
      u16x8 vr1 = *(const u16x8*)(Vt + (k4 + 1) * 128 + d8);
      u16x8 vr2 = *(const u16x8*)(Vt + (k4 + 2) * 128 + d8);
      u16x8 vr3 = *(const u16x8*)(Vt + (k4 + 3) * 128 + d8);
#pragma unroll
      for (int dd = 0; dd < 8; dd++) {
        u16x4 pk; pk[0] = vr0[dd]; pk[1] = vr1[dd]; pk[2] = vr2[dd]; pk[3] = vr3[dd];
        int row = d8 + dd;
        int byteoff = k4 * 2;                 // 0..120, multiple of 8
        int ch = byteoff >> 4, lo = byteoff & 15;
        *(u16x4*)((char*)Vs + row * 128 + ((ch ^ (row & 7)) << 4) + lo) = pk;
      }
    }
    __syncthreads();

    // S = Q K^T for this wave's 16 rows x 64 keys
    f32x4 s[4];
#pragma unroll
    for (int n = 0; n < 4; n++) s[n] = (f32x4)(0.0f);
#pragma unroll
    for (int ks = 0; ks < 4; ks++) {
      int arow = wave * 16 + frow;
      bf16x8 aq = *(const bf16x8*)(Qs + arow * 128 + (((ks * 4 + fk) ^ (arow & 15)) << 3));
#pragma unroll
      for (int n = 0; n < 4; n++) {
        int brow = n * 16 + frow;
        bf16x8 bk = *(const bf16x8*)(Ks + brow * 128 + (((ks * 4 + fk) ^ (brow & 15)) << 3));
        s[n] = __builtin_amdgcn_mfma_f32_16x16x32_bf16(aq, bk, s[n], 0, 0, 0);
      }
    }

    // online softmax (rows (lane>>4)*4+j; 64 cols across 16 lanes x 4 frags)
#pragma unroll
    for (int j = 0; j < 4; j++) {
      float mx = fmaxf(fmaxf(s[0][j], s[1][j]), fmaxf(s[2][j], s[3][j]));
      mx = fmaxf(mx, __shfl_xor(mx, 1));
      mx = fmaxf(mx, __shfl_xor(mx, 2));
      mx = fmaxf(mx, __shfl_xor(mx, 4));
      mx = fmaxf(mx, __shfl_xor(mx, 8));
      float mnew = fmaxf(m_r[j], mx);
      float f = __builtin_amdgcn_exp2f((m_r[j] - mnew) * SC);
      m_r[j] = mnew;
      float psum = 0.f;
#pragma unroll
      for (int n = 0; n < 4; n++) {
        float p = __builtin_amdgcn_exp2f((s[n][j] - mnew) * SC);
        s[n][j] = p;
        psum += p;
      }
      psum += __shfl_xor(psum, 1);
      psum += __shfl_xor(psum, 2);
      psum += __shfl_xor(psum, 4);
      psum += __shfl_xor(psum, 8);
      l_r[j] = l_r[j] * f + psum;
#pragma unroll
      for (int n = 0; n < 8; n++) o[n][j] *= f;
    }

    // write P (bf16) to own rows; same wave reads back -> no barrier needed
#pragma unroll
    for (int j = 0; j < 4; j++) {
      int row = wave * 16 + (lane >> 4) * 4 + j;
      int swz = row & 7;
#pragma unroll
      for (int n = 0; n < 4; n++) {
        int col = (lane & 15) + 16 * n;
        int byteoff = (((col >> 3) ^ swz) << 4) + (col & 7) * 2;
        *(unsigned short*)((char*)Ps + row * 128 + byteoff) = f2bf(s[n][j]);
      }
    }

    // O += P V
#pragma unroll
    for (int ks = 0; ks < 2; ks++) {
      int arow = wave * 16 + frow;
      bf16x8 ap = *(const bf16x8*)((char*)Ps + arow * 128 + (((ks * 4 + fk) ^ (arow & 7)) << 4));
#pragma unroll
      for (int n = 0; n < 8; n++) {
        int vrow = (lane & 15) + 16 * n;
        bf16x8 bv = *(const bf16x8*)((char*)Vs + vrow * 128 + (((ks * 4 + fk) ^ (vrow & 7)) << 4));
        o[n] = __builtin_amdgcn_mfma_f32_16x16x32_bf16(ap, bv, o[n], 0, 0, 0);
      }
    }
  }

  // epilogue
  float inv[4];
#pragma unroll
  for (int j = 0; j < 4; j++) inv[j] = 1.0f / l_r[j];
  const bool evenlane = (lane & 1) == 0;
#pragma unroll
  for (int n = 0; n < 8; n += 2) {
#pragma unroll
    for (int j = 0; j < 4; j++) {
      float v0 = o[n][j] * inv[j], v1 = o[n + 1][j] * inv[j];
      float p0 = __shfl_xor(v0, 1);
      float p1 = __shfl_xor(v1, 1);
      int tq = qtile * 64 + wave * 16 + (lane >> 4) * 4 + j;
      int col = evenlane ? (n * 16 + (lane & 15)) : ((n + 1) * 16 + (lane & 15) - 1);
      unsigned int wv = evenlane ? pack2(v0, p0) : pack2(p1, v1);
      *(unsigned int*)(attout + (size_t)(b * 2048 + tq) * 2048 + h * 128 + col) = wv;
    }
  }
}

// ---------------------------------------------------------------------------
// Kernel 3: output projection. out[i,j] = sum_e attout[i,e]*Wo[j,e] + bo[j] (fp32 out)
// ---------------------------------------------------------------------------
__global__ __launch_bounds__(256) void out_gemm(
    const unsigned short* __restrict__ Ab, const float* __restrict__ W,
    const float* __restrict__ bias, float* __restrict__ Out)
{
  __shared__ unsigned short As[128 * 32];
  __shared__ unsigned short Bs[128 * 32];

  const int tid = threadIdx.x;
  const int lane = tid & 63;
  const int wave = tid >> 6;
  const int wm = wave >> 1, wn = wave & 1;
  const int bm = blockIdx.x >> 4, bn = blockIdx.x & 15;

  const int srow = tid >> 1;
  const int shalf = tid & 1;
  const unsigned short* Ap = Ab + (size_t)(bm * 128 + srow) * 2048 + shalf * 16;
  const float* Wp = W + (size_t)(bn * 128 + srow) * 2048 + shalf * 16;
  const int ssw = (srow >> 1) & 3;
  const int aoff0 = srow * 32 + (((shalf * 2 + 0) ^ ssw) << 3);
  const int aoff1 = srow * 32 + (((shalf * 2 + 1) ^ ssw) << 3);

  const int frow = lane & 15;
  const int fk = lane >> 4;

  f32x4 acc[4][4];
#pragma unroll
  for (int m = 0; m < 4; m++)
#pragma unroll
    for (int n = 0; n < 4; n++) acc[m][n] = (f32x4)(0.0f);

  for (int kk = 0; kk < 2048; kk += 32) {
    u32x4 a0 = *(const u32x4*)(Ap + kk);
    u32x4 a1 = *(const u32x4*)(Ap + kk + 8);
    f32x4 b0 = *(const f32x4*)(Wp + kk);
    f32x4 b1 = *(const f32x4*)(Wp + kk + 4);
    f32x4 b2 = *(const f32x4*)(Wp + kk + 8);
    f32x4 b3 = *(const f32x4*)(Wp + kk + 12);
    __syncthreads();
    *(u32x4*)(As + aoff0) = a0;
    *(u32x4*)(As + aoff1) = a1;
    *(u32x4*)(Bs + aoff0) = pack8(b0, b1);
    *(u32x4*)(Bs + aoff1) = pack8(b2, b3);
    __syncthreads();
    bf16x8 af[4], bfr[4];
#pragma unroll
    for (int m = 0; m < 4; m++) {
      int r = wm * 64 + m * 16 + frow;
      af[m] = *(const bf16x8*)(As + r * 32 + ((fk ^ ((r >> 1) & 3)) << 3));
    }
#pragma unroll
    for (int n = 0; n < 4; n++) {
      int r = wn * 64 + n * 16 + frow;
      bfr[n] = *(const bf16x8*)(Bs + r * 32 + ((fk ^ ((r >> 1) & 3)) << 3));
    }
#pragma unroll
    for (int m = 0; m < 4; m++)
#pragma unroll
      for (int n = 0; n < 4; n++)
        acc[m][n] = __builtin_amdgcn_mfma_f32_16x16x32_bf16(af[m], bfr[n], acc[m][n], 0, 0, 0);
  }

  float bv[4];
#pragma unroll
  for (int n = 0; n < 4; n++) bv[n] = bias[bn * 128 + wn * 64 + n * 16 + (lane & 15)];
  const bool evenlane = (lane & 1) == 0;
#pragma unroll
  for (int m = 0; m < 4; m++) {
    int rowg = bm * 128 + wm * 64 + m * 16 + (lane >> 4) * 4;
#pragma unroll
    for (int n = 0; n < 4; n += 2) {
#pragma unroll
      for (int j = 0; j < 4; j++) {
        float v0 = acc[m][n][j] + bv[n];
        float v1 = acc[m][n + 1][j] + bv[n + 1];
        float p0 = __shfl_xor(v0, 1);
        float p1 = __shfl_xor(v1, 1);
        int row = rowg + j;
        int colbase = bn * 128 + wn * 64;
        int col = evenlane ? (colbase + n * 16 + (lane & 15))
                           : (colbase + (n + 1) * 16 + (lane & 15) - 1);
        f32x2 wv;
        if (evenlane) { wv[0] = v0; wv[1] = p0; }
        else          { wv[0] = p1; wv[1] = v1; }
        *(f32x2*)(Out + (size_t)row * 2048 + col) = wv;
      }
    }
  }
}

// ---------------------------------------------------------------------------
extern "C" void kernel_launch(void* const* d_in, const int* in_sizes, int n_in,
                              void* d_out, int out_size, void* d_ws, size_t ws_size,
                              hipStream_t stream)
{
  // setup_inputs order: k, q, v, Wk, Wq, Wv, Wo, bo
  const float* k  = (const float*)d_in[0];
  const float* q  = (const float*)d_in[1];
  const float* v  = (const float*)d_in[2];
  const float* Wk = (const float*)d_in[3];
  const float* Wq = (const float*)d_in[4];
  const float* Wv = (const float*)d_in[5];
  const float* Wo = (const float*)d_in[6];
  const float* bo = (const float*)d_in[7];
  float* out = (float*)d_out;

  // workspace: Q,K,V bf16 [B,H,T,D] (32MiB each) + attout bf16 [B,T,E] (32MiB) = 128MiB
  const size_t HSZ = (size_t)4 * 16 * 2048 * 128;
  unsigned short* Qw = (unsigned short*)d_ws;
  unsigned short* Kw = Qw + HSZ;
  unsigned short* Vw = Kw + HSZ;
  unsigned short* Aw = Vw + HSZ;

  qkv_gemm<<<dim3(1024, 1, 3), 256, 0, stream>>>(q, k, v, Wq, Wk, Wv, Qw, Kw, Vw);
  attn<<<dim3(2048), 256, 0, stream>>>(Qw, Kw, Vw, Aw);
  out_gemm<<<dim3(1024), 256, 0, stream>>>(Aw, Wo, bo, out);
}

// Round 2
// 974.005 us; speedup vs baseline: 1.3262x; 1.3262x over previous
//
#include <hip/hip_runtime.h>

// MHA: out = softmax((qWq^T)(kWk^T)^T/sqrt(128)) (vWv^T) Wo^T + bo
// B=4 T=2048 E=2048 H=16 D=128. All GEMMs via bf16 MFMA (fp32 accum).
//
// Fast path (ws >= 224 MiB): pre-convert fp32->bf16 once, m97-style GEMM with
// global_load_lds (linear LDS dest, inverse-swizzled global src, swizzled
// ds_read_b128). Fallback (ws < 224 MiB): round-1 in-kernel-pack GEMMs.

typedef __attribute__((ext_vector_type(4))) float f32x4;
typedef __attribute__((ext_vector_type(2))) float f32x2;
typedef __attribute__((ext_vector_type(8))) __bf16 bf16x8;
typedef __attribute__((ext_vector_type(4))) unsigned int u32x4;
typedef __attribute__((ext_vector_type(8))) unsigned short u16x8;
typedef __attribute__((ext_vector_type(4))) unsigned short u16x4;

#define DEVI static __device__ __forceinline__

DEVI unsigned short f2bf(float f) {            // RNE fp32 -> bf16
  union { float f; unsigned u; } x; x.f = f;
  unsigned u = x.u;
  return (unsigned short)((u + 0x7fffu + ((u >> 16) & 1u)) >> 16);
}
DEVI unsigned int pack2(float lo, float hi) {
  return (unsigned int)f2bf(lo) | ((unsigned int)f2bf(hi) << 16);
}
DEVI u32x4 pack8(const f32x4 a, const f32x4 b) {
  u32x4 r;
  r[0] = pack2(a[0], a[1]); r[1] = pack2(a[2], a[3]);
  r[2] = pack2(b[0], b[1]); r[3] = pack2(b[2], b[3]);
  return r;
}
DEVI void gload16(const unsigned short* g, unsigned short* l) {
  __builtin_amdgcn_global_load_lds(
      (const __attribute__((address_space(1))) unsigned int*)g,
      (__attribute__((address_space(3))) unsigned int*)l, 16, 0, 0);
}

// ---------------------------------------------------------------------------
// fp32 -> bf16 convert passes (vectorized 8 elems/thread)
// ---------------------------------------------------------------------------
__global__ __launch_bounds__(256) void convA(
    const float* __restrict__ q, const float* __restrict__ k,
    const float* __restrict__ v, unsigned short* __restrict__ dst)
{
  const int z = blockIdx.z;
  const float* src = z == 0 ? q : (z == 1 ? k : v);
  unsigned short* d = dst + (size_t)z * 16777216;
  size_t i = ((size_t)blockIdx.x * 256 + threadIdx.x) * 8;
  f32x4 a = *(const f32x4*)(src + i);
  f32x4 b = *(const f32x4*)(src + i + 4);
  *(u32x4*)(d + i) = pack8(a, b);
}

__global__ __launch_bounds__(256) void convW(
    const float* __restrict__ w0, const float* __restrict__ w1,
    const float* __restrict__ w2, const float* __restrict__ w3,
    unsigned short* __restrict__ dst)
{
  const int z = blockIdx.z;
  const float* src = z == 0 ? w0 : (z == 1 ? w1 : (z == 2 ? w2 : w3));
  unsigned short* d = dst + (size_t)z * 4194304;
  size_t i = ((size_t)blockIdx.x * 256 + threadIdx.x) * 8;
  f32x4 a = *(const f32x4*)(src + i);
  f32x4 b = *(const f32x4*)(src + i + 4);
  *(u32x4*)(d + i) = pack8(a, b);
}

// ---------------------------------------------------------------------------
// Shared bf16 GEMM mainloop (m97 structure): 128x128 tile, BK=32, 4 waves 2x2,
// global_load_lds width 16 with inverse-swizzled global source; swizzled
// ds_read_b128 (chunk ^= (row>>1)&3) -> conflict-free.
// C[i,j] = sum_e A[i,e]*B[j,e]  (both row-major [*, 2048] bf16)
// ---------------------------------------------------------------------------
DEVI void gemm128_bf16(const unsigned short* __restrict__ A,
                       const unsigned short* __restrict__ Bm,
                       unsigned short* As, unsigned short* Bs,
                       int bm, int bn, int tid, f32x4 (&acc)[4][4])
{
  const int lane = tid & 63, wave = tid >> 6;
  // staging: issue i covers LDS rows (wave*2+i)*16 .. +15; lane -> row lane>>2, chunk lane&3
  const int c = lane & 3;
  const int r0 = (wave * 2 + 0) * 16 + (lane >> 2);
  const int r1 = (wave * 2 + 1) * 16 + (lane >> 2);
  const unsigned short* Ap0 = A + (size_t)(bm * 128 + r0) * 2048 + ((c ^ ((r0 >> 1) & 3)) << 3);
  const unsigned short* Ap1 = A + (size_t)(bm * 128 + r1) * 2048 + ((c ^ ((r1 >> 1) & 3)) << 3);
  const unsigned short* Bp0 = Bm + (size_t)(bn * 128 + r0) * 2048 + ((c ^ ((r0 >> 1) & 3)) << 3);
  const unsigned short* Bp1 = Bm + (size_t)(bn * 128 + r1) * 2048 + ((c ^ ((r1 >> 1) & 3)) << 3);
  unsigned short* Asl0 = As + (wave * 2 + 0) * 512;  // wave-uniform LDS bases
  unsigned short* Asl1 = As + (wave * 2 + 1) * 512;
  unsigned short* Bsl0 = Bs + (wave * 2 + 0) * 512;
  unsigned short* Bsl1 = Bs + (wave * 2 + 1) * 512;

  const int wm = wave >> 1, wn = wave & 1;
  const int frow = lane & 15, fk = lane >> 4;
  int aoff[4], boff[4];
#pragma unroll
  for (int m = 0; m < 4; m++) {
    int ra = wm * 64 + m * 16 + frow;
    aoff[m] = ra * 32 + ((fk ^ ((ra >> 1) & 3)) << 3);
    int rb = wn * 64 + m * 16 + frow;
    boff[m] = rb * 32 + ((fk ^ ((rb >> 1) & 3)) << 3);
  }

  for (int kk = 0; kk < 2048; kk += 32) {
    __syncthreads();                 // prior iteration's LDS reads done
    gload16(Ap0 + kk, Asl0);
    gload16(Ap1 + kk, Asl1);
    gload16(Bp0 + kk, Bsl0);
    gload16(Bp1 + kk, Bsl1);
    __syncthreads();                 // barrier drains vmcnt -> tile resident
    bf16x8 af[4], bfv[4];
#pragma unroll
    for (int m = 0; m < 4; m++) af[m] = *(const bf16x8*)(As + aoff[m]);
#pragma unroll
    for (int n = 0; n < 4; n++) bfv[n] = *(const bf16x8*)(Bs + boff[n]);
#pragma unroll
    for (int m = 0; m < 4; m++)
#pragma unroll
      for (int n = 0; n < 4; n++)
        acc[m][n] = __builtin_amdgcn_mfma_f32_16x16x32_bf16(af[m], bfv[n], acc[m][n], 0, 0, 0);
  }
}

// ---------------------------------------------------------------------------
// Fast-path kernel 1: QKV projection from pre-converted bf16. Output [B,H,T,D] bf16.
// ---------------------------------------------------------------------------
__global__ __launch_bounds__(256) void qkv_gemm_bf(
    const unsigned short* __restrict__ Abf, const unsigned short* __restrict__ Wbf,
    unsigned short* __restrict__ O0, unsigned short* __restrict__ O1,
    unsigned short* __restrict__ O2)
{
  __shared__ unsigned short As[128 * 32];
  __shared__ unsigned short Bs[128 * 32];
  const int z = blockIdx.z;
  const unsigned short* A = Abf + (size_t)z * 16777216;
  const unsigned short* W = Wbf + (size_t)z * 4194304;
  unsigned short* O = z == 0 ? O0 : (z == 1 ? O1 : O2);

  const int tid = threadIdx.x;
  const int lane = tid & 63, wave = tid >> 6;
  const int wm = wave >> 1, wn = wave & 1;
  const int bm = blockIdx.x >> 4, bn = blockIdx.x & 15;

  f32x4 acc[4][4];
#pragma unroll
  for (int m = 0; m < 4; m++)
#pragma unroll
    for (int n = 0; n < 4; n++) acc[m][n] = (f32x4)(0.0f);

  gemm128_bf16(A, W, As, Bs, bm, bn, tid, acc);

  // epilogue: C/D layout col=lane&15, row=(lane>>4)*4+j. Pair cols via shfl -> u32 stores.
  const bool evenlane = (lane & 1) == 0;
#pragma unroll
  for (int m = 0; m < 4; m++) {
    int rowg = bm * 128 + wm * 64 + m * 16 + (lane >> 4) * 4;
#pragma unroll
    for (int n = 0; n < 4; n += 2) {
#pragma unroll
      for (int j = 0; j < 4; j++) {
        float v0 = acc[m][n][j], v1 = acc[m][n + 1][j];
        float p0 = __shfl_xor(v0, 1);
        float p1 = __shfl_xor(v1, 1);
        int row = rowg + j;
        int b = row >> 11, t = row & 2047;
        int colbase = bn * 128 + wn * 64;
        int col = evenlane ? (colbase + n * 16 + (lane & 15))
                           : (colbase + (n + 1) * 16 + (lane & 15) - 1);
        unsigned int wv = evenlane ? pack2(v0, p0) : pack2(p1, v1);
        int h = col >> 7, d = col & 127;
        *(unsigned int*)(O + (((size_t)(b * 16 + h) * 2048 + t) << 7) + d) = wv;
      }
    }
  }
}

// ---------------------------------------------------------------------------
// Fast-path kernel 3: output projection from bf16 attout + bf16 Wo. fp32 out + bias.
// ---------------------------------------------------------------------------
__global__ __launch_bounds__(256) void out_gemm_bf(
    const unsigned short* __restrict__ Ab, const unsigned short* __restrict__ Wb,
    const float* __restrict__ bias, float* __restrict__ Out)
{
  __shared__ unsigned short As[128 * 32];
  __shared__ unsigned short Bs[128 * 32];
  const int tid = threadIdx.x;
  const int lane = tid & 63, wave = tid >> 6;
  const int wm = wave >> 1, wn = wave & 1;
  const int bm = blockIdx.x >> 4, bn = blockIdx.x & 15;

  f32x4 acc[4][4];
#pragma unroll
  for (int m = 0; m < 4; m++)
#pragma unroll
    for (int n = 0; n < 4; n++) acc[m][n] = (f32x4)(0.0f);

  gemm128_bf16(Ab, Wb, As, Bs, bm, bn, tid, acc);

  float bv[4];
#pragma unroll
  for (int n = 0; n < 4; n++) bv[n] = bias[bn * 128 + wn * 64 + n * 16 + (lane & 15)];
  const bool evenlane = (lane & 1) == 0;
#pragma unroll
  for (int m = 0; m < 4; m++) {
    int rowg = bm * 128 + wm * 64 + m * 16 + (lane >> 4) * 4;
#pragma unroll
    for (int n = 0; n < 4; n += 2) {
#pragma unroll
      for (int j = 0; j < 4; j++) {
        float v0 = acc[m][n][j] + bv[n];
        float v1 = acc[m][n + 1][j] + bv[n + 1];
        float p0 = __shfl_xor(v0, 1);
        float p1 = __shfl_xor(v1, 1);
        int row = rowg + j;
        int colbase = bn * 128 + wn * 64;
        int col = evenlane ? (colbase + n * 16 + (lane & 15))
                           : (colbase + (n + 1) * 16 + (lane & 15) - 1);
        f32x2 wv;
        if (evenlane) { wv[0] = v0; wv[1] = p0; }
        else          { wv[0] = p1; wv[1] = v1; }
        *(f32x2*)(Out + (size_t)row * 2048 + col) = wv;
      }
    }
  }
}

// ---------------------------------------------------------------------------
// Fallback kernel 1 (round-1): fused QKV projection with in-kernel fp32->bf16.
// ---------------------------------------------------------------------------
__global__ __launch_bounds__(256) void qkv_gemm(
    const float* __restrict__ A0, const float* __restrict__ A1, const float* __restrict__ A2,
    const float* __restrict__ W0, const float* __restrict__ W1, const float* __restrict__ W2,
    unsigned short* __restrict__ O0, unsigned short* __restrict__ O1, unsigned short* __restrict__ O2)
{
  __shared__ unsigned short As[128 * 32];
  __shared__ unsigned short Bs[128 * 32];
  const int z = blockIdx.z;
  const float* A = z == 0 ? A0 : (z == 1 ? A1 : A2);
  const float* W = z == 0 ? W0 : (z == 1 ? W1 : W2);
  unsigned short* O = z == 0 ? O0 : (z == 1 ? O1 : O2);

  const int tid = threadIdx.x;
  const int lane = tid & 63;
  const int wave = tid >> 6;
  const int wm = wave >> 1, wn = wave & 1;
  const int bm = blockIdx.x >> 4, bn = blockIdx.x & 15;

  const int srow = tid >> 1;
  const int shalf = tid & 1;
  const float* Ap = A + (size_t)(bm * 128 + srow) * 2048 + shalf * 16;
  const float* Wp = W + (size_t)(bn * 128 + srow) * 2048 + shalf * 16;
  const int ssw = (srow >> 1) & 3;
  const int aoff0 = srow * 32 + (((shalf * 2 + 0) ^ ssw) << 3);
  const int aoff1 = srow * 32 + (((shalf * 2 + 1) ^ ssw) << 3);

  const int frow = lane & 15;
  const int fk = lane >> 4;

  f32x4 acc[4][4];
#pragma unroll
  for (int m = 0; m < 4; m++)
#pragma unroll
    for (int n = 0; n < 4; n++) acc[m][n] = (f32x4)(0.0f);

  for (int kk = 0; kk < 2048; kk += 32) {
    f32x4 a0 = *(const f32x4*)(Ap + kk);
    f32x4 a1 = *(const f32x4*)(Ap + kk + 4);
    f32x4 a2 = *(const f32x4*)(Ap + kk + 8);
    f32x4 a3 = *(const f32x4*)(Ap + kk + 12);
    f32x4 b0 = *(const f32x4*)(Wp + kk);
    f32x4 b1 = *(const f32x4*)(Wp + kk + 4);
    f32x4 b2 = *(const f32x4*)(Wp + kk + 8);
    f32x4 b3 = *(const f32x4*)(Wp + kk + 12);
    __syncthreads();
    *(u32x4*)(As + aoff0) = pack8(a0, a1);
    *(u32x4*)(As + aoff1) = pack8(a2, a3);
    *(u32x4*)(Bs + aoff0) = pack8(b0, b1);
    *(u32x4*)(Bs + aoff1) = pack8(b2, b3);
    __syncthreads();
    bf16x8 af[4], bfr[4];
#pragma unroll
    for (int m = 0; m < 4; m++) {
      int r = wm * 64 + m * 16 + frow;
      af[m] = *(const bf16x8*)(As + r * 32 + ((fk ^ ((r >> 1) & 3)) << 3));
    }
#pragma unroll
    for (int n = 0; n < 4; n++) {
      int r = wn * 64 + n * 16 + frow;
      bfr[n] = *(const bf16x8*)(Bs + r * 32 + ((fk ^ ((r >> 1) & 3)) << 3));
    }
#pragma unroll
    for (int m = 0; m < 4; m++)
#pragma unroll
      for (int n = 0; n < 4; n++)
        acc[m][n] = __builtin_amdgcn_mfma_f32_16x16x32_bf16(af[m], bfr[n], acc[m][n], 0, 0, 0);
  }

  const bool evenlane = (lane & 1) == 0;
#pragma unroll
  for (int m = 0; m < 4; m++) {
    int rowg = bm * 128 + wm * 64 + m * 16 + (lane >> 4) * 4;
#pragma unroll
    for (int n = 0; n < 4; n += 2) {
#pragma unroll
      for (int j = 0; j < 4; j++) {
        float v0 = acc[m][n][j], v1 = acc[m][n + 1][j];
        float p0 = __shfl_xor(v0, 1);
        float p1 = __shfl_xor(v1, 1);
        int row = rowg + j;
        int b = row >> 11, t = row & 2047;
        int colbase = bn * 128 + wn * 64;
        int col = evenlane ? (colbase + n * 16 + (lane & 15))
                           : (colbase + (n + 1) * 16 + (lane & 15) - 1);
        unsigned int wv = evenlane ? pack2(v0, p0) : pack2(p1, v1);
        int h = col >> 7, d = col & 127;
        *(unsigned int*)(O + (((size_t)(b * 16 + h) * 2048 + t) << 7) + d) = wv;
      }
    }
  }
}

// ---------------------------------------------------------------------------
// Kernel 2 (shared): flash attention. 64 (b,h) pairs x 32 Q-tiles of 64 rows.
// ---------------------------------------------------------------------------
__global__ __launch_bounds__(256) void attn(
    const unsigned short* __restrict__ Qw, const unsigned short* __restrict__ Kw,
    const unsigned short* __restrict__ Vw, unsigned short* __restrict__ attout)
{
  __shared__ unsigned short Qs[64 * 128];
  __shared__ unsigned short Ks[64 * 128];
  __shared__ unsigned short Vs[128 * 64];
  __shared__ unsigned short Ps[64 * 64];

  const int bh = blockIdx.x >> 5;
  const int qtile = blockIdx.x & 31;
  const int b = bh >> 4, h = bh & 15;
  const unsigned short* Qbase = Qw + (size_t)bh * 2048 * 128 + qtile * 64 * 128;
  const unsigned short* Kbase = Kw + (size_t)bh * 2048 * 128;
  const unsigned short* Vbase = Vw + (size_t)bh * 2048 * 128;
  const int tid = threadIdx.x, lane = tid & 63, wave = tid >> 6;

#pragma unroll
  for (int p = 0; p < 4; p++) {
    int row = p * 16 + (tid >> 4);
    int ch = tid & 15;
    *(u32x4*)(Qs + row * 128 + ((ch ^ (row & 15)) << 3)) =
        *(const u32x4*)(Qbase + row * 128 + ch * 8);
  }

  f32x4 o[8];
#pragma unroll
  for (int n = 0; n < 8; n++) o[n] = (f32x4)(0.0f);
  float m_r[4] = {-INFINITY, -INFINITY, -INFINITY, -INFINITY};
  float l_r[4] = {0.f, 0.f, 0.f, 0.f};
  const float SC = 0.12751721769f;  // log2(e)/sqrt(128)

  const int frow = lane & 15;
  const int fk = lane >> 4;

  for (int kt = 0; kt < 32; kt++) {
    const unsigned short* Kt = Kbase + kt * 64 * 128;
    const unsigned short* Vt = Vbase + kt * 64 * 128;
    __syncthreads();
#pragma unroll
    for (int p = 0; p < 4; p++) {
      int row = p * 16 + (tid >> 4);
      int ch = tid & 15;
      *(u32x4*)(Ks + row * 128 + ((ch ^ (row & 15)) << 3)) =
          *(const u32x4*)(Kt + row * 128 + ch * 8);
    }
    {
      int k4 = (tid >> 4) * 4;
      int d8 = (tid & 15) * 8;
      u16x8 vr0 = *(const u16x8*)(Vt + (k4 + 0) * 128 + d8);
      u16x8 vr1 = *(const u16x8*)(Vt + (k4 + 1) * 128 + d8);
      u16x8 vr2 = *(const u16x8*)(Vt + (k4 + 2) * 128 + d8);
      u16x8 vr3 = *(const u16x8*)(Vt + (k4 + 3) * 128 + d8);
#pragma unroll
      for (int dd = 0; dd < 8; dd++) {
        u16x4 pk; pk[0] = vr0[dd]; pk[1] = vr1[dd]; pk[2] = vr2[dd]; pk[3] = vr3[dd];
        int row = d8 + dd;
        int byteoff = k4 * 2;
        int ch = byteoff >> 4, lo = byteoff & 15;
        *(u16x4*)((char*)Vs + row * 128 + ((ch ^ (row & 7)) << 4) + lo) = pk;
      }
    }
    __syncthreads();

    f32x4 s[4];
#pragma unroll
    for (int n = 0; n < 4; n++) s[n] = (f32x4)(0.0f);
#pragma unroll
    for (int ks = 0; ks < 4; ks++) {
      int arow = wave * 16 + frow;
      bf16x8 aq = *(const bf16x8*)(Qs + arow * 128 + (((ks * 4 + fk) ^ (arow & 15)) << 3));
#pragma unroll
      for (int n = 0; n < 4; n++) {
        int brow = n * 16 + frow;
        bf16x8 bk = *(const bf16x8*)(Ks + brow * 128 + (((ks * 4 + fk) ^ (brow & 15)) << 3));
        s[n] = __builtin_amdgcn_mfma_f32_16x16x32_bf16(aq, bk, s[n], 0, 0, 0);
      }
    }

#pragma unroll
    for (int j = 0; j < 4; j++) {
      float mx = fmaxf(fmaxf(s[0][j], s[1][j]), fmaxf(s[2][j], s[3][j]));
      mx = fmaxf(mx, __shfl_xor(mx, 1));
      mx = fmaxf(mx, __shfl_xor(mx, 2));
      mx = fmaxf(mx, __shfl_xor(mx, 4));
      mx = fmaxf(mx, __shfl_xor(mx, 8));
      float mnew = fmaxf(m_r[j], mx);
      float f = __builtin_amdgcn_exp2f((m_r[j] - mnew) * SC);
      m_r[j] = mnew;
      float psum = 0.f;
#pragma unroll
      for (int n = 0; n < 4; n++) {
        float p = __builtin_amdgcn_exp2f((s[n][j] - mnew) * SC);
        s[n][j] = p;
        psum += p;
      }
      psum += __shfl_xor(psum, 1);
      psum += __shfl_xor(psum, 2);
      psum += __shfl_xor(psum, 4);
      psum += __shfl_xor(psum, 8);
      l_r[j] = l_r[j] * f + psum;
#pragma unroll
      for (int n = 0; n < 8; n++) o[n][j] *= f;
    }

#pragma unroll
    for (int j = 0; j < 4; j++) {
      int row = wave * 16 + (lane >> 4) * 4 + j;
      int swz = row & 7;
#pragma unroll
      for (int n = 0; n < 4; n++) {
        int col = (lane & 15) + 16 * n;
        int byteoff = (((col >> 3) ^ swz) << 4) + (col & 7) * 2;
        *(unsigned short*)((char*)Ps + row * 128 + byteoff) = f2bf(s[n][j]);
      }
    }

#pragma unroll
    for (int ks = 0; ks < 2; ks++) {
      int arow = wave * 16 + frow;
      bf16x8 ap = *(const bf16x8*)((char*)Ps + arow * 128 + (((ks * 4 + fk) ^ (arow & 7)) << 4));
#pragma unroll
      for (int n = 0; n < 8; n++) {
        int vrow = (lane & 15) + 16 * n;
        bf16x8 bv = *(const bf16x8*)((char*)Vs + vrow * 128 + (((ks * 4 + fk) ^ (vrow & 7)) << 4));
        o[n] = __builtin_amdgcn_mfma_f32_16x16x32_bf16(ap, bv, o[n], 0, 0, 0);
      }
    }
  }

  float inv[4];
#pragma unroll
  for (int j = 0; j < 4; j++) inv[j] = 1.0f / l_r[j];
  const bool evenlane = (lane & 1) == 0;
#pragma unroll
  for (int n = 0; n < 8; n += 2) {
#pragma unroll
    for (int j = 0; j < 4; j++) {
      float v0 = o[n][j] * inv[j], v1 = o[n + 1][j] * inv[j];
      float p0 = __shfl_xor(v0, 1);
      float p1 = __shfl_xor(v1, 1);
      int tq = qtile * 64 + wave * 16 + (lane >> 4) * 4 + j;
      int col = evenlane ? (n * 16 + (lane & 15)) : ((n + 1) * 16 + (lane & 15) - 1);
      unsigned int wv = evenlane ? pack2(v0, p0) : pack2(p1, v1);
      *(unsigned int*)(attout + (size_t)(b * 2048 + tq) * 2048 + h * 128 + col) = wv;
    }
  }
}

// ---------------------------------------------------------------------------
// Fallback kernel 3 (round-1): output projection with in-kernel fp32 W pack.
// ---------------------------------------------------------------------------
__global__ __launch_bounds__(256) void out_gemm(
    const unsigned short* __restrict__ Ab, const float* __restrict__ W,
    const float* __restrict__ bias, float* __restrict__ Out)
{
  __shared__ unsigned short As[128 * 32];
  __shared__ unsigned short Bs[128 * 32];

  const int tid = threadIdx.x;
  const int lane = tid & 63;
  const int wave = tid >> 6;
  const int wm = wave >> 1, wn = wave & 1;
  const int bm = blockIdx.x >> 4, bn = blockIdx.x & 15;

  const int srow = tid >> 1;
  const int shalf = tid & 1;
  const unsigned short* Ap = Ab + (size_t)(bm * 128 + srow) * 2048 + shalf * 16;
  const float* Wp = W + (size_t)(bn * 128 + srow) * 2048 + shalf * 16;
  const int ssw = (srow >> 1) & 3;
  const int aoff0 = srow * 32 + (((shalf * 2 + 0) ^ ssw) << 3);
  const int aoff1 = srow * 32 + (((shalf * 2 + 1) ^ ssw) << 3);

  const int frow = lane & 15;
  const int fk = lane >> 4;

  f32x4 acc[4][4];
#pragma unroll
  for (int m = 0; m < 4; m++)
#pragma unroll
    for (int n = 0; n < 4; n++) acc[m][n] = (f32x4)(0.0f);

  for (int kk = 0; kk < 2048; kk += 32) {
    u32x4 a0 = *(const u32x4*)(Ap + kk);
    u32x4 a1 = *(const u32x4*)(Ap + kk + 8);
    f32x4 b0 = *(const f32x4*)(Wp + kk);
    f32x4 b1 = *(const f32x4*)(Wp + kk + 4);
    f32x4 b2 = *(const f32x4*)(Wp + kk + 8);
    f32x4 b3 = *(const f32x4*)(Wp + kk + 12);
    __syncthreads();
    *(u32x4*)(As + aoff0) = a0;
    *(u32x4*)(As + aoff1) = a1;
    *(u32x4*)(Bs + aoff0) = pack8(b0, b1);
    *(u32x4*)(Bs + aoff1) = pack8(b2, b3);
    __syncthreads();
    bf16x8 af[4], bfr[4];
#pragma unroll
    for (int m = 0; m < 4; m++) {
      int r = wm * 64 + m * 16 + frow;
      af[m] = *(const bf16x8*)(As + r * 32 + ((fk ^ ((r >> 1) & 3)) << 3));
    }
#pragma unroll
    for (int n = 0; n < 4; n++) {
      int r = wn * 64 + n * 16 + frow;
      bfr[n] = *(const bf16x8*)(Bs + r * 32 + ((fk ^ ((r >> 1) & 3)) << 3));
    }
#pragma unroll
    for (int m = 0; m < 4; m++)
#pragma unroll
      for (int n = 0; n < 4; n++)
        acc[m][n] = __builtin_amdgcn_mfma_f32_16x16x32_bf16(af[m], bfr[n], acc[m][n], 0, 0, 0);
  }

  float bv[4];
#pragma unroll
  for (int n = 0; n < 4; n++) bv[n] = bias[bn * 128 + wn * 64 + n * 16 + (lane & 15)];
  const bool evenlane = (lane & 1) == 0;
#pragma unroll
  for (int m = 0; m < 4; m++) {
    int rowg = bm * 128 + wm * 64 + m * 16 + (lane >> 4) * 4;
#pragma unroll
    for (int n = 0; n < 4; n += 2) {
#pragma unroll
      for (int j = 0; j < 4; j++) {
        float v0 = acc[m][n][j] + bv[n];
        float v1 = acc[m][n + 1][j] + bv[n + 1];
        float p0 = __shfl_xor(v0, 1);
        float p1 = __shfl_xor(v1, 1);
        int row = rowg + j;
        int colbase = bn * 128 + wn * 64;
        int col = evenlane ? (colbase + n * 16 + (lane & 15))
                           : (colbase + (n + 1) * 16 + (lane & 15) - 1);
        f32x2 wv;
        if (evenlane) { wv[0] = v0; wv[1] = p0; }
        else          { wv[0] = p1; wv[1] = v1; }
        *(f32x2*)(Out + (size_t)row * 2048 + col) = wv;
      }
    }
  }
}

// ---------------------------------------------------------------------------
extern "C" void kernel_launch(void* const* d_in, const int* in_sizes, int n_in,
                              void* d_out, int out_size, void* d_ws, size_t ws_size,
                              hipStream_t stream)
{
  // setup_inputs order: k, q, v, Wk, Wq, Wv, Wo, bo
  const float* k  = (const float*)d_in[0];
  const float* q  = (const float*)d_in[1];
  const float* v  = (const float*)d_in[2];
  const float* Wk = (const float*)d_in[3];
  const float* Wq = (const float*)d_in[4];
  const float* Wv = (const float*)d_in[5];
  const float* Wo = (const float*)d_in[6];
  const float* bo = (const float*)d_in[7];
  float* out = (float*)d_out;

  const size_t HSZ = (size_t)4 * 16 * 2048 * 128;   // 16,777,216 elems = 32 MiB

  if (ws_size >= (size_t)224 << 20) {
    // Fast path: Abf[0,96MiB) | Wbf[96,128) | Qw/Kw/Vw[128,224). attout reuses Abf.
    unsigned short* Abf = (unsigned short*)d_ws;
    unsigned short* Wbf = Abf + 3 * HSZ;
    unsigned short* Qw  = Wbf + 4 * 4194304;
    unsigned short* Kw  = Qw + HSZ;
    unsigned short* Vw  = Kw + HSZ;
    unsigned short* Aw  = Abf;                      // attout (after projections done)

    convA<<<dim3(8192, 1, 3), 256, 0, stream>>>(q, k, v, Abf);
    convW<<<dim3(2048, 1, 4), 256, 0, stream>>>(Wq, Wk, Wv, Wo, Wbf);
    qkv_gemm_bf<<<dim3(1024, 1, 3), 256, 0, stream>>>(Abf, Wbf, Qw, Kw, Vw);
    attn<<<dim3(2048), 256, 0, stream>>>(Qw, Kw, Vw, Aw);
    out_gemm_bf<<<dim3(1024), 256, 0, stream>>>(Aw, Wbf + 3 * 4194304, bo, out);
  } else {
    // Fallback (round-1, 128 MiB)
    unsigned short* Qw = (unsigned short*)d_ws;
    unsigned short* Kw = Qw + HSZ;
    unsigned short* Vw = Kw + HSZ;
    unsigned short* Aw = Vw + HSZ;
    qkv_gemm<<<dim3(1024, 1, 3), 256, 0, stream>>>(q, k, v, Wq, Wk, Wv, Qw, Kw, Vw);
    attn<<<dim3(2048), 256, 0, stream>>>(Qw, Kw, Vw, Aw);
    out_gemm<<<dim3(1024), 256, 0, stream>>>(Aw, Wo, bo, out);
  }
}

// Round 3
// 817.860 us; speedup vs baseline: 1.5794x; 1.1909x over previous
//
#include <hip/hip_runtime.h>

// MHA: out = softmax((qWq^T)(kWk^T)^T/sqrt(128)) (vWv^T) Wo^T + bo
// B=4 T=2048 E=2048 H=16 D=128. All GEMMs via bf16 MFMA (fp32 accum).

typedef __attribute__((ext_vector_type(4))) float f32x4;
typedef __attribute__((ext_vector_type(2))) float f32x2;
typedef __attribute__((ext_vector_type(8))) __bf16 bf16x8;
typedef __attribute__((ext_vector_type(4))) unsigned int u32x4;
typedef __attribute__((ext_vector_type(8))) unsigned short u16x8;
typedef __attribute__((ext_vector_type(4))) unsigned short u16x4;

#define DEVI static __device__ __forceinline__

DEVI unsigned short f2bf(float f) {            // RNE fp32 -> bf16
  union { float f; unsigned u; } x; x.f = f;
  unsigned u = x.u;
  return (unsigned short)((u + 0x7fffu + ((u >> 16) & 1u)) >> 16);
}
DEVI unsigned int pack2(float lo, float hi) {
  return (unsigned int)f2bf(lo) | ((unsigned int)f2bf(hi) << 16);
}
DEVI u32x4 pack8(const f32x4 a, const f32x4 b) {
  u32x4 r;
  r[0] = pack2(a[0], a[1]); r[1] = pack2(a[2], a[3]);
  r[2] = pack2(b[0], b[1]); r[3] = pack2(b[2], b[3]);
  return r;
}
DEVI void gload16(const unsigned short* g, unsigned short* l) {
  __builtin_amdgcn_global_load_lds(
      (const __attribute__((address_space(1))) unsigned int*)g,
      (__attribute__((address_space(3))) unsigned int*)l, 16, 0, 0);
}

// ---------------------------------------------------------------------------
// fp32 -> bf16 convert passes
// ---------------------------------------------------------------------------
__global__ __launch_bounds__(256) void convA(
    const float* __restrict__ q, const float* __restrict__ k,
    const float* __restrict__ v, unsigned short* __restrict__ dst)
{
  const int z = blockIdx.z;
  const float* src = z == 0 ? q : (z == 1 ? k : v);
  unsigned short* d = dst + (size_t)z * 16777216;
  size_t i = ((size_t)blockIdx.x * 256 + threadIdx.x) * 8;
  f32x4 a = *(const f32x4*)(src + i);
  f32x4 b = *(const f32x4*)(src + i + 4);
  *(u32x4*)(d + i) = pack8(a, b);
}

__global__ __launch_bounds__(256) void convW(
    const float* __restrict__ w0, const float* __restrict__ w1,
    const float* __restrict__ w2, const float* __restrict__ w3,
    unsigned short* __restrict__ dst)
{
  const int z = blockIdx.z;
  const float* src = z == 0 ? w0 : (z == 1 ? w1 : (z == 2 ? w2 : w3));
  unsigned short* d = dst + (size_t)z * 4194304;
  size_t i = ((size_t)blockIdx.x * 256 + threadIdx.x) * 8;
  f32x4 a = *(const f32x4*)(src + i);
  f32x4 b = *(const f32x4*)(src + i + 4);
  *(u32x4*)(d + i) = pack8(a, b);
}

// ---------------------------------------------------------------------------
// Shared bf16 GEMM mainloop (m97 structure): 128x128 tile, BK=32, 4 waves 2x2.
// ---------------------------------------------------------------------------
DEVI void gemm128_bf16(const unsigned short* __restrict__ A,
                       const unsigned short* __restrict__ Bm,
                       unsigned short* As, unsigned short* Bs,
                       int bm, int bn, int tid, f32x4 (&acc)[4][4])
{
  const int lane = tid & 63, wave = tid >> 6;
  const int c = lane & 3;
  const int r0 = (wave * 2 + 0) * 16 + (lane >> 2);
  const int r1 = (wave * 2 + 1) * 16 + (lane >> 2);
  const unsigned short* Ap0 = A + (size_t)(bm * 128 + r0) * 2048 + ((c ^ ((r0 >> 1) & 3)) << 3);
  const unsigned short* Ap1 = A + (size_t)(bm * 128 + r1) * 2048 + ((c ^ ((r1 >> 1) & 3)) << 3);
  const unsigned short* Bp0 = Bm + (size_t)(bn * 128 + r0) * 2048 + ((c ^ ((r0 >> 1) & 3)) << 3);
  const unsigned short* Bp1 = Bm + (size_t)(bn * 128 + r1) * 2048 + ((c ^ ((r1 >> 1) & 3)) << 3);
  unsigned short* Asl0 = As + (wave * 2 + 0) * 512;
  unsigned short* Asl1 = As + (wave * 2 + 1) * 512;
  unsigned short* Bsl0 = Bs + (wave * 2 + 0) * 512;
  unsigned short* Bsl1 = Bs + (wave * 2 + 1) * 512;

  const int wm = wave >> 1, wn = wave & 1;
  const int frow = lane & 15, fk = lane >> 4;
  int aoff[4], boff[4];
#pragma unroll
  for (int m = 0; m < 4; m++) {
    int ra = wm * 64 + m * 16 + frow;
    aoff[m] = ra * 32 + ((fk ^ ((ra >> 1) & 3)) << 3);
    int rb = wn * 64 + m * 16 + frow;
    boff[m] = rb * 32 + ((fk ^ ((rb >> 1) & 3)) << 3);
  }

  for (int kk = 0; kk < 2048; kk += 32) {
    __syncthreads();
    gload16(Ap0 + kk, Asl0);
    gload16(Ap1 + kk, Asl1);
    gload16(Bp0 + kk, Bsl0);
    gload16(Bp1 + kk, Bsl1);
    __syncthreads();
    bf16x8 af[4], bfv[4];
#pragma unroll
    for (int m = 0; m < 4; m++) af[m] = *(const bf16x8*)(As + aoff[m]);
#pragma unroll
    for (int n = 0; n < 4; n++) bfv[n] = *(const bf16x8*)(Bs + boff[n]);
#pragma unroll
    for (int m = 0; m < 4; m++)
#pragma unroll
      for (int n = 0; n < 4; n++)
        acc[m][n] = __builtin_amdgcn_mfma_f32_16x16x32_bf16(af[m], bfv[n], acc[m][n], 0, 0, 0);
  }
}

// ---------------------------------------------------------------------------
// Kernel 1: QKV projection from pre-converted bf16. Output [B,H,T,D] bf16.
// ---------------------------------------------------------------------------
__global__ __launch_bounds__(256) void qkv_gemm_bf(
    const unsigned short* __restrict__ Abf, const unsigned short* __restrict__ Wbf,
    unsigned short* __restrict__ O0, unsigned short* __restrict__ O1,
    unsigned short* __restrict__ O2)
{
  __shared__ unsigned short As[128 * 32];
  __shared__ unsigned short Bs[128 * 32];
  const int z = blockIdx.z;
  const unsigned short* A = Abf + (size_t)z * 16777216;
  const unsigned short* W = Wbf + (size_t)z * 4194304;
  unsigned short* O = z == 0 ? O0 : (z == 1 ? O1 : O2);

  const int tid = threadIdx.x;
  const int lane = tid & 63, wave = tid >> 6;
  const int wm = wave >> 1, wn = wave & 1;
  const int bm = blockIdx.x >> 4, bn = blockIdx.x & 15;

  f32x4 acc[4][4];
#pragma unroll
  for (int m = 0; m < 4; m++)
#pragma unroll
    for (int n = 0; n < 4; n++) acc[m][n] = (f32x4)(0.0f);

  gemm128_bf16(A, W, As, Bs, bm, bn, tid, acc);

  const bool evenlane = (lane & 1) == 0;
#pragma unroll
  for (int m = 0; m < 4; m++) {
    int rowg = bm * 128 + wm * 64 + m * 16 + (lane >> 4) * 4;
#pragma unroll
    for (int n = 0; n < 4; n += 2) {
#pragma unroll
      for (int j = 0; j < 4; j++) {
        float v0 = acc[m][n][j], v1 = acc[m][n + 1][j];
        float p0 = __shfl_xor(v0, 1);
        float p1 = __shfl_xor(v1, 1);
        int row = rowg + j;
        int b = row >> 11, t = row & 2047;
        int colbase = bn * 128 + wn * 64;
        int col = evenlane ? (colbase + n * 16 + (lane & 15))
                           : (colbase + (n + 1) * 16 + (lane & 15) - 1);
        unsigned int wv = evenlane ? pack2(v0, p0) : pack2(p1, v1);
        int h = col >> 7, d = col & 127;
        *(unsigned int*)(O + (((size_t)(b * 16 + h) * 2048 + t) << 7) + d) = wv;
      }
    }
  }
}

// ---------------------------------------------------------------------------
// Kernel 3: output projection from bf16 attout + bf16 Wo. fp32 out + bias.
// ---------------------------------------------------------------------------
__global__ __launch_bounds__(256) void out_gemm_bf(
    const unsigned short* __restrict__ Ab, const unsigned short* __restrict__ Wb,
    const float* __restrict__ bias, float* __restrict__ Out)
{
  __shared__ unsigned short As[128 * 32];
  __shared__ unsigned short Bs[128 * 32];
  const int tid = threadIdx.x;
  const int lane = tid & 63, wave = tid >> 6;
  const int wm = wave >> 1, wn = wave & 1;
  const int bm = blockIdx.x >> 4, bn = blockIdx.x & 15;

  f32x4 acc[4][4];
#pragma unroll
  for (int m = 0; m < 4; m++)
#pragma unroll
    for (int n = 0; n < 4; n++) acc[m][n] = (f32x4)(0.0f);

  gemm128_bf16(Ab, Wb, As, Bs, bm, bn, tid, acc);

  float bv[4];
#pragma unroll
  for (int n = 0; n < 4; n++) bv[n] = bias[bn * 128 + wn * 64 + n * 16 + (lane & 15)];
  const bool evenlane = (lane & 1) == 0;
#pragma unroll
  for (int m = 0; m < 4; m++) {
    int rowg = bm * 128 + wm * 64 + m * 16 + (lane >> 4) * 4;
#pragma unroll
    for (int n = 0; n < 4; n += 2) {
#pragma unroll
      for (int j = 0; j < 4; j++) {
        float v0 = acc[m][n][j] + bv[n];
        float v1 = acc[m][n + 1][j] + bv[n + 1];
        float p0 = __shfl_xor(v0, 1);
        float p1 = __shfl_xor(v1, 1);
        int row = rowg + j;
        int colbase = bn * 128 + wn * 64;
        int col = evenlane ? (colbase + n * 16 + (lane & 15))
                           : (colbase + (n + 1) * 16 + (lane & 15) - 1);
        f32x2 wv;
        if (evenlane) { wv[0] = v0; wv[1] = p0; }
        else          { wv[0] = p1; wv[1] = v1; }
        *(f32x2*)(Out + (size_t)row * 2048 + col) = wv;
      }
    }
  }
}

// ---------------------------------------------------------------------------
// Fallback kernel 1 (round-1): fused QKV projection with in-kernel fp32->bf16.
// ---------------------------------------------------------------------------
__global__ __launch_bounds__(256) void qkv_gemm(
    const float* __restrict__ A0, const float* __restrict__ A1, const float* __restrict__ A2,
    const float* __restrict__ W0, const float* __restrict__ W1, const float* __restrict__ W2,
    unsigned short* __restrict__ O0, unsigned short* __restrict__ O1, unsigned short* __restrict__ O2)
{
  __shared__ unsigned short As[128 * 32];
  __shared__ unsigned short Bs[128 * 32];
  const int z = blockIdx.z;
  const float* A = z == 0 ? A0 : (z == 1 ? A1 : A2);
  const float* W = z == 0 ? W0 : (z == 1 ? W1 : W2);
  unsigned short* O = z == 0 ? O0 : (z == 1 ? O1 : O2);

  const int tid = threadIdx.x;
  const int lane = tid & 63;
  const int wave = tid >> 6;
  const int wm = wave >> 1, wn = wave & 1;
  const int bm = blockIdx.x >> 4, bn = blockIdx.x & 15;

  const int srow = tid >> 1;
  const int shalf = tid & 1;
  const float* Ap = A + (size_t)(bm * 128 + srow) * 2048 + shalf * 16;
  const float* Wp = W + (size_t)(bn * 128 + srow) * 2048 + shalf * 16;
  const int ssw = (srow >> 1) & 3;
  const int aoff0 = srow * 32 + (((shalf * 2 + 0) ^ ssw) << 3);
  const int aoff1 = srow * 32 + (((shalf * 2 + 1) ^ ssw) << 3);

  const int frow = lane & 15;
  const int fk = lane >> 4;

  f32x4 acc[4][4];
#pragma unroll
  for (int m = 0; m < 4; m++)
#pragma unroll
    for (int n = 0; n < 4; n++) acc[m][n] = (f32x4)(0.0f);

  for (int kk = 0; kk < 2048; kk += 32) {
    f32x4 a0 = *(const f32x4*)(Ap + kk);
    f32x4 a1 = *(const f32x4*)(Ap + kk + 4);
    f32x4 a2 = *(const f32x4*)(Ap + kk + 8);
    f32x4 a3 = *(const f32x4*)(Ap + kk + 12);
    f32x4 b0 = *(const f32x4*)(Wp + kk);
    f32x4 b1 = *(const f32x4*)(Wp + kk + 4);
    f32x4 b2 = *(const f32x4*)(Wp + kk + 8);
    f32x4 b3 = *(const f32x4*)(Wp + kk + 12);
    __syncthreads();
    *(u32x4*)(As + aoff0) = pack8(a0, a1);
    *(u32x4*)(As + aoff1) = pack8(a2, a3);
    *(u32x4*)(Bs + aoff0) = pack8(b0, b1);
    *(u32x4*)(Bs + aoff1) = pack8(b2, b3);
    __syncthreads();
    bf16x8 af[4], bfr[4];
#pragma unroll
    for (int m = 0; m < 4; m++) {
      int r = wm * 64 + m * 16 + frow;
      af[m] = *(const bf16x8*)(As + r * 32 + ((fk ^ ((r >> 1) & 3)) << 3));
    }
#pragma unroll
    for (int n = 0; n < 4; n++) {
      int r = wn * 64 + n * 16 + frow;
      bfr[n] = *(const bf16x8*)(Bs + r * 32 + ((fk ^ ((r >> 1) & 3)) << 3));
    }
#pragma unroll
    for (int m = 0; m < 4; m++)
#pragma unroll
      for (int n = 0; n < 4; n++)
        acc[m][n] = __builtin_amdgcn_mfma_f32_16x16x32_bf16(af[m], bfr[n], acc[m][n], 0, 0, 0);
  }

  const bool evenlane = (lane & 1) == 0;
#pragma unroll
  for (int m = 0; m < 4; m++) {
    int rowg = bm * 128 + wm * 64 + m * 16 + (lane >> 4) * 4;
#pragma unroll
    for (int n = 0; n < 4; n += 2) {
#pragma unroll
      for (int j = 0; j < 4; j++) {
        float v0 = acc[m][n][j], v1 = acc[m][n + 1][j];
        float p0 = __shfl_xor(v0, 1);
        float p1 = __shfl_xor(v1, 1);
        int row = rowg + j;
        int b = row >> 11, t = row & 2047;
        int colbase = bn * 128 + wn * 64;
        int col = evenlane ? (colbase + n * 16 + (lane & 15))
                           : (colbase + (n + 1) * 16 + (lane & 15) - 1);
        unsigned int wv = evenlane ? pack2(v0, p0) : pack2(p1, v1);
        int h = col >> 7, d = col & 127;
        *(unsigned int*)(O + (((size_t)(b * 16 + h) * 2048 + t) << 7) + d) = wv;
      }
    }
  }
}

// ---------------------------------------------------------------------------
// Kernel 2: flash attention v2. 64 (b,h) x 16 Q-tiles of 128 rows; 4 waves,
// wave owns 32 q-rows (M_rep=2). Q hoisted to registers. KVBLK=64, K/V LDS
// double-buffered (T14 split: issue loads early, ds_write V after compute).
// K staged via global_load_lds (linear dest, pre-swizzled global src).
// ---------------------------------------------------------------------------
__global__ __launch_bounds__(256, 2) void attn(
    const unsigned short* __restrict__ Qw, const unsigned short* __restrict__ Kw,
    const unsigned short* __restrict__ Vw, unsigned short* __restrict__ attout)
{
  __shared__ unsigned short Ks[2][64 * 128];   // [key][d], 16-byte slot swizzle s^(row&15)
  __shared__ unsigned short Vs[2][128 * 64];   // V^T [d][key], slot swizzle s^(row&7)
  __shared__ unsigned short Ps[128 * 64];      // P [q][key], slot swizzle s^(row&7)

  const int bh = blockIdx.x >> 4;
  const int qtile = blockIdx.x & 15;
  const int b = bh >> 4, h = bh & 15;
  const unsigned short* Qbase = Qw + (size_t)bh * 2048 * 128 + qtile * 128 * 128;
  const unsigned short* Kbase = Kw + (size_t)bh * 2048 * 128;
  const unsigned short* Vbase = Vw + (size_t)bh * 2048 * 128;
  const int tid = threadIdx.x, lane = tid & 63, w = tid >> 6;
  const int frow = lane & 15, fk = lane >> 4;

  // ---- Q hoist: 2 m-frags x 4 ks-frags in registers (loaded once)
  bf16x8 qf[2][4];
#pragma unroll
  for (int m = 0; m < 2; m++)
#pragma unroll
    for (int ks = 0; ks < 4; ks++)
      qf[m][ks] = *(const bf16x8*)(Qbase + (size_t)(w * 32 + m * 16 + frow) * 128 + ks * 32 + fk * 8);

  // staging geometry
  const int krow_i = lane >> 4;     // K: row-in-issue 0..3
  const int kslot = lane & 15;      // K: 16B slot 0..15
  const int vkb = (tid & 7) * 8;    // V: this thread's 8 keys
  const int vdb = (tid >> 3) * 4;   // V: this thread's 4 d-cols

  f32x4 o[2][8];
#pragma unroll
  for (int m = 0; m < 2; m++)
#pragma unroll
    for (int n = 0; n < 8; n++) o[m][n] = (f32x4)(0.0f);
  float m_r[2][4], l_r[2][4];
#pragma unroll
  for (int m = 0; m < 2; m++)
#pragma unroll
    for (int j = 0; j < 4; j++) { m_r[m][j] = -INFINITY; l_r[m][j] = 0.f; }
  const float SC = 0.12751721769f;  // log2(e)/sqrt(128)

  // ---- prologue: stage tile 0 into buffer 0
  {
#pragma unroll
    for (int i = 0; i < 4; i++) {
      int row = w * 16 + i * 4 + krow_i;
      gload16(Kbase + (size_t)row * 128 + ((kslot ^ (row & 15)) << 3),
              &Ks[0][(w * 16 + i * 4) * 128]);
    }
    u16x4 vr[8];
#pragma unroll
    for (int i = 0; i < 8; i++) vr[i] = *(const u16x4*)(Vbase + (size_t)(vkb + i) * 128 + vdb);
#pragma unroll
    for (int dd = 0; dd < 4; dd++) {
      int row = vdb + dd;
      u16x8 pk;
#pragma unroll
      for (int i = 0; i < 8; i++) pk[i] = vr[i][dd];
      *(u16x8*)((char*)&Vs[0][0] + row * 128 + (((tid & 7) ^ (row & 7)) << 4)) = pk;
    }
  }

  for (int kt = 0; kt < 32; kt++) {
    const int cur = kt & 1;
    __syncthreads();   // buf[cur] staged (barrier drains vmcnt+lgkm); buf[cur^1] reads done

    // ---- T14: issue next tile's loads now, write V to LDS after compute
    u16x4 vr[8];
    const bool have_next = (kt + 1) < 32;
    if (have_next) {
      const unsigned short* Kt = Kbase + (kt + 1) * 64 * 128;
      const unsigned short* Vt = Vbase + (kt + 1) * 64 * 128;
#pragma unroll
      for (int i = 0; i < 4; i++) {
        int row = w * 16 + i * 4 + krow_i;
        gload16(Kt + (size_t)row * 128 + ((kslot ^ (row & 15)) << 3),
                &Ks[cur ^ 1][(w * 16 + i * 4) * 128]);
      }
#pragma unroll
      for (int i = 0; i < 8; i++) vr[i] = *(const u16x4*)(Vt + (size_t)(vkb + i) * 128 + vdb);
    }

    // ---- S = Q K^T (32 q-rows x 64 keys per wave); bk reused across m
    f32x4 s[2][4];
#pragma unroll
    for (int m = 0; m < 2; m++)
#pragma unroll
      for (int n = 0; n < 4; n++) s[m][n] = (f32x4)(0.0f);
#pragma unroll
    for (int ks = 0; ks < 4; ks++) {
#pragma unroll
      for (int n = 0; n < 4; n++) {
        int brow = n * 16 + frow;
        bf16x8 bk = *(const bf16x8*)(&Ks[cur][0] + brow * 128 + (((ks * 4 + fk) ^ (brow & 15)) << 3));
#pragma unroll
        for (int m = 0; m < 2; m++)
          s[m][n] = __builtin_amdgcn_mfma_f32_16x16x32_bf16(qf[m][ks], bk, s[m][n], 0, 0, 0);
      }
    }

    // ---- online softmax (8 rows/lane: 2 m x 4 j)
#pragma unroll
    for (int m = 0; m < 2; m++) {
#pragma unroll
      for (int j = 0; j < 4; j++) {
        float mx = fmaxf(fmaxf(s[m][0][j], s[m][1][j]), fmaxf(s[m][2][j], s[m][3][j]));
        mx = fmaxf(mx, __shfl_xor(mx, 1));
        mx = fmaxf(mx, __shfl_xor(mx, 2));
        mx = fmaxf(mx, __shfl_xor(mx, 4));
        mx = fmaxf(mx, __shfl_xor(mx, 8));
        float mnew = fmaxf(m_r[m][j], mx);
        float f = __builtin_amdgcn_exp2f((m_r[m][j] - mnew) * SC);
        m_r[m][j] = mnew;
        float psum = 0.f;
#pragma unroll
        for (int n = 0; n < 4; n++) {
          float p = __builtin_amdgcn_exp2f((s[m][n][j] - mnew) * SC);
          s[m][n][j] = p;
          psum += p;
        }
        psum += __shfl_xor(psum, 1);
        psum += __shfl_xor(psum, 2);
        psum += __shfl_xor(psum, 4);
        psum += __shfl_xor(psum, 8);
        l_r[m][j] = l_r[m][j] * f + psum;
#pragma unroll
        for (int n = 0; n < 8; n++) o[m][n][j] *= f;
      }
    }

    // ---- write P (bf16); own rows -> same-wave readback, no barrier
#pragma unroll
    for (int m = 0; m < 2; m++) {
#pragma unroll
      for (int j = 0; j < 4; j++) {
        int row = w * 32 + m * 16 + (lane >> 4) * 4 + j;
        int swz = row & 7;
#pragma unroll
        for (int n = 0; n < 4; n++) {
          int col = (lane & 15) + 16 * n;
          *(unsigned short*)((char*)Ps + row * 128 + (((col >> 3) ^ swz) << 4) + (col & 7) * 2) =
              f2bf(s[m][n][j]);
        }
      }
    }

    // ---- O += P V  (bv reused across m)
#pragma unroll
    for (int ks = 0; ks < 2; ks++) {
      bf16x8 ap[2];
#pragma unroll
      for (int m = 0; m < 2; m++) {
        int arow = w * 32 + m * 16 + frow;
        ap[m] = *(const bf16x8*)((char*)Ps + arow * 128 + (((ks * 4 + fk) ^ (arow & 7)) << 4));
      }
#pragma unroll
      for (int n = 0; n < 8; n++) {
        int vrow = n * 16 + frow;
        bf16x8 bv = *(const bf16x8*)((char*)&Vs[cur][0] + vrow * 128 + (((ks * 4 + fk) ^ (vrow & 7)) << 4));
#pragma unroll
        for (int m = 0; m < 2; m++)
          o[m][n] = __builtin_amdgcn_mfma_f32_16x16x32_bf16(ap[m], bv, o[m][n], 0, 0, 0);
      }
    }

    // ---- late V ds_write for next tile (vmcnt waited here, after compute)
    if (have_next) {
#pragma unroll
      for (int dd = 0; dd < 4; dd++) {
        int row = vdb + dd;
        u16x8 pk;
#pragma unroll
        for (int i = 0; i < 8; i++) pk[i] = vr[i][dd];
        *(u16x8*)((char*)&Vs[cur ^ 1][0] + row * 128 + (((tid & 7) ^ (row & 7)) << 4)) = pk;
      }
    }
  }

  // ---- epilogue
  const bool evenlane = (lane & 1) == 0;
#pragma unroll
  for (int m = 0; m < 2; m++) {
    float inv[4];
#pragma unroll
    for (int j = 0; j < 4; j++) inv[j] = 1.0f / l_r[m][j];
#pragma unroll
    for (int n = 0; n < 8; n += 2) {
#pragma unroll
      for (int j = 0; j < 4; j++) {
        float v0 = o[m][n][j] * inv[j], v1 = o[m][n + 1][j] * inv[j];
        float p0 = __shfl_xor(v0, 1);
        float p1 = __shfl_xor(v1, 1);
        int tq = qtile * 128 + w * 32 + m * 16 + (lane >> 4) * 4 + j;
        int col = evenlane ? (n * 16 + (lane & 15)) : ((n + 1) * 16 + (lane & 15) - 1);
        unsigned int wv = evenlane ? pack2(v0, p0) : pack2(p1, v1);
        *(unsigned int*)(attout + (size_t)(b * 2048 + tq) * 2048 + h * 128 + col) = wv;
      }
    }
  }
}

// ---------------------------------------------------------------------------
// Fallback kernel 3 (round-1): output projection with in-kernel fp32 W pack.
// ---------------------------------------------------------------------------
__global__ __launch_bounds__(256) void out_gemm(
    const unsigned short* __restrict__ Ab, const float* __restrict__ W,
    const float* __restrict__ bias, float* __restrict__ Out)
{
  __shared__ unsigned short As[128 * 32];
  __shared__ unsigned short Bs[128 * 32];

  const int tid = threadIdx.x;
  const int lane = tid & 63;
  const int wave = tid >> 6;
  const int wm = wave >> 1, wn = wave & 1;
  const int bm = blockIdx.x >> 4, bn = blockIdx.x & 15;

  const int srow = tid >> 1;
  const int shalf = tid & 1;
  const unsigned short* Ap = Ab + (size_t)(bm * 128 + srow) * 2048 + shalf * 16;
  const float* Wp = W + (size_t)(bn * 128 + srow) * 2048 + shalf * 16;
  const int ssw = (srow >> 1) & 3;
  const int aoff0 = srow * 32 + (((shalf * 2 + 0) ^ ssw) << 3);
  const int aoff1 = srow * 32 + (((shalf * 2 + 1) ^ ssw) << 3);

  const int frow = lane & 15;
  const int fk = lane >> 4;

  f32x4 acc[4][4];
#pragma unroll
  for (int m = 0; m < 4; m++)
#pragma unroll
    for (int n = 0; n < 4; n++) acc[m][n] = (f32x4)(0.0f);

  for (int kk = 0; kk < 2048; kk += 32) {
    u32x4 a0 = *(const u32x4*)(Ap + kk);
    u32x4 a1 = *(const u32x4*)(Ap + kk + 8);
    f32x4 b0 = *(const f32x4*)(Wp + kk);
    f32x4 b1 = *(const f32x4*)(Wp + kk + 4);
    f32x4 b2 = *(const f32x4*)(Wp + kk + 8);
    f32x4 b3 = *(const f32x4*)(Wp + kk + 12);
    __syncthreads();
    *(u32x4*)(As + aoff0) = a0;
    *(u32x4*)(As + aoff1) = a1;
    *(u32x4*)(Bs + aoff0) = pack8(b0, b1);
    *(u32x4*)(Bs + aoff1) = pack8(b2, b3);
    __syncthreads();
    bf16x8 af[4], bfr[4];
#pragma unroll
    for (int m = 0; m < 4; m++) {
      int r = wm * 64 + m * 16 + frow;
      af[m] = *(const bf16x8*)(As + r * 32 + ((fk ^ ((r >> 1) & 3)) << 3));
    }
#pragma unroll
    for (int n = 0; n < 4; n++) {
      int r = wn * 64 + n * 16 + frow;
      bfr[n] = *(const bf16x8*)(Bs + r * 32 + ((fk ^ ((r >> 1) & 3)) << 3));
    }
#pragma unroll
    for (int m = 0; m < 4; m++)
#pragma unroll
      for (int n = 0; n < 4; n++)
        acc[m][n] = __builtin_amdgcn_mfma_f32_16x16x32_bf16(af[m], bfr[n], acc[m][n], 0, 0, 0);
  }

  float bv[4];
#pragma unroll
  for (int n = 0; n < 4; n++) bv[n] = bias[bn * 128 + wn * 64 + n * 16 + (lane & 15)];
  const bool evenlane = (lane & 1) == 0;
#pragma unroll
  for (int m = 0; m < 4; m++) {
    int rowg = bm * 128 + wm * 64 + m * 16 + (lane >> 4) * 4;
#pragma unroll
    for (int n = 0; n < 4; n += 2) {
#pragma unroll
      for (int j = 0; j < 4; j++) {
        float v0 = acc[m][n][j] + bv[n];
        float v1 = acc[m][n + 1][j] + bv[n + 1];
        float p0 = __shfl_xor(v0, 1);
        float p1 = __shfl_xor(v1, 1);
        int row = rowg + j;
        int colbase = bn * 128 + wn * 64;
        int col = evenlane ? (colbase + n * 16 + (lane & 15))
                           : (colbase + (n + 1) * 16 + (lane & 15) - 1);
        f32x2 wv;
        if (evenlane) { wv[0] = v0; wv[1] = p0; }
        else          { wv[0] = p1; wv[1] = v1; }
        *(f32x2*)(Out + (size_t)row * 2048 + col) = wv;
      }
    }
  }
}

// ---------------------------------------------------------------------------
extern "C" void kernel_launch(void* const* d_in, const int* in_sizes, int n_in,
                              void* d_out, int out_size, void* d_ws, size_t ws_size,
                              hipStream_t stream)
{
  // setup_inputs order: k, q, v, Wk, Wq, Wv, Wo, bo
  const float* k  = (const float*)d_in[0];
  const float* q  = (const float*)d_in[1];
  const float* v  = (const float*)d_in[2];
  const float* Wk = (const float*)d_in[3];
  const float* Wq = (const float*)d_in[4];
  const float* Wv = (const float*)d_in[5];
  const float* Wo = (const float*)d_in[6];
  const float* bo = (const float*)d_in[7];
  float* out = (float*)d_out;

  const size_t HSZ = (size_t)4 * 16 * 2048 * 128;   // 16,777,216 elems = 32 MiB

  if (ws_size >= (size_t)224 << 20) {
    // Fast path: Abf[0,96MiB) | Wbf[96,128) | Qw/Kw/Vw[128,224). attout reuses Abf.
    unsigned short* Abf = (unsigned short*)d_ws;
    unsigned short* Wbf = Abf + 3 * HSZ;
    unsigned short* Qw  = Wbf + 4 * 4194304;
    unsigned short* Kw  = Qw + HSZ;
    unsigned short* Vw  = Kw + HSZ;
    unsigned short* Aw  = Abf;

    convA<<<dim3(8192, 1, 3), 256, 0, stream>>>(q, k, v, Abf);
    convW<<<dim3(2048, 1, 4), 256, 0, stream>>>(Wq, Wk, Wv, Wo, Wbf);
    qkv_gemm_bf<<<dim3(1024, 1, 3), 256, 0, stream>>>(Abf, Wbf, Qw, Kw, Vw);
    attn<<<dim3(1024), 256, 0, stream>>>(Qw, Kw, Vw, Aw);
    out_gemm_bf<<<dim3(1024), 256, 0, stream>>>(Aw, Wbf + 3 * 4194304, bo, out);
  } else {
    // Fallback (128 MiB)
    unsigned short* Qw = (unsigned short*)d_ws;
    unsigned short* Kw = Qw + HSZ;
    unsigned short* Vw = Kw + HSZ;
    unsigned short* Aw = Vw + HSZ;
    qkv_gemm<<<dim3(1024, 1, 3), 256, 0, stream>>>(q, k, v, Wq, Wk, Wv, Qw, Kw, Vw);
    attn<<<dim3(1024), 256, 0, stream>>>(Qw, Kw, Vw, Aw);
    out_gemm<<<dim3(1024), 256, 0, stream>>>(Aw, Wo, bo, out);
  }
}

// Round 4
// 683.420 us; speedup vs baseline: 1.8901x; 1.1967x over previous
//
#include <hip/hip_runtime.h>

// MHA: out = softmax((qWq^T)(kWk^T)^T/sqrt(128)) (vWv^T) Wo^T + bo
// B=4 T=2048 E=2048 H=16 D=128. All GEMMs via bf16 MFMA (fp32 accum).

typedef __attribute__((ext_vector_type(4))) float f32x4;
typedef __attribute__((ext_vector_type(2))) float f32x2;
typedef __attribute__((ext_vector_type(8))) __bf16 bf16x8;
typedef __attribute__((ext_vector_type(4))) unsigned int u32x4;
typedef __attribute__((ext_vector_type(8))) unsigned short u16x8;
typedef __attribute__((ext_vector_type(4))) unsigned short u16x4;

#define DEVI static __device__ __forceinline__

DEVI unsigned short f2bf(float f) {            // RNE fp32 -> bf16
  union { float f; unsigned u; } x; x.f = f;
  unsigned u = x.u;
  return (unsigned short)((u + 0x7fffu + ((u >> 16) & 1u)) >> 16);
}
DEVI unsigned int pack2(float lo, float hi) {
  return (unsigned int)f2bf(lo) | ((unsigned int)f2bf(hi) << 16);
}
DEVI u32x4 pack8(const f32x4 a, const f32x4 b) {
  u32x4 r;
  r[0] = pack2(a[0], a[1]); r[1] = pack2(a[2], a[3]);
  r[2] = pack2(b[0], b[1]); r[3] = pack2(b[2], b[3]);
  return r;
}
DEVI void gload16(const unsigned short* g, unsigned short* l) {
  __builtin_amdgcn_global_load_lds(
      (const __attribute__((address_space(1))) unsigned int*)g,
      (__attribute__((address_space(3))) unsigned int*)l, 16, 0, 0);
}

// DPP cross-lane (VALU-rate, within 16-lane row) — avoids ds_bpermute shfl.
template <int CTRL> DEVI float dppf(float x) {
  return __builtin_bit_cast(float, __builtin_amdgcn_update_dpp(
      __builtin_bit_cast(int, x), __builtin_bit_cast(int, x), CTRL, 0xF, 0xF, true));
}
DEVI float rowmax16(float x) {   // row_ror:1,2,4,8 fold -> all 16 lanes get max
  x = fmaxf(x, dppf<0x121>(x));
  x = fmaxf(x, dppf<0x122>(x));
  x = fmaxf(x, dppf<0x124>(x));
  x = fmaxf(x, dppf<0x128>(x));
  return x;
}
DEVI float rowsum16(float x) {
  x += dppf<0x121>(x);
  x += dppf<0x122>(x);
  x += dppf<0x124>(x);
  x += dppf<0x128>(x);
  return x;
}

// ---------------------------------------------------------------------------
// fp32 -> bf16 convert passes
// ---------------------------------------------------------------------------
__global__ __launch_bounds__(256) void convA(
    const float* __restrict__ q, const float* __restrict__ k,
    const float* __restrict__ v, unsigned short* __restrict__ dst)
{
  const int z = blockIdx.z;
  const float* src = z == 0 ? q : (z == 1 ? k : v);
  unsigned short* d = dst + (size_t)z * 16777216;
  size_t i = ((size_t)blockIdx.x * 256 + threadIdx.x) * 8;
  f32x4 a = *(const f32x4*)(src + i);
  f32x4 b = *(const f32x4*)(src + i + 4);
  *(u32x4*)(d + i) = pack8(a, b);
}

__global__ __launch_bounds__(256) void convW(
    const float* __restrict__ w0, const float* __restrict__ w1,
    const float* __restrict__ w2, const float* __restrict__ w3,
    unsigned short* __restrict__ dst)
{
  const int z = blockIdx.z;
  const float* src = z == 0 ? w0 : (z == 1 ? w1 : (z == 2 ? w2 : w3));
  unsigned short* d = dst + (size_t)z * 4194304;
  size_t i = ((size_t)blockIdx.x * 256 + threadIdx.x) * 8;
  f32x4 a = *(const f32x4*)(src + i);
  f32x4 b = *(const f32x4*)(src + i + 4);
  *(u32x4*)(d + i) = pack8(a, b);
}

// ---------------------------------------------------------------------------
// Shared bf16 GEMM mainloop (m97 structure): 128x128 tile, BK=32, 4 waves 2x2.
// ---------------------------------------------------------------------------
DEVI void gemm128_bf16(const unsigned short* __restrict__ A,
                       const unsigned short* __restrict__ Bm,
                       unsigned short* As, unsigned short* Bs,
                       int bm, int bn, int tid, f32x4 (&acc)[4][4])
{
  const int lane = tid & 63, wave = tid >> 6;
  const int c = lane & 3;
  const int r0 = (wave * 2 + 0) * 16 + (lane >> 2);
  const int r1 = (wave * 2 + 1) * 16 + (lane >> 2);
  const unsigned short* Ap0 = A + (size_t)(bm * 128 + r0) * 2048 + ((c ^ ((r0 >> 1) & 3)) << 3);
  const unsigned short* Ap1 = A + (size_t)(bm * 128 + r1) * 2048 + ((c ^ ((r1 >> 1) & 3)) << 3);
  const unsigned short* Bp0 = Bm + (size_t)(bn * 128 + r0) * 2048 + ((c ^ ((r0 >> 1) & 3)) << 3);
  const unsigned short* Bp1 = Bm + (size_t)(bn * 128 + r1) * 2048 + ((c ^ ((r1 >> 1) & 3)) << 3);
  unsigned short* Asl0 = As + (wave * 2 + 0) * 512;
  unsigned short* Asl1 = As + (wave * 2 + 1) * 512;
  unsigned short* Bsl0 = Bs + (wave * 2 + 0) * 512;
  unsigned short* Bsl1 = Bs + (wave * 2 + 1) * 512;

  const int wm = wave >> 1, wn = wave & 1;
  const int frow = lane & 15, fk = lane >> 4;
  int aoff[4], boff[4];
#pragma unroll
  for (int m = 0; m < 4; m++) {
    int ra = wm * 64 + m * 16 + frow;
    aoff[m] = ra * 32 + ((fk ^ ((ra >> 1) & 3)) << 3);
    int rb = wn * 64 + m * 16 + frow;
    boff[m] = rb * 32 + ((fk ^ ((rb >> 1) & 3)) << 3);
  }

  for (int kk = 0; kk < 2048; kk += 32) {
    __syncthreads();
    gload16(Ap0 + kk, Asl0);
    gload16(Ap1 + kk, Asl1);
    gload16(Bp0 + kk, Bsl0);
    gload16(Bp1 + kk, Bsl1);
    __syncthreads();
    bf16x8 af[4], bfv[4];
#pragma unroll
    for (int m = 0; m < 4; m++) af[m] = *(const bf16x8*)(As + aoff[m]);
#pragma unroll
    for (int n = 0; n < 4; n++) bfv[n] = *(const bf16x8*)(Bs + boff[n]);
#pragma unroll
    for (int m = 0; m < 4; m++)
#pragma unroll
      for (int n = 0; n < 4; n++)
        acc[m][n] = __builtin_amdgcn_mfma_f32_16x16x32_bf16(af[m], bfv[n], acc[m][n], 0, 0, 0);
  }
}

// ---------------------------------------------------------------------------
// Kernel 1: QKV projection from pre-converted bf16. Output [B,H,T,D] bf16.
// ---------------------------------------------------------------------------
__global__ __launch_bounds__(256) void qkv_gemm_bf(
    const unsigned short* __restrict__ Abf, const unsigned short* __restrict__ Wbf,
    unsigned short* __restrict__ O0, unsigned short* __restrict__ O1,
    unsigned short* __restrict__ O2)
{
  __shared__ unsigned short As[128 * 32];
  __shared__ unsigned short Bs[128 * 32];
  const int z = blockIdx.z;
  const unsigned short* A = Abf + (size_t)z * 16777216;
  const unsigned short* W = Wbf + (size_t)z * 4194304;
  unsigned short* O = z == 0 ? O0 : (z == 1 ? O1 : O2);

  const int tid = threadIdx.x;
  const int lane = tid & 63, wave = tid >> 6;
  const int wm = wave >> 1, wn = wave & 1;
  const int bm = blockIdx.x >> 4, bn = blockIdx.x & 15;

  f32x4 acc[4][4];
#pragma unroll
  for (int m = 0; m < 4; m++)
#pragma unroll
    for (int n = 0; n < 4; n++) acc[m][n] = (f32x4)(0.0f);

  gemm128_bf16(A, W, As, Bs, bm, bn, tid, acc);

  const bool evenlane = (lane & 1) == 0;
#pragma unroll
  for (int m = 0; m < 4; m++) {
    int rowg = bm * 128 + wm * 64 + m * 16 + (lane >> 4) * 4;
#pragma unroll
    for (int n = 0; n < 4; n += 2) {
#pragma unroll
      for (int j = 0; j < 4; j++) {
        float v0 = acc[m][n][j], v1 = acc[m][n + 1][j];
        float p0 = __shfl_xor(v0, 1);
        float p1 = __shfl_xor(v1, 1);
        int row = rowg + j;
        int b = row >> 11, t = row & 2047;
        int colbase = bn * 128 + wn * 64;
        int col = evenlane ? (colbase + n * 16 + (lane & 15))
                           : (colbase + (n + 1) * 16 + (lane & 15) - 1);
        unsigned int wv = evenlane ? pack2(v0, p0) : pack2(p1, v1);
        int h = col >> 7, d = col & 127;
        *(unsigned int*)(O + (((size_t)(b * 16 + h) * 2048 + t) << 7) + d) = wv;
      }
    }
  }
}

// ---------------------------------------------------------------------------
// Kernel 3: output projection from bf16 attout + bf16 Wo. fp32 out + bias.
// ---------------------------------------------------------------------------
__global__ __launch_bounds__(256) void out_gemm_bf(
    const unsigned short* __restrict__ Ab, const unsigned short* __restrict__ Wb,
    const float* __restrict__ bias, float* __restrict__ Out)
{
  __shared__ unsigned short As[128 * 32];
  __shared__ unsigned short Bs[128 * 32];
  const int tid = threadIdx.x;
  const int lane = tid & 63, wave = tid >> 6;
  const int wm = wave >> 1, wn = wave & 1;
  const int bm = blockIdx.x >> 4, bn = blockIdx.x & 15;

  f32x4 acc[4][4];
#pragma unroll
  for (int m = 0; m < 4; m++)
#pragma unroll
    for (int n = 0; n < 4; n++) acc[m][n] = (f32x4)(0.0f);

  gemm128_bf16(Ab, Wb, As, Bs, bm, bn, tid, acc);

  float bv[4];
#pragma unroll
  for (int n = 0; n < 4; n++) bv[n] = bias[bn * 128 + wn * 64 + n * 16 + (lane & 15)];
  const bool evenlane = (lane & 1) == 0;
#pragma unroll
  for (int m = 0; m < 4; m++) {
    int rowg = bm * 128 + wm * 64 + m * 16 + (lane >> 4) * 4;
#pragma unroll
    for (int n = 0; n < 4; n += 2) {
#pragma unroll
      for (int j = 0; j < 4; j++) {
        float v0 = acc[m][n][j] + bv[n];
        float v1 = acc[m][n + 1][j] + bv[n + 1];
        float p0 = __shfl_xor(v0, 1);
        float p1 = __shfl_xor(v1, 1);
        int row = rowg + j;
        int colbase = bn * 128 + wn * 64;
        int col = evenlane ? (colbase + n * 16 + (lane & 15))
                           : (colbase + (n + 1) * 16 + (lane & 15) - 1);
        f32x2 wv;
        if (evenlane) { wv[0] = v0; wv[1] = p0; }
        else          { wv[0] = p1; wv[1] = v1; }
        *(f32x2*)(Out + (size_t)row * 2048 + col) = wv;
      }
    }
  }
}

// ---------------------------------------------------------------------------
// Fallback kernel 1 (round-1): fused QKV projection with in-kernel fp32->bf16.
// ---------------------------------------------------------------------------
__global__ __launch_bounds__(256) void qkv_gemm(
    const float* __restrict__ A0, const float* __restrict__ A1, const float* __restrict__ A2,
    const float* __restrict__ W0, const float* __restrict__ W1, const float* __restrict__ W2,
    unsigned short* __restrict__ O0, unsigned short* __restrict__ O1, unsigned short* __restrict__ O2)
{
  __shared__ unsigned short As[128 * 32];
  __shared__ unsigned short Bs[128 * 32];
  const int z = blockIdx.z;
  const float* A = z == 0 ? A0 : (z == 1 ? A1 : A2);
  const float* W = z == 0 ? W0 : (z == 1 ? W1 : W2);
  unsigned short* O = z == 0 ? O0 : (z == 1 ? O1 : O2);

  const int tid = threadIdx.x;
  const int lane = tid & 63;
  const int wave = tid >> 6;
  const int wm = wave >> 1, wn = wave & 1;
  const int bm = blockIdx.x >> 4, bn = blockIdx.x & 15;

  const int srow = tid >> 1;
  const int shalf = tid & 1;
  const float* Ap = A + (size_t)(bm * 128 + srow) * 2048 + shalf * 16;
  const float* Wp = W + (size_t)(bn * 128 + srow) * 2048 + shalf * 16;
  const int ssw = (srow >> 1) & 3;
  const int aoff0 = srow * 32 + (((shalf * 2 + 0) ^ ssw) << 3);
  const int aoff1 = srow * 32 + (((shalf * 2 + 1) ^ ssw) << 3);

  const int frow = lane & 15;
  const int fk = lane >> 4;

  f32x4 acc[4][4];
#pragma unroll
  for (int m = 0; m < 4; m++)
#pragma unroll
    for (int n = 0; n < 4; n++) acc[m][n] = (f32x4)(0.0f);

  for (int kk = 0; kk < 2048; kk += 32) {
    f32x4 a0 = *(const f32x4*)(Ap + kk);
    f32x4 a1 = *(const f32x4*)(Ap + kk + 4);
    f32x4 a2 = *(const f32x4*)(Ap + kk + 8);
    f32x4 a3 = *(const f32x4*)(Ap + kk + 12);
    f32x4 b0 = *(const f32x4*)(Wp + kk);
    f32x4 b1 = *(const f32x4*)(Wp + kk + 4);
    f32x4 b2 = *(const f32x4*)(Wp + kk + 8);
    f32x4 b3 = *(const f32x4*)(Wp + kk + 12);
    __syncthreads();
    *(u32x4*)(As + aoff0) = pack8(a0, a1);
    *(u32x4*)(As + aoff1) = pack8(a2, a3);
    *(u32x4*)(Bs + aoff0) = pack8(b0, b1);
    *(u32x4*)(Bs + aoff1) = pack8(b2, b3);
    __syncthreads();
    bf16x8 af[4], bfr[4];
#pragma unroll
    for (int m = 0; m < 4; m++) {
      int r = wm * 64 + m * 16 + frow;
      af[m] = *(const bf16x8*)(As + r * 32 + ((fk ^ ((r >> 1) & 3)) << 3));
    }
#pragma unroll
    for (int n = 0; n < 4; n++) {
      int r = wn * 64 + n * 16 + frow;
      bfr[n] = *(const bf16x8*)(Bs + r * 32 + ((fk ^ ((r >> 1) & 3)) << 3));
    }
#pragma unroll
    for (int m = 0; m < 4; m++)
#pragma unroll
      for (int n = 0; n < 4; n++)
        acc[m][n] = __builtin_amdgcn_mfma_f32_16x16x32_bf16(af[m], bfr[n], acc[m][n], 0, 0, 0);
  }

  const bool evenlane = (lane & 1) == 0;
#pragma unroll
  for (int m = 0; m < 4; m++) {
    int rowg = bm * 128 + wm * 64 + m * 16 + (lane >> 4) * 4;
#pragma unroll
    for (int n = 0; n < 4; n += 2) {
#pragma unroll
      for (int j = 0; j < 4; j++) {
        float v0 = acc[m][n][j], v1 = acc[m][n + 1][j];
        float p0 = __shfl_xor(v0, 1);
        float p1 = __shfl_xor(v1, 1);
        int row = rowg + j;
        int b = row >> 11, t = row & 2047;
        int colbase = bn * 128 + wn * 64;
        int col = evenlane ? (colbase + n * 16 + (lane & 15))
                           : (colbase + (n + 1) * 16 + (lane & 15) - 1);
        unsigned int wv = evenlane ? pack2(v0, p0) : pack2(p1, v1);
        int h = col >> 7, d = col & 127;
        *(unsigned int*)(O + (((size_t)(b * 16 + h) * 2048 + t) << 7) + d) = wv;
      }
    }
  }
}

// ---------------------------------------------------------------------------
// Kernel 2: flash attention v3. 64 (b,h) x 16 Q-tiles of 128 rows; 4 waves,
// wave owns 32 q-rows (M_rep=2). Q hoisted to registers. KVBLK=64, K/V LDS
// double-buffered (T14 split). DPP row-reduces (no ds_bpermute), defer-max
// (T13), setprio around MFMA (T5), bijective XCD swizzle on grid (T1).
// ---------------------------------------------------------------------------
__global__ __launch_bounds__(256, 2) void attn(
    const unsigned short* __restrict__ Qw, const unsigned short* __restrict__ Kw,
    const unsigned short* __restrict__ Vw, unsigned short* __restrict__ attout)
{
  __shared__ unsigned short Ks[2][64 * 128];   // [key][d], 16-byte slot swizzle s^(row&15)
  __shared__ unsigned short Vs[2][128 * 64];   // V^T [d][key], slot swizzle s^(row&7)
  __shared__ unsigned short Ps[128 * 64];      // P [q][key], slot swizzle s^(row&7)

  // XCD-aware bijective swizzle: 1024 blocks = 8 XCDs x 128; co-XCD blocks
  // get contiguous work -> same bh's K/V stays in that XCD's L2.
  const int bid = blockIdx.x;
  const int work = ((bid & 7) << 7) | (bid >> 3);
  const int bh = work >> 4;
  const int qtile = work & 15;
  const int b = bh >> 4, h = bh & 15;
  const unsigned short* Qbase = Qw + (size_t)bh * 2048 * 128 + qtile * 128 * 128;
  const unsigned short* Kbase = Kw + (size_t)bh * 2048 * 128;
  const unsigned short* Vbase = Vw + (size_t)bh * 2048 * 128;
  const int tid = threadIdx.x, lane = tid & 63, w = tid >> 6;
  const int frow = lane & 15, fk = lane >> 4;

  // ---- Q hoist: 2 m-frags x 4 ks-frags in registers (loaded once)
  bf16x8 qf[2][4];
#pragma unroll
  for (int m = 0; m < 2; m++)
#pragma unroll
    for (int ks = 0; ks < 4; ks++)
      qf[m][ks] = *(const bf16x8*)(Qbase + (size_t)(w * 32 + m * 16 + frow) * 128 + ks * 32 + fk * 8);

  // staging geometry
  const int krow_i = lane >> 4;     // K: row-in-issue 0..3
  const int kslot = lane & 15;      // K: 16B slot 0..15
  const int vkb = (tid & 7) * 8;    // V: this thread's 8 keys
  const int vdb = (tid >> 3) * 4;   // V: this thread's 4 d-cols

  f32x4 o[2][8];
#pragma unroll
  for (int m = 0; m < 2; m++)
#pragma unroll
    for (int n = 0; n < 8; n++) o[m][n] = (f32x4)(0.0f);
  float m_r[2][4], l_r[2][4];
#pragma unroll
  for (int m = 0; m < 2; m++)
#pragma unroll
    for (int j = 0; j < 4; j++) { m_r[m][j] = -INFINITY; l_r[m][j] = 0.f; }
  const float SC = 0.12751721769f;   // log2(e)/sqrt(128)
  const float THR = 90.5f;           // 8 ln-units in s-space: P <= 2^11.5

  // ---- prologue: stage tile 0 into buffer 0
  {
#pragma unroll
    for (int i = 0; i < 4; i++) {
      int row = w * 16 + i * 4 + krow_i;
      gload16(Kbase + (size_t)row * 128 + ((kslot ^ (row & 15)) << 3),
              &Ks[0][(w * 16 + i * 4) * 128]);
    }
    u16x4 vr[8];
#pragma unroll
    for (int i = 0; i < 8; i++) vr[i] = *(const u16x4*)(Vbase + (size_t)(vkb + i) * 128 + vdb);
#pragma unroll
    for (int dd = 0; dd < 4; dd++) {
      int row = vdb + dd;
      u16x8 pk;
#pragma unroll
      for (int i = 0; i < 8; i++) pk[i] = vr[i][dd];
      *(u16x8*)((char*)&Vs[0][0] + row * 128 + (((tid & 7) ^ (row & 7)) << 4)) = pk;
    }
  }

  for (int kt = 0; kt < 32; kt++) {
    const int cur = kt & 1;
    __syncthreads();   // buf[cur] staged (barrier drains vmcnt+lgkm); buf[cur^1] reads done

    // ---- T14: issue next tile's loads now, write V to LDS after compute
    u16x4 vr[8];
    const bool have_next = (kt + 1) < 32;
    if (have_next) {
      const unsigned short* Kt = Kbase + (kt + 1) * 64 * 128;
      const unsigned short* Vt = Vbase + (kt + 1) * 64 * 128;
#pragma unroll
      for (int i = 0; i < 4; i++) {
        int row = w * 16 + i * 4 + krow_i;
        gload16(Kt + (size_t)row * 128 + ((kslot ^ (row & 15)) << 3),
                &Ks[cur ^ 1][(w * 16 + i * 4) * 128]);
      }
#pragma unroll
      for (int i = 0; i < 8; i++) vr[i] = *(const u16x4*)(Vt + (size_t)(vkb + i) * 128 + vdb);
    }

    // ---- S = Q K^T (32 q-rows x 64 keys per wave); bk reused across m
    f32x4 s[2][4];
#pragma unroll
    for (int m = 0; m < 2; m++)
#pragma unroll
      for (int n = 0; n < 4; n++) s[m][n] = (f32x4)(0.0f);
    __builtin_amdgcn_s_setprio(1);
#pragma unroll
    for (int ks = 0; ks < 4; ks++) {
#pragma unroll
      for (int n = 0; n < 4; n++) {
        int brow = n * 16 + frow;
        bf16x8 bk = *(const bf16x8*)(&Ks[cur][0] + brow * 128 + (((ks * 4 + fk) ^ (brow & 15)) << 3));
#pragma unroll
        for (int m = 0; m < 2; m++)
          s[m][n] = __builtin_amdgcn_mfma_f32_16x16x32_bf16(qf[m][ks], bk, s[m][n], 0, 0, 0);
      }
    }
    __builtin_amdgcn_s_setprio(0);

    // ---- online softmax (8 rows/lane-group: 2 m x 4 j), DPP reduces + defer-max
#pragma unroll
    for (int m = 0; m < 2; m++) {
#pragma unroll
      for (int j = 0; j < 4; j++) {
        float mx = fmaxf(fmaxf(s[m][0][j], s[m][1][j]), fmaxf(s[m][2][j], s[m][3][j]));
        mx = rowmax16(mx);
        float mo = m_r[m][j];
        if (!__all(mx - mo <= THR)) {          // T13: rescale only on big max jump
          float mnew = fmaxf(mo, mx);
          float f = __builtin_amdgcn_exp2f((mo - mnew) * SC);
          m_r[m][j] = mnew;
          l_r[m][j] *= f;
#pragma unroll
          for (int n = 0; n < 8; n++) o[m][n][j] *= f;
        }
        float mm = m_r[m][j];
        float psum = 0.f;
#pragma unroll
        for (int n = 0; n < 4; n++) {
          float p = __builtin_amdgcn_exp2f((s[m][n][j] - mm) * SC);
          s[m][n][j] = p;
          psum += p;
        }
        l_r[m][j] += rowsum16(psum);
      }
    }

    // ---- write P (bf16); own rows -> same-wave readback, no barrier
#pragma unroll
    for (int m = 0; m < 2; m++) {
#pragma unroll
      for (int j = 0; j < 4; j++) {
        int row = w * 32 + m * 16 + (lane >> 4) * 4 + j;
        int swz = row & 7;
#pragma unroll
        for (int n = 0; n < 4; n++) {
          int col = (lane & 15) + 16 * n;
          *(unsigned short*)((char*)Ps + row * 128 + (((col >> 3) ^ swz) << 4) + (col & 7) * 2) =
              f2bf(s[m][n][j]);
        }
      }
    }

    // ---- O += P V  (bv reused across m)
    __builtin_amdgcn_s_setprio(1);
#pragma unroll
    for (int ks = 0; ks < 2; ks++) {
      bf16x8 ap[2];
#pragma unroll
      for (int m = 0; m < 2; m++) {
        int arow = w * 32 + m * 16 + frow;
        ap[m] = *(const bf16x8*)((char*)Ps + arow * 128 + (((ks * 4 + fk) ^ (arow & 7)) << 4));
      }
#pragma unroll
      for (int n = 0; n < 8; n++) {
        int vrow = n * 16 + frow;
        bf16x8 bv = *(const bf16x8*)((char*)&Vs[cur][0] + vrow * 128 + (((ks * 4 + fk) ^ (vrow & 7)) << 4));
#pragma unroll
        for (int m = 0; m < 2; m++)
          o[m][n] = __builtin_amdgcn_mfma_f32_16x16x32_bf16(ap[m], bv, o[m][n], 0, 0, 0);
      }
    }
    __builtin_amdgcn_s_setprio(0);

    // ---- late V ds_write for next tile (vmcnt waited here, after compute)
    if (have_next) {
#pragma unroll
      for (int dd = 0; dd < 4; dd++) {
        int row = vdb + dd;
        u16x8 pk;
#pragma unroll
        for (int i = 0; i < 8; i++) pk[i] = vr[i][dd];
        *(u16x8*)((char*)&Vs[cur ^ 1][0] + row * 128 + (((tid & 7) ^ (row & 7)) << 4)) = pk;
      }
    }
  }

  // ---- epilogue
  const bool evenlane = (lane & 1) == 0;
#pragma unroll
  for (int m = 0; m < 2; m++) {
    float inv[4];
#pragma unroll
    for (int j = 0; j < 4; j++) inv[j] = 1.0f / l_r[m][j];
#pragma unroll
    for (int n = 0; n < 8; n += 2) {
#pragma unroll
      for (int j = 0; j < 4; j++) {
        float v0 = o[m][n][j] * inv[j], v1 = o[m][n + 1][j] * inv[j];
        float p0 = __shfl_xor(v0, 1);
        float p1 = __shfl_xor(v1, 1);
        int tq = qtile * 128 + w * 32 + m * 16 + (lane >> 4) * 4 + j;
        int col = evenlane ? (n * 16 + (lane & 15)) : ((n + 1) * 16 + (lane & 15) - 1);
        unsigned int wv = evenlane ? pack2(v0, p0) : pack2(p1, v1);
        *(unsigned int*)(attout + (size_t)(b * 2048 + tq) * 2048 + h * 128 + col) = wv;
      }
    }
  }
}

// ---------------------------------------------------------------------------
// Fallback kernel 3 (round-1): output projection with in-kernel fp32 W pack.
// ---------------------------------------------------------------------------
__global__ __launch_bounds__(256) void out_gemm(
    const unsigned short* __restrict__ Ab, const float* __restrict__ W,
    const float* __restrict__ bias, float* __restrict__ Out)
{
  __shared__ unsigned short As[128 * 32];
  __shared__ unsigned short Bs[128 * 32];

  const int tid = threadIdx.x;
  const int lane = tid & 63;
  const int wave = tid >> 6;
  const int wm = wave >> 1, wn = wave & 1;
  const int bm = blockIdx.x >> 4, bn = blockIdx.x & 15;

  const int srow = tid >> 1;
  const int shalf = tid & 1;
  const unsigned short* Ap = Ab + (size_t)(bm * 128 + srow) * 2048 + shalf * 16;
  const float* Wp = W + (size_t)(bn * 128 + srow) * 2048 + shalf * 16;
  const int ssw = (srow >> 1) & 3;
  const int aoff0 = srow * 32 + (((shalf * 2 + 0) ^ ssw) << 3);
  const int aoff1 = srow * 32 + (((shalf * 2 + 1) ^ ssw) << 3);

  const int frow = lane & 15;
  const int fk = lane >> 4;

  f32x4 acc[4][4];
#pragma unroll
  for (int m = 0; m < 4; m++)
#pragma unroll
    for (int n = 0; n < 4; n++) acc[m][n] = (f32x4)(0.0f);

  for (int kk = 0; kk < 2048; kk += 32) {
    u32x4 a0 = *(const u32x4*)(Ap + kk);
    u32x4 a1 = *(const u32x4*)(Ap + kk + 8);
    f32x4 b0 = *(const f32x4*)(Wp + kk);
    f32x4 b1 = *(const f32x4*)(Wp + kk + 4);
    f32x4 b2 = *(const f32x4*)(Wp + kk + 8);
    f32x4 b3 = *(const f32x4*)(Wp + kk + 12);
    __syncthreads();
    *(u32x4*)(As + aoff0) = a0;
    *(u32x4*)(As + aoff1) = a1;
    *(u32x4*)(Bs + aoff0) = pack8(b0, b1);
    *(u32x4*)(Bs + aoff1) = pack8(b2, b3);
    __syncthreads();
    bf16x8 af[4], bfr[4];
#pragma unroll
    for (int m = 0; m < 4; m++) {
      int r = wm * 64 + m * 16 + frow;
      af[m] = *(const bf16x8*)(As + r * 32 + ((fk ^ ((r >> 1) & 3)) << 3));
    }
#pragma unroll
    for (int n = 0; n < 4; n++) {
      int r = wn * 64 + n * 16 + frow;
      bfr[n] = *(const bf16x8*)(Bs + r * 32 + ((fk ^ ((r >> 1) & 3)) << 3));
    }
#pragma unroll
    for (int m = 0; m < 4; m++)
#pragma unroll
      for (int n = 0; n < 4; n++)
        acc[m][n] = __builtin_amdgcn_mfma_f32_16x16x32_bf16(af[m], bfr[n], acc[m][n], 0, 0, 0);
  }

  float bv[4];
#pragma unroll
  for (int n = 0; n < 4; n++) bv[n] = bias[bn * 128 + wn * 64 + n * 16 + (lane & 15)];
  const bool evenlane = (lane & 1) == 0;
#pragma unroll
  for (int m = 0; m < 4; m++) {
    int rowg = bm * 128 + wm * 64 + m * 16 + (lane >> 4) * 4;
#pragma unroll
    for (int n = 0; n < 4; n += 2) {
#pragma unroll
      for (int j = 0; j < 4; j++) {
        float v0 = acc[m][n][j] + bv[n];
        float v1 = acc[m][n + 1][j] + bv[n + 1];
        float p0 = __shfl_xor(v0, 1);
        float p1 = __shfl_xor(v1, 1);
        int row = rowg + j;
        int colbase = bn * 128 + wn * 64;
        int col = evenlane ? (colbase + n * 16 + (lane & 15))
                           : (colbase + (n + 1) * 16 + (lane & 15) - 1);
        f32x2 wv;
        if (evenlane) { wv[0] = v0; wv[1] = p0; }
        else          { wv[0] = p1; wv[1] = v1; }
        *(f32x2*)(Out + (size_t)row * 2048 + col) = wv;
      }
    }
  }
}

// ---------------------------------------------------------------------------
extern "C" void kernel_launch(void* const* d_in, const int* in_sizes, int n_in,
                              void* d_out, int out_size, void* d_ws, size_t ws_size,
                              hipStream_t stream)
{
  // setup_inputs order: k, q, v, Wk, Wq, Wv, Wo, bo
  const float* k  = (const float*)d_in[0];
  const float* q  = (const float*)d_in[1];
  const float* v  = (const float*)d_in[2];
  const float* Wk = (const float*)d_in[3];
  const float* Wq = (const float*)d_in[4];
  const float* Wv = (const float*)d_in[5];
  const float* Wo = (const float*)d_in[6];
  const float* bo = (const float*)d_in[7];
  float* out = (float*)d_out;

  const size_t HSZ = (size_t)4 * 16 * 2048 * 128;   // 16,777,216 elems = 32 MiB

  if (ws_size >= (size_t)224 << 20) {
    // Fast path: Abf[0,96MiB) | Wbf[96,128) | Qw/Kw/Vw[128,224). attout reuses Abf.
    unsigned short* Abf = (unsigned short*)d_ws;
    unsigned short* Wbf = Abf + 3 * HSZ;
    unsigned short* Qw  = Wbf + 4 * 4194304;
    unsigned short* Kw  = Qw + HSZ;
    unsigned short* Vw  = Kw + HSZ;
    unsigned short* Aw  = Abf;

    convA<<<dim3(8192, 1, 3), 256, 0, stream>>>(q, k, v, Abf);
    convW<<<dim3(2048, 1, 4), 256, 0, stream>>>(Wq, Wk, Wv, Wo, Wbf);
    qkv_gemm_bf<<<dim3(1024, 1, 3), 256, 0, stream>>>(Abf, Wbf, Qw, Kw, Vw);
    attn<<<dim3(1024), 256, 0, stream>>>(Qw, Kw, Vw, Aw);
    out_gemm_bf<<<dim3(1024), 256, 0, stream>>>(Aw, Wbf + 3 * 4194304, bo, out);
  } else {
    // Fallback (128 MiB)
    unsigned short* Qw = (unsigned short*)d_ws;
    unsigned short* Kw = Qw + HSZ;
    unsigned short* Vw = Kw + HSZ;
    unsigned short* Aw = Vw + HSZ;
    qkv_gemm<<<dim3(1024, 1, 3), 256, 0, stream>>>(q, k, v, Wq, Wk, Wv, Qw, Kw, Vw);
    attn<<<dim3(1024), 256, 0, stream>>>(Qw, Kw, Vw, Aw);
    out_gemm<<<dim3(1024), 256, 0, stream>>>(Aw, Wo, bo, out);
  }
}

// Round 5
// 650.344 us; speedup vs baseline: 1.9862x; 1.0509x over previous
//
#include <hip/hip_runtime.h>

// MHA: out = softmax((qWq^T)(kWk^T)^T/sqrt(128)) (vWv^T) Wo^T + bo
// B=4 T=2048 E=2048 H=16 D=128. All GEMMs via bf16 MFMA (fp32 accum).
// GEMM mainloop: 128x128 tile, BK=64 (32 barrier-drains/block), global_load_lds
// w/ pre-swizzled source, XCD-chunked grid swizzle for L2 locality.

typedef __attribute__((ext_vector_type(4))) float f32x4;
typedef __attribute__((ext_vector_type(2))) float f32x2;
typedef __attribute__((ext_vector_type(8))) __bf16 bf16x8;
typedef __attribute__((ext_vector_type(4))) unsigned int u32x4;
typedef __attribute__((ext_vector_type(8))) unsigned short u16x8;
typedef __attribute__((ext_vector_type(4))) unsigned short u16x4;

#define DEVI static __device__ __forceinline__

DEVI unsigned short f2bf(float f) {            // RNE fp32 -> bf16
  union { float f; unsigned u; } x; x.f = f;
  unsigned u = x.u;
  return (unsigned short)((u + 0x7fffu + ((u >> 16) & 1u)) >> 16);
}
DEVI unsigned int pack2(float lo, float hi) {
  return (unsigned int)f2bf(lo) | ((unsigned int)f2bf(hi) << 16);
}
DEVI u32x4 pack8(const f32x4 a, const f32x4 b) {
  u32x4 r;
  r[0] = pack2(a[0], a[1]); r[1] = pack2(a[2], a[3]);
  r[2] = pack2(b[0], b[1]); r[3] = pack2(b[2], b[3]);
  return r;
}
DEVI void gload16(const unsigned short* g, unsigned short* l) {
  __builtin_amdgcn_global_load_lds(
      (const __attribute__((address_space(1))) unsigned int*)g,
      (__attribute__((address_space(3))) unsigned int*)l, 16, 0, 0);
}

// DPP cross-lane (VALU-rate, within 16-lane row) — avoids ds_bpermute shfl.
template <int CTRL> DEVI float dppf(float x) {
  return __builtin_bit_cast(float, __builtin_amdgcn_update_dpp(
      __builtin_bit_cast(int, x), __builtin_bit_cast(int, x), CTRL, 0xF, 0xF, true));
}
DEVI float rowmax16(float x) {   // row_ror:1,2,4,8 fold -> all 16 lanes get max
  x = fmaxf(x, dppf<0x121>(x));
  x = fmaxf(x, dppf<0x122>(x));
  x = fmaxf(x, dppf<0x124>(x));
  x = fmaxf(x, dppf<0x128>(x));
  return x;
}
DEVI float rowsum16(float x) {
  x += dppf<0x121>(x);
  x += dppf<0x122>(x);
  x += dppf<0x124>(x);
  x += dppf<0x128>(x);
  return x;
}

// ---------------------------------------------------------------------------
// fp32 -> bf16 convert passes
// ---------------------------------------------------------------------------
__global__ __launch_bounds__(256) void convA(
    const float* __restrict__ q, const float* __restrict__ k,
    const float* __restrict__ v, unsigned short* __restrict__ dst)
{
  const int z = blockIdx.z;
  const float* src = z == 0 ? q : (z == 1 ? k : v);
  unsigned short* d = dst + (size_t)z * 16777216;
  size_t i = ((size_t)blockIdx.x * 256 + threadIdx.x) * 8;
  f32x4 a = *(const f32x4*)(src + i);
  f32x4 b = *(const f32x4*)(src + i + 4);
  *(u32x4*)(d + i) = pack8(a, b);
}

__global__ __launch_bounds__(256) void convW(
    const float* __restrict__ w0, const float* __restrict__ w1,
    const float* __restrict__ w2, const float* __restrict__ w3,
    unsigned short* __restrict__ dst)
{
  const int z = blockIdx.z;
  const float* src = z == 0 ? w0 : (z == 1 ? w1 : (z == 2 ? w2 : w3));
  unsigned short* d = dst + (size_t)z * 4194304;
  size_t i = ((size_t)blockIdx.x * 256 + threadIdx.x) * 8;
  f32x4 a = *(const f32x4*)(src + i);
  f32x4 b = *(const f32x4*)(src + i + 4);
  *(u32x4*)(d + i) = pack8(a, b);
}

// ---------------------------------------------------------------------------
// Shared bf16 GEMM mainloop: 128x128 tile, BK=64, 4 waves 2x2.
// LDS tiles [128][64] linear; 16B-slot swizzle: logical chunk c of row r lives
// in slot c^(r&7). gload source pre-swizzled: lane l stages global chunk
// (l&7)^(l>>3) of row w*8+(l>>3)+i*32 -> LDS slot l&7 (involution both sides).
// ds_read_b128 per 16-lane group: 8 distinct slots x2 rows = 2-way (free).
// ---------------------------------------------------------------------------
DEVI void gemm128_bf16(const unsigned short* __restrict__ A,
                       const unsigned short* __restrict__ Bm,
                       unsigned short* As, unsigned short* Bs,
                       int bm, int bn, int tid, f32x4 (&acc)[4][4])
{
  const int lane = tid & 63, wave = tid >> 6;
  // staging: issue i covers rows i*32 + wave*8 + (lane>>3), slot lane&7
  const int srow = wave * 8 + (lane >> 3);
  const int schunk = (lane & 7) ^ (lane >> 3);       // pre-swizzled global chunk
  const unsigned short* ApG = A + (size_t)(bm * 128 + srow) * 2048 + (schunk << 3);
  const unsigned short* BpG = Bm + (size_t)(bn * 128 + srow) * 2048 + (schunk << 3);
  unsigned short* AsW = As + wave * 8 * 64;          // wave-uniform LDS bases
  unsigned short* BsW = Bs + wave * 8 * 64;

  const int wm = wave >> 1, wn = wave & 1;
  const int frow = lane & 15, fk = lane >> 4;
  int aoff[4][2], boff[4][2];
#pragma unroll
  for (int m = 0; m < 4; m++) {
#pragma unroll
    for (int ks = 0; ks < 2; ks++) {
      int ra = wm * 64 + m * 16 + frow;
      aoff[m][ks] = ra * 64 + (((ks * 4 + fk) ^ (ra & 7)) << 3);
      int rb = wn * 64 + m * 16 + frow;
      boff[m][ks] = rb * 64 + (((ks * 4 + fk) ^ (rb & 7)) << 3);
    }
  }

  for (int kk = 0; kk < 2048; kk += 64) {
    __syncthreads();                 // prior iteration's LDS reads done
#pragma unroll
    for (int i = 0; i < 4; i++) {
      gload16(ApG + kk + (size_t)(i * 32) * 2048, AsW + i * 32 * 64);
      gload16(BpG + kk + (size_t)(i * 32) * 2048, BsW + i * 32 * 64);
    }
    __syncthreads();                 // barrier drains vmcnt -> tile resident
#pragma unroll
    for (int ks = 0; ks < 2; ks++) {
      bf16x8 af[4], bfv[4];
#pragma unroll
      for (int m = 0; m < 4; m++) af[m] = *(const bf16x8*)(As + aoff[m][ks]);
#pragma unroll
      for (int n = 0; n < 4; n++) bfv[n] = *(const bf16x8*)(Bs + boff[n][ks]);
#pragma unroll
      for (int m = 0; m < 4; m++)
#pragma unroll
        for (int n = 0; n < 4; n++)
          acc[m][n] = __builtin_amdgcn_mfma_f32_16x16x32_bf16(af[m], bfv[n], acc[m][n], 0, 0, 0);
    }
  }
}

// XCD-chunked bijective swizzle for grid.x = 1024 (8 XCDs x 128 blocks).
// Consecutive post-swizzle ids share bm -> one XCD's L2 holds 8 A-panels (4MB).
DEVI int xcd_swz1024(int bid) { return ((bid & 7) << 7) | (bid >> 3); }

// ---------------------------------------------------------------------------
// Kernel 1: QKV projection from pre-converted bf16. Output [B,H,T,D] bf16.
// ---------------------------------------------------------------------------
__global__ __launch_bounds__(256) void qkv_gemm_bf(
    const unsigned short* __restrict__ Abf, const unsigned short* __restrict__ Wbf,
    unsigned short* __restrict__ O0, unsigned short* __restrict__ O1,
    unsigned short* __restrict__ O2)
{
  __shared__ unsigned short As[128 * 64];
  __shared__ unsigned short Bs[128 * 64];
  const int z = blockIdx.z;
  const unsigned short* A = Abf + (size_t)z * 16777216;
  const unsigned short* W = Wbf + (size_t)z * 4194304;
  unsigned short* O = z == 0 ? O0 : (z == 1 ? O1 : O2);

  const int tid = threadIdx.x;
  const int lane = tid & 63, wave = tid >> 6;
  const int wm = wave >> 1, wn = wave & 1;
  const int bs = xcd_swz1024(blockIdx.x);
  const int bm = bs >> 4, bn = bs & 15;

  f32x4 acc[4][4];
#pragma unroll
  for (int m = 0; m < 4; m++)
#pragma unroll
    for (int n = 0; n < 4; n++) acc[m][n] = (f32x4)(0.0f);

  gemm128_bf16(A, W, As, Bs, bm, bn, tid, acc);

  const bool evenlane = (lane & 1) == 0;
#pragma unroll
  for (int m = 0; m < 4; m++) {
    int rowg = bm * 128 + wm * 64 + m * 16 + (lane >> 4) * 4;
#pragma unroll
    for (int n = 0; n < 4; n += 2) {
#pragma unroll
      for (int j = 0; j < 4; j++) {
        float v0 = acc[m][n][j], v1 = acc[m][n + 1][j];
        float p0 = __shfl_xor(v0, 1);
        float p1 = __shfl_xor(v1, 1);
        int row = rowg + j;
        int b = row >> 11, t = row & 2047;
        int colbase = bn * 128 + wn * 64;
        int col = evenlane ? (colbase + n * 16 + (lane & 15))
                           : (colbase + (n + 1) * 16 + (lane & 15) - 1);
        unsigned int wv = evenlane ? pack2(v0, p0) : pack2(p1, v1);
        int h = col >> 7, d = col & 127;
        *(unsigned int*)(O + (((size_t)(b * 16 + h) * 2048 + t) << 7) + d) = wv;
      }
    }
  }
}

// ---------------------------------------------------------------------------
// Kernel 3: output projection from bf16 attout + bf16 Wo. fp32 out + bias.
// ---------------------------------------------------------------------------
__global__ __launch_bounds__(256) void out_gemm_bf(
    const unsigned short* __restrict__ Ab, const unsigned short* __restrict__ Wb,
    const float* __restrict__ bias, float* __restrict__ Out)
{
  __shared__ unsigned short As[128 * 64];
  __shared__ unsigned short Bs[128 * 64];
  const int tid = threadIdx.x;
  const int lane = tid & 63, wave = tid >> 6;
  const int wm = wave >> 1, wn = wave & 1;
  const int bs = xcd_swz1024(blockIdx.x);
  const int bm = bs >> 4, bn = bs & 15;

  f32x4 acc[4][4];
#pragma unroll
  for (int m = 0; m < 4; m++)
#pragma unroll
    for (int n = 0; n < 4; n++) acc[m][n] = (f32x4)(0.0f);

  gemm128_bf16(Ab, Wb, As, Bs, bm, bn, tid, acc);

  float bv[4];
#pragma unroll
  for (int n = 0; n < 4; n++) bv[n] = bias[bn * 128 + wn * 64 + n * 16 + (lane & 15)];
  const bool evenlane = (lane & 1) == 0;
#pragma unroll
  for (int m = 0; m < 4; m++) {
    int rowg = bm * 128 + wm * 64 + m * 16 + (lane >> 4) * 4;
#pragma unroll
    for (int n = 0; n < 4; n += 2) {
#pragma unroll
      for (int j = 0; j < 4; j++) {
        float v0 = acc[m][n][j] + bv[n];
        float v1 = acc[m][n + 1][j] + bv[n + 1];
        float p0 = __shfl_xor(v0, 1);
        float p1 = __shfl_xor(v1, 1);
        int row = rowg + j;
        int colbase = bn * 128 + wn * 64;
        int col = evenlane ? (colbase + n * 16 + (lane & 15))
                           : (colbase + (n + 1) * 16 + (lane & 15) - 1);
        f32x2 wv;
        if (evenlane) { wv[0] = v0; wv[1] = p0; }
        else          { wv[0] = p1; wv[1] = v1; }
        *(f32x2*)(Out + (size_t)row * 2048 + col) = wv;
      }
    }
  }
}

// ---------------------------------------------------------------------------
// Fallback kernel 1 (round-1): fused QKV projection with in-kernel fp32->bf16.
// ---------------------------------------------------------------------------
__global__ __launch_bounds__(256) void qkv_gemm(
    const float* __restrict__ A0, const float* __restrict__ A1, const float* __restrict__ A2,
    const float* __restrict__ W0, const float* __restrict__ W1, const float* __restrict__ W2,
    unsigned short* __restrict__ O0, unsigned short* __restrict__ O1, unsigned short* __restrict__ O2)
{
  __shared__ unsigned short As[128 * 32];
  __shared__ unsigned short Bs[128 * 32];
  const int z = blockIdx.z;
  const float* A = z == 0 ? A0 : (z == 1 ? A1 : A2);
  const float* W = z == 0 ? W0 : (z == 1 ? W1 : W2);
  unsigned short* O = z == 0 ? O0 : (z == 1 ? O1 : O2);

  const int tid = threadIdx.x;
  const int lane = tid & 63;
  const int wave = tid >> 6;
  const int wm = wave >> 1, wn = wave & 1;
  const int bm = blockIdx.x >> 4, bn = blockIdx.x & 15;

  const int srow = tid >> 1;
  const int shalf = tid & 1;
  const float* Ap = A + (size_t)(bm * 128 + srow) * 2048 + shalf * 16;
  const float* Wp = W + (size_t)(bn * 128 + srow) * 2048 + shalf * 16;
  const int ssw = (srow >> 1) & 3;
  const int aoff0 = srow * 32 + (((shalf * 2 + 0) ^ ssw) << 3);
  const int aoff1 = srow * 32 + (((shalf * 2 + 1) ^ ssw) << 3);

  const int frow = lane & 15;
  const int fk = lane >> 4;

  f32x4 acc[4][4];
#pragma unroll
  for (int m = 0; m < 4; m++)
#pragma unroll
    for (int n = 0; n < 4; n++) acc[m][n] = (f32x4)(0.0f);

  for (int kk = 0; kk < 2048; kk += 32) {
    f32x4 a0 = *(const f32x4*)(Ap + kk);
    f32x4 a1 = *(const f32x4*)(Ap + kk + 4);
    f32x4 a2 = *(const f32x4*)(Ap + kk + 8);
    f32x4 a3 = *(const f32x4*)(Ap + kk + 12);
    f32x4 b0 = *(const f32x4*)(Wp + kk);
    f32x4 b1 = *(const f32x4*)(Wp + kk + 4);
    f32x4 b2 = *(const f32x4*)(Wp + kk + 8);
    f32x4 b3 = *(const f32x4*)(Wp + kk + 12);
    __syncthreads();
    *(u32x4*)(As + aoff0) = pack8(a0, a1);
    *(u32x4*)(As + aoff1) = pack8(a2, a3);
    *(u32x4*)(Bs + aoff0) = pack8(b0, b1);
    *(u32x4*)(Bs + aoff1) = pack8(b2, b3);
    __syncthreads();
    bf16x8 af[4], bfr[4];
#pragma unroll
    for (int m = 0; m < 4; m++) {
      int r = wm * 64 + m * 16 + frow;
      af[m] = *(const bf16x8*)(As + r * 32 + ((fk ^ ((r >> 1) & 3)) << 3));
    }
#pragma unroll
    for (int n = 0; n < 4; n++) {
      int r = wn * 64 + n * 16 + frow;
      bfr[n] = *(const bf16x8*)(Bs + r * 32 + ((fk ^ ((r >> 1) & 3)) << 3));
    }
#pragma unroll
    for (int m = 0; m < 4; m++)
#pragma unroll
      for (int n = 0; n < 4; n++)
        acc[m][n] = __builtin_amdgcn_mfma_f32_16x16x32_bf16(af[m], bfr[n], acc[m][n], 0, 0, 0);
  }

  const bool evenlane = (lane & 1) == 0;
#pragma unroll
  for (int m = 0; m < 4; m++) {
    int rowg = bm * 128 + wm * 64 + m * 16 + (lane >> 4) * 4;
#pragma unroll
    for (int n = 0; n < 4; n += 2) {
#pragma unroll
      for (int j = 0; j < 4; j++) {
        float v0 = acc[m][n][j], v1 = acc[m][n + 1][j];
        float p0 = __shfl_xor(v0, 1);
        float p1 = __shfl_xor(v1, 1);
        int row = rowg + j;
        int b = row >> 11, t = row & 2047;
        int colbase = bn * 128 + wn * 64;
        int col = evenlane ? (colbase + n * 16 + (lane & 15))
                           : (colbase + (n + 1) * 16 + (lane & 15) - 1);
        unsigned int wv = evenlane ? pack2(v0, p0) : pack2(p1, v1);
        int h = col >> 7, d = col & 127;
        *(unsigned int*)(O + (((size_t)(b * 16 + h) * 2048 + t) << 7) + d) = wv;
      }
    }
  }
}

// ---------------------------------------------------------------------------
// Kernel 2: flash attention v3 (round-4, unchanged). 64 (b,h) x 16 Q-tiles of
// 128 rows; 4 waves, wave owns 32 q-rows. Q in regs, K/V LDS dbuf (T14),
// DPP reduces, defer-max (T13), setprio (T5), XCD swizzle (T1).
// ---------------------------------------------------------------------------
__global__ __launch_bounds__(256, 2) void attn(
    const unsigned short* __restrict__ Qw, const unsigned short* __restrict__ Kw,
    const unsigned short* __restrict__ Vw, unsigned short* __restrict__ attout)
{
  __shared__ unsigned short Ks[2][64 * 128];   // [key][d], 16-byte slot swizzle s^(row&15)
  __shared__ unsigned short Vs[2][128 * 64];   // V^T [d][key], slot swizzle s^(row&7)
  __shared__ unsigned short Ps[128 * 64];      // P [q][key], slot swizzle s^(row&7)

  const int bid = blockIdx.x;
  const int work = ((bid & 7) << 7) | (bid >> 3);
  const int bh = work >> 4;
  const int qtile = work & 15;
  const int b = bh >> 4, h = bh & 15;
  const unsigned short* Qbase = Qw + (size_t)bh * 2048 * 128 + qtile * 128 * 128;
  const unsigned short* Kbase = Kw + (size_t)bh * 2048 * 128;
  const unsigned short* Vbase = Vw + (size_t)bh * 2048 * 128;
  const int tid = threadIdx.x, lane = tid & 63, w = tid >> 6;
  const int frow = lane & 15, fk = lane >> 4;

  bf16x8 qf[2][4];
#pragma unroll
  for (int m = 0; m < 2; m++)
#pragma unroll
    for (int ks = 0; ks < 4; ks++)
      qf[m][ks] = *(const bf16x8*)(Qbase + (size_t)(w * 32 + m * 16 + frow) * 128 + ks * 32 + fk * 8);

  const int krow_i = lane >> 4;
  const int kslot = lane & 15;
  const int vkb = (tid & 7) * 8;
  const int vdb = (tid >> 3) * 4;

  f32x4 o[2][8];
#pragma unroll
  for (int m = 0; m < 2; m++)
#pragma unroll
    for (int n = 0; n < 8; n++) o[m][n] = (f32x4)(0.0f);
  float m_r[2][4], l_r[2][4];
#pragma unroll
  for (int m = 0; m < 2; m++)
#pragma unroll
    for (int j = 0; j < 4; j++) { m_r[m][j] = -INFINITY; l_r[m][j] = 0.f; }
  const float SC = 0.12751721769f;   // log2(e)/sqrt(128)
  const float THR = 90.5f;           // 8 ln-units in s-space: P <= 2^11.5

  {
#pragma unroll
    for (int i = 0; i < 4; i++) {
      int row = w * 16 + i * 4 + krow_i;
      gload16(Kbase + (size_t)row * 128 + ((kslot ^ (row & 15)) << 3),
              &Ks[0][(w * 16 + i * 4) * 128]);
    }
    u16x4 vr[8];
#pragma unroll
    for (int i = 0; i < 8; i++) vr[i] = *(const u16x4*)(Vbase + (size_t)(vkb + i) * 128 + vdb);
#pragma unroll
    for (int dd = 0; dd < 4; dd++) {
      int row = vdb + dd;
      u16x8 pk;
#pragma unroll
      for (int i = 0; i < 8; i++) pk[i] = vr[i][dd];
      *(u16x8*)((char*)&Vs[0][0] + row * 128 + (((tid & 7) ^ (row & 7)) << 4)) = pk;
    }
  }

  for (int kt = 0; kt < 32; kt++) {
    const int cur = kt & 1;
    __syncthreads();

    u16x4 vr[8];
    const bool have_next = (kt + 1) < 32;
    if (have_next) {
      const unsigned short* Kt = Kbase + (kt + 1) * 64 * 128;
      const unsigned short* Vt = Vbase + (kt + 1) * 64 * 128;
#pragma unroll
      for (int i = 0; i < 4; i++) {
        int row = w * 16 + i * 4 + krow_i;
        gload16(Kt + (size_t)row * 128 + ((kslot ^ (row & 15)) << 3),
                &Ks[cur ^ 1][(w * 16 + i * 4) * 128]);
      }
#pragma unroll
      for (int i = 0; i < 8; i++) vr[i] = *(const u16x4*)(Vt + (size_t)(vkb + i) * 128 + vdb);
    }

    f32x4 s[2][4];
#pragma unroll
    for (int m = 0; m < 2; m++)
#pragma unroll
      for (int n = 0; n < 4; n++) s[m][n] = (f32x4)(0.0f);
    __builtin_amdgcn_s_setprio(1);
#pragma unroll
    for (int ks = 0; ks < 4; ks++) {
#pragma unroll
      for (int n = 0; n < 4; n++) {
        int brow = n * 16 + frow;
        bf16x8 bk = *(const bf16x8*)(&Ks[cur][0] + brow * 128 + (((ks * 4 + fk) ^ (brow & 15)) << 3));
#pragma unroll
        for (int m = 0; m < 2; m++)
          s[m][n] = __builtin_amdgcn_mfma_f32_16x16x32_bf16(qf[m][ks], bk, s[m][n], 0, 0, 0);
      }
    }
    __builtin_amdgcn_s_setprio(0);

#pragma unroll
    for (int m = 0; m < 2; m++) {
#pragma unroll
      for (int j = 0; j < 4; j++) {
        float mx = fmaxf(fmaxf(s[m][0][j], s[m][1][j]), fmaxf(s[m][2][j], s[m][3][j]));
        mx = rowmax16(mx);
        float mo = m_r[m][j];
        if (!__all(mx - mo <= THR)) {
          float mnew = fmaxf(mo, mx);
          float f = __builtin_amdgcn_exp2f((mo - mnew) * SC);
          m_r[m][j] = mnew;
          l_r[m][j] *= f;
#pragma unroll
          for (int n = 0; n < 8; n++) o[m][n][j] *= f;
        }
        float mm = m_r[m][j];
        float psum = 0.f;
#pragma unroll
        for (int n = 0; n < 4; n++) {
          float p = __builtin_amdgcn_exp2f((s[m][n][j] - mm) * SC);
          s[m][n][j] = p;
          psum += p;
        }
        l_r[m][j] += rowsum16(psum);
      }
    }

#pragma unroll
    for (int m = 0; m < 2; m++) {
#pragma unroll
      for (int j = 0; j < 4; j++) {
        int row = w * 32 + m * 16 + (lane >> 4) * 4 + j;
        int swz = row & 7;
#pragma unroll
        for (int n = 0; n < 4; n++) {
          int col = (lane & 15) + 16 * n;
          *(unsigned short*)((char*)Ps + row * 128 + (((col >> 3) ^ swz) << 4) + (col & 7) * 2) =
              f2bf(s[m][n][j]);
        }
      }
    }

    __builtin_amdgcn_s_setprio(1);
#pragma unroll
    for (int ks = 0; ks < 2; ks++) {
      bf16x8 ap[2];
#pragma unroll
      for (int m = 0; m < 2; m++) {
        int arow = w * 32 + m * 16 + frow;
        ap[m] = *(const bf16x8*)((char*)Ps + arow * 128 + (((ks * 4 + fk) ^ (arow & 7)) << 4));
      }
#pragma unroll
      for (int n = 0; n < 8; n++) {
        int vrow = n * 16 + frow;
        bf16x8 bv = *(const bf16x8*)((char*)&Vs[cur][0] + vrow * 128 + (((ks * 4 + fk) ^ (vrow & 7)) << 4));
#pragma unroll
        for (int m = 0; m < 2; m++)
          o[m][n] = __builtin_amdgcn_mfma_f32_16x16x32_bf16(ap[m], bv, o[m][n], 0, 0, 0);
      }
    }
    __builtin_amdgcn_s_setprio(0);

    if (have_next) {
#pragma unroll
      for (int dd = 0; dd < 4; dd++) {
        int row = vdb + dd;
        u16x8 pk;
#pragma unroll
        for (int i = 0; i < 8; i++) pk[i] = vr[i][dd];
        *(u16x8*)((char*)&Vs[cur ^ 1][0] + row * 128 + (((tid & 7) ^ (row & 7)) << 4)) = pk;
      }
    }
  }

  const bool evenlane = (lane & 1) == 0;
#pragma unroll
  for (int m = 0; m < 2; m++) {
    float inv[4];
#pragma unroll
    for (int j = 0; j < 4; j++) inv[j] = 1.0f / l_r[m][j];
#pragma unroll
    for (int n = 0; n < 8; n += 2) {
#pragma unroll
      for (int j = 0; j < 4; j++) {
        float v0 = o[m][n][j] * inv[j], v1 = o[m][n + 1][j] * inv[j];
        float p0 = __shfl_xor(v0, 1);
        float p1 = __shfl_xor(v1, 1);
        int tq = qtile * 128 + w * 32 + m * 16 + (lane >> 4) * 4 + j;
        int col = evenlane ? (n * 16 + (lane & 15)) : ((n + 1) * 16 + (lane & 15) - 1);
        unsigned int wv = evenlane ? pack2(v0, p0) : pack2(p1, v1);
        *(unsigned int*)(attout + (size_t)(b * 2048 + tq) * 2048 + h * 128 + col) = wv;
      }
    }
  }
}

// ---------------------------------------------------------------------------
// Fallback kernel 3 (round-1): output projection with in-kernel fp32 W pack.
// ---------------------------------------------------------------------------
__global__ __launch_bounds__(256) void out_gemm(
    const unsigned short* __restrict__ Ab, const float* __restrict__ W,
    const float* __restrict__ bias, float* __restrict__ Out)
{
  __shared__ unsigned short As[128 * 32];
  __shared__ unsigned short Bs[128 * 32];

  const int tid = threadIdx.x;
  const int lane = tid & 63;
  const int wave = tid >> 6;
  const int wm = wave >> 1, wn = wave & 1;
  const int bm = blockIdx.x >> 4, bn = blockIdx.x & 15;

  const int srow = tid >> 1;
  const int shalf = tid & 1;
  const unsigned short* Ap = Ab + (size_t)(bm * 128 + srow) * 2048 + shalf * 16;
  const float* Wp = W + (size_t)(bn * 128 + srow) * 2048 + shalf * 16;
  const int ssw = (srow >> 1) & 3;
  const int aoff0 = srow * 32 + (((shalf * 2 + 0) ^ ssw) << 3);
  const int aoff1 = srow * 32 + (((shalf * 2 + 1) ^ ssw) << 3);

  const int frow = lane & 15;
  const int fk = lane >> 4;

  f32x4 acc[4][4];
#pragma unroll
  for (int m = 0; m < 4; m++)
#pragma unroll
    for (int n = 0; n < 4; n++) acc[m][n] = (f32x4)(0.0f);

  for (int kk = 0; kk < 2048; kk += 32) {
    u32x4 a0 = *(const u32x4*)(Ap + kk);
    u32x4 a1 = *(const u32x4*)(Ap + kk + 8);
    f32x4 b0 = *(const f32x4*)(Wp + kk);
    f32x4 b1 = *(const f32x4*)(Wp + kk + 4);
    f32x4 b2 = *(const f32x4*)(Wp + kk + 8);
    f32x4 b3 = *(const f32x4*)(Wp + kk + 12);
    __syncthreads();
    *(u32x4*)(As + aoff0) = a0;
    *(u32x4*)(As + aoff1) = a1;
    *(u32x4*)(Bs + aoff0) = pack8(b0, b1);
    *(u32x4*)(Bs + aoff1) = pack8(b2, b3);
    __syncthreads();
    bf16x8 af[4], bfr[4];
#pragma unroll
    for (int m = 0; m < 4; m++) {
      int r = wm * 64 + m * 16 + frow;
      af[m] = *(const bf16x8*)(As + r * 32 + ((fk ^ ((r >> 1) & 3)) << 3));
    }
#pragma unroll
    for (int n = 0; n < 4; n++) {
      int r = wn * 64 + n * 16 + frow;
      bfr[n] = *(const bf16x8*)(Bs + r * 32 + ((fk ^ ((r >> 1) & 3)) << 3));
    }
#pragma unroll
    for (int m = 0; m < 4; m++)
#pragma unroll
      for (int n = 0; n < 4; n++)
        acc[m][n] = __builtin_amdgcn_mfma_f32_16x16x32_bf16(af[m], bfr[n], acc[m][n], 0, 0, 0);
  }

  float bv[4];
#pragma unroll
  for (int n = 0; n < 4; n++) bv[n] = bias[bn * 128 + wn * 64 + n * 16 + (lane & 15)];
  const bool evenlane = (lane & 1) == 0;
#pragma unroll
  for (int m = 0; m < 4; m++) {
    int rowg = bm * 128 + wm * 64 + m * 16 + (lane >> 4) * 4;
#pragma unroll
    for (int n = 0; n < 4; n += 2) {
#pragma unroll
      for (int j = 0; j < 4; j++) {
        float v0 = acc[m][n][j] + bv[n];
        float v1 = acc[m][n + 1][j] + bv[n + 1];
        float p0 = __shfl_xor(v0, 1);
        float p1 = __shfl_xor(v1, 1);
        int row = rowg + j;
        int colbase = bn * 128 + wn * 64;
        int col = evenlane ? (colbase + n * 16 + (lane & 15))
                           : (colbase + (n + 1) * 16 + (lane & 15) - 1);
        f32x2 wv;
        if (evenlane) { wv[0] = v0; wv[1] = p0; }
        else          { wv[0] = p1; wv[1] = v1; }
        *(f32x2*)(Out + (size_t)row * 2048 + col) = wv;
      }
    }
  }
}

// ---------------------------------------------------------------------------
extern "C" void kernel_launch(void* const* d_in, const int* in_sizes, int n_in,
                              void* d_out, int out_size, void* d_ws, size_t ws_size,
                              hipStream_t stream)
{
  // setup_inputs order: k, q, v, Wk, Wq, Wv, Wo, bo
  const float* k  = (const float*)d_in[0];
  const float* q  = (const float*)d_in[1];
  const float* v  = (const float*)d_in[2];
  const float* Wk = (const float*)d_in[3];
  const float* Wq = (const float*)d_in[4];
  const float* Wv = (const float*)d_in[5];
  const float* Wo = (const float*)d_in[6];
  const float* bo = (const float*)d_in[7];
  float* out = (float*)d_out;

  const size_t HSZ = (size_t)4 * 16 * 2048 * 128;   // 16,777,216 elems = 32 MiB

  if (ws_size >= (size_t)224 << 20) {
    // Fast path: Abf[0,96MiB) | Wbf[96,128) | Qw/Kw/Vw[128,224). attout reuses Abf.
    unsigned short* Abf = (unsigned short*)d_ws;
    unsigned short* Wbf = Abf + 3 * HSZ;
    unsigned short* Qw  = Wbf + 4 * 4194304;
    unsigned short* Kw  = Qw + HSZ;
    unsigned short* Vw  = Kw + HSZ;
    unsigned short* Aw  = Abf;

    convA<<<dim3(8192, 1, 3), 256, 0, stream>>>(q, k, v, Abf);
    convW<<<dim3(2048, 1, 4), 256, 0, stream>>>(Wq, Wk, Wv, Wo, Wbf);
    qkv_gemm_bf<<<dim3(1024, 1, 3), 256, 0, stream>>>(Abf, Wbf, Qw, Kw, Vw);
    attn<<<dim3(1024), 256, 0, stream>>>(Qw, Kw, Vw, Aw);
    out_gemm_bf<<<dim3(1024), 256, 0, stream>>>(Aw, Wbf + 3 * 4194304, bo, out);
  } else {
    // Fallback (128 MiB)
    unsigned short* Qw = (unsigned short*)d_ws;
    unsigned short* Kw = Qw + HSZ;
    unsigned short* Vw = Kw + HSZ;
    unsigned short* Aw = Vw + HSZ;
    qkv_gemm<<<dim3(1024, 1, 3), 256, 0, stream>>>(q, k, v, Wq, Wk, Wv, Qw, Kw, Vw);
    attn<<<dim3(1024), 256, 0, stream>>>(Qw, Kw, Vw, Aw);
    out_gemm<<<dim3(1024), 256, 0, stream>>>(Aw, Wo, bo, out);
  }
}

// Round 6
// 565.815 us; speedup vs baseline: 2.2830x; 1.1494x over previous
//
#include <hip/hip_runtime.h>

// MHA: out = softmax((qWq^T)(kWk^T)^T/sqrt(128)) (vWv^T) Wo^T + bo
// B=4 T=2048 E=2048 H=16 D=128. All GEMMs via bf16 MFMA (fp32 accum).
// GEMMs: 256x256 tile, BK=64, 8-phase counted-vmcnt schedule (T2+T3+T4+T5),
// global_load_lds w/ pre-swizzled source, XCD-chunked grid swizzle.

typedef __attribute__((ext_vector_type(4))) float f32x4;
typedef __attribute__((ext_vector_type(2))) float f32x2;
typedef __attribute__((ext_vector_type(8))) __bf16 bf16x8;
typedef __attribute__((ext_vector_type(4))) unsigned int u32x4;
typedef __attribute__((ext_vector_type(8))) unsigned short u16x8;
typedef __attribute__((ext_vector_type(4))) unsigned short u16x4;

#define DEVI static __device__ __forceinline__

DEVI unsigned short f2bf(float f) {            // RNE fp32 -> bf16
  union { float f; unsigned u; } x; x.f = f;
  unsigned u = x.u;
  return (unsigned short)((u + 0x7fffu + ((u >> 16) & 1u)) >> 16);
}
DEVI unsigned int pack2(float lo, float hi) {
  return (unsigned int)f2bf(lo) | ((unsigned int)f2bf(hi) << 16);
}
DEVI u32x4 pack8(const f32x4 a, const f32x4 b) {
  u32x4 r;
  r[0] = pack2(a[0], a[1]); r[1] = pack2(a[2], a[3]);
  r[2] = pack2(b[0], b[1]); r[3] = pack2(b[2], b[3]);
  return r;
}
DEVI void gload16(const unsigned short* g, unsigned short* l) {
  __builtin_amdgcn_global_load_lds(
      (const __attribute__((address_space(1))) unsigned int*)g,
      (__attribute__((address_space(3))) unsigned int*)l, 16, 0, 0);
}

// DPP cross-lane (VALU-rate, within 16-lane row)
template <int CTRL> DEVI float dppf(float x) {
  return __builtin_bit_cast(float, __builtin_amdgcn_update_dpp(
      __builtin_bit_cast(int, x), __builtin_bit_cast(int, x), CTRL, 0xF, 0xF, true));
}
DEVI float rowmax16(float x) {
  x = fmaxf(x, dppf<0x121>(x));
  x = fmaxf(x, dppf<0x122>(x));
  x = fmaxf(x, dppf<0x124>(x));
  x = fmaxf(x, dppf<0x128>(x));
  return x;
}
DEVI float rowsum16(float x) {
  x += dppf<0x121>(x);
  x += dppf<0x122>(x);
  x += dppf<0x124>(x);
  x += dppf<0x128>(x);
  return x;
}

// ---------------------------------------------------------------------------
// fp32 -> bf16 convert passes
// ---------------------------------------------------------------------------
__global__ __launch_bounds__(256) void convA(
    const float* __restrict__ q, const float* __restrict__ k,
    const float* __restrict__ v, unsigned short* __restrict__ dst)
{
  const int z = blockIdx.z;
  const float* src = z == 0 ? q : (z == 1 ? k : v);
  unsigned short* d = dst + (size_t)z * 16777216;
  size_t i = ((size_t)blockIdx.x * 256 + threadIdx.x) * 8;
  f32x4 a = *(const f32x4*)(src + i);
  f32x4 b = *(const f32x4*)(src + i + 4);
  *(u32x4*)(d + i) = pack8(a, b);
}

__global__ __launch_bounds__(256) void convW(
    const float* __restrict__ w0, const float* __restrict__ w1,
    const float* __restrict__ w2, const float* __restrict__ w3,
    unsigned short* __restrict__ dst)
{
  const int z = blockIdx.z;
  const float* src = z == 0 ? w0 : (z == 1 ? w1 : (z == 2 ? w2 : w3));
  unsigned short* d = dst + (size_t)z * 4194304;
  size_t i = ((size_t)blockIdx.x * 256 + threadIdx.x) * 8;
  f32x4 a = *(const f32x4*)(src + i);
  f32x4 b = *(const f32x4*)(src + i + 4);
  *(u32x4*)(d + i) = pack8(a, b);
}

// ---------------------------------------------------------------------------
// 256x256 8-phase GEMM mainloop. K=2048, BK=64, 8 waves (2M x 4N), 512 thr.
// LDS: As/Bs [2 buf][256 rows][64 cols] bf16, 16B-slot swizzle slot = c^(r&7)
// (gload source pre-swizzled; reads use same involution -> conflict-free).
// Per iteration: compute K-tiles t (buf0, ph1-4) and t+1 (buf1, ph5-8);
// stage stream (1 half-tile = 2 gloads/thread per phase):
//   ph1:A1(t+1) ph2:B0(t+1) ph3:B1(t+1) ph4:A0(t+2)
//   ph5:A1(t+2) ph6:B0(t+2) ph7:B1(t+2) ph8:A0(t+3)
// WAR-safe: A-halves of a buffer are last read in ph3/ph7, B-halves in ph4/ph8;
// each restage issues only after the pinned barrier following the last reader.
// vmcnt(2) at ph4/ph8 completes exactly the next tile's 8 loads.
// ---------------------------------------------------------------------------
#define STG2(gp, lp, tile) do { \
    gload16((gp) + (size_t)(tile) * 64,            (lp)); \
    gload16((gp) + (size_t)(tile) * 64 + 8 * 2048, (lp) + 8 * 64); \
  } while (0)
#define LDA8(bufoff, ksbit) { \
    _Pragma("unroll") for (int m = 0; m < 8; m++) \
      a[m] = *(const bf16x8*)(As + (bufoff) + (aoff[m] ^ (ksbit))); }
#define LDB2(bufoff, ksbit, n0) { \
    b0 = *(const bf16x8*)(Bs + (bufoff) + (boff[n0] ^ (ksbit))); \
    b1 = *(const bf16x8*)(Bs + (bufoff) + (boff[(n0) + 1] ^ (ksbit))); }
#define MM2(n0) { \
    __builtin_amdgcn_s_setprio(1); \
    _Pragma("unroll") for (int m = 0; m < 8; m++) { \
      acc[m][n0] = __builtin_amdgcn_mfma_f32_16x16x32_bf16(a[m], b0, acc[m][n0], 0, 0, 0); \
      acc[m][(n0) + 1] = __builtin_amdgcn_mfma_f32_16x16x32_bf16(a[m], b1, acc[m][(n0) + 1], 0, 0, 0); \
    } \
    __builtin_amdgcn_s_setprio(0); }
#define BARX() { __builtin_amdgcn_sched_barrier(0); __builtin_amdgcn_s_barrier(); }
#define WVM(n) asm volatile("s_waitcnt vmcnt(" #n ")" ::: "memory");

DEVI void gemm256_bf16(const unsigned short* __restrict__ A,
                       const unsigned short* __restrict__ Bm,
                       unsigned short* As, unsigned short* Bs,
                       int bm, int bn, int tid, f32x4 (&acc)[8][4])
{
  const int lane = tid & 63, w = tid >> 6;
  const int wm = w >> 2, wn = w & 3;
  // staging geometry: per gload instr a wave covers 8 rows x 64 cols.
  const int sr = lane >> 3;                  // row within 8-row group
  const int sc = (lane & 7) ^ sr;            // pre-swizzled global chunk
  const unsigned short* gA0 = A  + (size_t)(bm * 256 +   0 + w * 16 + sr) * 2048 + sc * 8;
  const unsigned short* gA1 = A  + (size_t)(bm * 256 + 128 + w * 16 + sr) * 2048 + sc * 8;
  const unsigned short* gB0 = Bm + (size_t)(bn * 256 +   0 + w * 16 + sr) * 2048 + sc * 8;
  const unsigned short* gB1 = Bm + (size_t)(bn * 256 + 128 + w * 16 + sr) * 2048 + sc * 8;
  unsigned short* lA00 = As +         (  0 + w * 16) * 64;   // [buf0][half0]
  unsigned short* lA01 = As +         (128 + w * 16) * 64;
  unsigned short* lA10 = As + 16384 + (  0 + w * 16) * 64;   // [buf1][half0]
  unsigned short* lA11 = As + 16384 + (128 + w * 16) * 64;
  unsigned short* lB00 = Bs +         (  0 + w * 16) * 64;
  unsigned short* lB01 = Bs +         (128 + w * 16) * 64;
  unsigned short* lB10 = Bs + 16384 + (  0 + w * 16) * 64;
  unsigned short* lB11 = Bs + 16384 + (128 + w * 16) * 64;

  const int fr = lane & 15, fk = lane >> 4;
  const int swz = (fk ^ (lane & 7)) << 3;    // r&7 == lane&7 for all frag rows
  int aoff[8], boff[4];
#pragma unroll
  for (int m = 0; m < 8; m++) aoff[m] = (wm * 128 + m * 16 + fr) * 64 + swz;
#pragma unroll
  for (int n = 0; n < 4; n++) boff[n] = (wn * 64 + n * 16 + fr) * 64 + swz;

  bf16x8 a[8], b0, b1;

  // prologue: tile0 (buf0) + A0(tile1); wait tile0 complete (leave A0(1) pair)
  STG2(gA0, lA00, 0); STG2(gA1, lA01, 0); STG2(gB0, lB00, 0); STG2(gB1, lB01, 0);
  STG2(gA0, lA10, 1);
  WVM(2) BARX()

  for (int t = 0; t < 30; t += 2) {
    // ph1: buf0 ks0 n01
    LDA8(0, 0) LDB2(0, 0, 0) STG2(gA1, lA11, t + 1);
    BARX() MM2(0) BARX()
    // ph2: buf0 ks0 n23
    LDB2(0, 0, 2) STG2(gB0, lB10, t + 1);
    BARX() MM2(2) BARX()
    // ph3: buf0 ks1 n01
    LDA8(0, 32) LDB2(0, 32, 0) STG2(gB1, lB11, t + 1);
    BARX() MM2(0) BARX()
    // ph4: buf0 ks1 n23 ; tile t+1 must be resident after this phase
    LDB2(0, 32, 2) STG2(gA0, lA00, t + 2);
    BARX() MM2(2) WVM(2) BARX()
    // ph5: buf1 ks0 n01
    LDA8(16384, 0) LDB2(16384, 0, 0) STG2(gA1, lA01, t + 2);
    BARX() MM2(0) BARX()
    // ph6: buf1 ks0 n23
    LDB2(16384, 0, 2) STG2(gB0, lB00, t + 2);
    BARX() MM2(2) BARX()
    // ph7: buf1 ks1 n01
    LDA8(16384, 32) LDB2(16384, 32, 0) STG2(gB1, lB01, t + 2);
    BARX() MM2(0) BARX()
    // ph8: buf1 ks1 n23 ; tile t+2 must be resident after this phase
    LDB2(16384, 32, 2) STG2(gA0, lA10, t + 3);
    BARX() MM2(2) WVM(2) BARX()
  }
  // final pair: t=30 (buf0), t=31 (buf1); finish staging tile 31 in ph1-3
  LDA8(0, 0) LDB2(0, 0, 0) STG2(gA1, lA11, 31);
  BARX() MM2(0) BARX()
  LDB2(0, 0, 2) STG2(gB0, lB10, 31);
  BARX() MM2(2) BARX()
  LDA8(0, 32) LDB2(0, 32, 0) STG2(gB1, lB11, 31);
  BARX() MM2(0) BARX()
  LDB2(0, 32, 2)
  BARX() MM2(2) WVM(0) BARX()
  LDA8(16384, 0) LDB2(16384, 0, 0)
  BARX() MM2(0) BARX()
  LDB2(16384, 0, 2)
  BARX() MM2(2) BARX()
  LDA8(16384, 32) LDB2(16384, 32, 0)
  BARX() MM2(0) BARX()
  LDB2(16384, 32, 2)
  BARX() MM2(2)
}

// XCD-chunked bijective swizzle for grid.x = 256 (8 XCDs x 32 blocks).
DEVI int xcd_swz256(int bid) { return ((bid & 7) << 5) | (bid >> 3); }

// ---------------------------------------------------------------------------
// Kernel 1: QKV projection from pre-converted bf16. Output [B,H,T,D] bf16.
// ---------------------------------------------------------------------------
__global__ __launch_bounds__(512, 2) void qkv_gemm_bf(
    const unsigned short* __restrict__ Abf, const unsigned short* __restrict__ Wbf,
    unsigned short* __restrict__ O0, unsigned short* __restrict__ O1,
    unsigned short* __restrict__ O2)
{
  __shared__ unsigned short As[2 * 256 * 64];   // 64 KB
  __shared__ unsigned short Bs[2 * 256 * 64];   // 64 KB
  const int z = blockIdx.z;
  const unsigned short* A = Abf + (size_t)z * 16777216;
  const unsigned short* W = Wbf + (size_t)z * 4194304;
  unsigned short* O = z == 0 ? O0 : (z == 1 ? O1 : O2);

  const int tid = threadIdx.x;
  const int lane = tid & 63, w = tid >> 6;
  const int wm = w >> 2, wn = w & 3;
  const int bs = xcd_swz256(blockIdx.x);
  const int bm = bs >> 3, bn = bs & 7;

  f32x4 acc[8][4];
#pragma unroll
  for (int m = 0; m < 8; m++)
#pragma unroll
    for (int n = 0; n < 4; n++) acc[m][n] = (f32x4)(0.0f);

  gemm256_bf16(A, W, As, Bs, bm, bn, tid, acc);

  const bool evenlane = (lane & 1) == 0;
#pragma unroll
  for (int m = 0; m < 8; m++) {
    int rowg = bm * 256 + wm * 128 + m * 16 + (lane >> 4) * 4;
#pragma unroll
    for (int n = 0; n < 4; n += 2) {
#pragma unroll
      for (int j = 0; j < 4; j++) {
        float v0 = acc[m][n][j], v1 = acc[m][n + 1][j];
        float p0 = __shfl_xor(v0, 1);
        float p1 = __shfl_xor(v1, 1);
        int row = rowg + j;
        int b = row >> 11, t = row & 2047;
        int colbase = bn * 256 + wn * 64;
        int col = evenlane ? (colbase + n * 16 + (lane & 15))
                           : (colbase + (n + 1) * 16 + (lane & 15) - 1);
        unsigned int wv = evenlane ? pack2(v0, p0) : pack2(p1, v1);
        int h = col >> 7, d = col & 127;
        *(unsigned int*)(O + (((size_t)(b * 16 + h) * 2048 + t) << 7) + d) = wv;
      }
    }
  }
}

// ---------------------------------------------------------------------------
// Kernel 3: output projection from bf16 attout + bf16 Wo. fp32 out + bias.
// ---------------------------------------------------------------------------
__global__ __launch_bounds__(512, 2) void out_gemm_bf(
    const unsigned short* __restrict__ Ab, const unsigned short* __restrict__ Wb,
    const float* __restrict__ bias, float* __restrict__ Out)
{
  __shared__ unsigned short As[2 * 256 * 64];
  __shared__ unsigned short Bs[2 * 256 * 64];
  const int tid = threadIdx.x;
  const int lane = tid & 63, w = tid >> 6;
  const int wm = w >> 2, wn = w & 3;
  const int bs = xcd_swz256(blockIdx.x);
  const int bm = bs >> 3, bn = bs & 7;

  f32x4 acc[8][4];
#pragma unroll
  for (int m = 0; m < 8; m++)
#pragma unroll
    for (int n = 0; n < 4; n++) acc[m][n] = (f32x4)(0.0f);

  gemm256_bf16(Ab, Wb, As, Bs, bm, bn, tid, acc);

  float bv[4];
#pragma unroll
  for (int n = 0; n < 4; n++) bv[n] = bias[bn * 256 + wn * 64 + n * 16 + (lane & 15)];
  const bool evenlane = (lane & 1) == 0;
#pragma unroll
  for (int m = 0; m < 8; m++) {
    int rowg = bm * 256 + wm * 128 + m * 16 + (lane >> 4) * 4;
#pragma unroll
    for (int n = 0; n < 4; n += 2) {
#pragma unroll
      for (int j = 0; j < 4; j++) {
        float v0 = acc[m][n][j] + bv[n];
        float v1 = acc[m][n + 1][j] + bv[n + 1];
        float p0 = __shfl_xor(v0, 1);
        float p1 = __shfl_xor(v1, 1);
        int row = rowg + j;
        int colbase = bn * 256 + wn * 64;
        int col = evenlane ? (colbase + n * 16 + (lane & 15))
                           : (colbase + (n + 1) * 16 + (lane & 15) - 1);
        f32x2 wv;
        if (evenlane) { wv[0] = v0; wv[1] = p0; }
        else          { wv[0] = p1; wv[1] = v1; }
        *(f32x2*)(Out + (size_t)row * 2048 + col) = wv;
      }
    }
  }
}

// ---------------------------------------------------------------------------
// Fallback kernel 1 (round-1): fused QKV projection with in-kernel fp32->bf16.
// ---------------------------------------------------------------------------
__global__ __launch_bounds__(256) void qkv_gemm(
    const float* __restrict__ A0, const float* __restrict__ A1, const float* __restrict__ A2,
    const float* __restrict__ W0, const float* __restrict__ W1, const float* __restrict__ W2,
    unsigned short* __restrict__ O0, unsigned short* __restrict__ O1, unsigned short* __restrict__ O2)
{
  __shared__ unsigned short As[128 * 32];
  __shared__ unsigned short Bs[128 * 32];
  const int z = blockIdx.z;
  const float* A = z == 0 ? A0 : (z == 1 ? A1 : A2);
  const float* W = z == 0 ? W0 : (z == 1 ? W1 : W2);
  unsigned short* O = z == 0 ? O0 : (z == 1 ? O1 : O2);

  const int tid = threadIdx.x;
  const int lane = tid & 63;
  const int wave = tid >> 6;
  const int wm = wave >> 1, wn = wave & 1;
  const int bm = blockIdx.x >> 4, bn = blockIdx.x & 15;

  const int srow = tid >> 1;
  const int shalf = tid & 1;
  const float* Ap = A + (size_t)(bm * 128 + srow) * 2048 + shalf * 16;
  const float* Wp = W + (size_t)(bn * 128 + srow) * 2048 + shalf * 16;
  const int ssw = (srow >> 1) & 3;
  const int aoff0 = srow * 32 + (((shalf * 2 + 0) ^ ssw) << 3);
  const int aoff1 = srow * 32 + (((shalf * 2 + 1) ^ ssw) << 3);

  const int frow = lane & 15;
  const int fk = lane >> 4;

  f32x4 acc[4][4];
#pragma unroll
  for (int m = 0; m < 4; m++)
#pragma unroll
    for (int n = 0; n < 4; n++) acc[m][n] = (f32x4)(0.0f);

  for (int kk = 0; kk < 2048; kk += 32) {
    f32x4 a0 = *(const f32x4*)(Ap + kk);
    f32x4 a1 = *(const f32x4*)(Ap + kk + 4);
    f32x4 a2 = *(const f32x4*)(Ap + kk + 8);
    f32x4 a3 = *(const f32x4*)(Ap + kk + 12);
    f32x4 b0 = *(const f32x4*)(Wp + kk);
    f32x4 b1 = *(const f32x4*)(Wp + kk + 4);
    f32x4 b2 = *(const f32x4*)(Wp + kk + 8);
    f32x4 b3 = *(const f32x4*)(Wp + kk + 12);
    __syncthreads();
    *(u32x4*)(As + aoff0) = pack8(a0, a1);
    *(u32x4*)(As + aoff1) = pack8(a2, a3);
    *(u32x4*)(Bs + aoff0) = pack8(b0, b1);
    *(u32x4*)(Bs + aoff1) = pack8(b2, b3);
    __syncthreads();
    bf16x8 af[4], bfr[4];
#pragma unroll
    for (int m = 0; m < 4; m++) {
      int r = wm * 64 + m * 16 + frow;
      af[m] = *(const bf16x8*)(As + r * 32 + ((fk ^ ((r >> 1) & 3)) << 3));
    }
#pragma unroll
    for (int n = 0; n < 4; n++) {
      int r = wn * 64 + n * 16 + frow;
      bfr[n] = *(const bf16x8*)(Bs + r * 32 + ((fk ^ ((r >> 1) & 3)) << 3));
    }
#pragma unroll
    for (int m = 0; m < 4; m++)
#pragma unroll
      for (int n = 0; n < 4; n++)
        acc[m][n] = __builtin_amdgcn_mfma_f32_16x16x32_bf16(af[m], bfr[n], acc[m][n], 0, 0, 0);
  }

  const bool evenlane = (lane & 1) == 0;
#pragma unroll
  for (int m = 0; m < 4; m++) {
    int rowg = bm * 128 + wm * 64 + m * 16 + (lane >> 4) * 4;
#pragma unroll
    for (int n = 0; n < 4; n += 2) {
#pragma unroll
      for (int j = 0; j < 4; j++) {
        float v0 = acc[m][n][j], v1 = acc[m][n + 1][j];
        float p0 = __shfl_xor(v0, 1);
        float p1 = __shfl_xor(v1, 1);
        int row = rowg + j;
        int b = row >> 11, t = row & 2047;
        int colbase = bn * 128 + wn * 64;
        int col = evenlane ? (colbase + n * 16 + (lane & 15))
                           : (colbase + (n + 1) * 16 + (lane & 15) - 1);
        unsigned int wv = evenlane ? pack2(v0, p0) : pack2(p1, v1);
        int h = col >> 7, d = col & 127;
        *(unsigned int*)(O + (((size_t)(b * 16 + h) * 2048 + t) << 7) + d) = wv;
      }
    }
  }
}

// ---------------------------------------------------------------------------
// Kernel 2: flash attention (round-4, unchanged). 64 (b,h) x 16 Q-tiles of
// 128 rows; 4 waves, wave owns 32 q-rows. Q in regs, K/V LDS dbuf (T14),
// DPP reduces, defer-max (T13), setprio (T5), XCD swizzle (T1).
// ---------------------------------------------------------------------------
__global__ __launch_bounds__(256, 2) void attn(
    const unsigned short* __restrict__ Qw, const unsigned short* __restrict__ Kw,
    const unsigned short* __restrict__ Vw, unsigned short* __restrict__ attout)
{
  __shared__ unsigned short Ks[2][64 * 128];
  __shared__ unsigned short Vs[2][128 * 64];
  __shared__ unsigned short Ps[128 * 64];

  const int bid = blockIdx.x;
  const int work = ((bid & 7) << 7) | (bid >> 3);
  const int bh = work >> 4;
  const int qtile = work & 15;
  const int b = bh >> 4, h = bh & 15;
  const unsigned short* Qbase = Qw + (size_t)bh * 2048 * 128 + qtile * 128 * 128;
  const unsigned short* Kbase = Kw + (size_t)bh * 2048 * 128;
  const unsigned short* Vbase = Vw + (size_t)bh * 2048 * 128;
  const int tid = threadIdx.x, lane = tid & 63, w = tid >> 6;
  const int frow = lane & 15, fk = lane >> 4;

  bf16x8 qf[2][4];
#pragma unroll
  for (int m = 0; m < 2; m++)
#pragma unroll
    for (int ks = 0; ks < 4; ks++)
      qf[m][ks] = *(const bf16x8*)(Qbase + (size_t)(w * 32 + m * 16 + frow) * 128 + ks * 32 + fk * 8);

  const int krow_i = lane >> 4;
  const int kslot = lane & 15;
  const int vkb = (tid & 7) * 8;
  const int vdb = (tid >> 3) * 4;

  f32x4 o[2][8];
#pragma unroll
  for (int m = 0; m < 2; m++)
#pragma unroll
    for (int n = 0; n < 8; n++) o[m][n] = (f32x4)(0.0f);
  float m_r[2][4], l_r[2][4];
#pragma unroll
  for (int m = 0; m < 2; m++)
#pragma unroll
    for (int j = 0; j < 4; j++) { m_r[m][j] = -INFINITY; l_r[m][j] = 0.f; }
  const float SC = 0.12751721769f;   // log2(e)/sqrt(128)
  const float THR = 90.5f;           // 8 ln-units in s-space

  {
#pragma unroll
    for (int i = 0; i < 4; i++) {
      int row = w * 16 + i * 4 + krow_i;
      gload16(Kbase + (size_t)row * 128 + ((kslot ^ (row & 15)) << 3),
              &Ks[0][(w * 16 + i * 4) * 128]);
    }
    u16x4 vr[8];
#pragma unroll
    for (int i = 0; i < 8; i++) vr[i] = *(const u16x4*)(Vbase + (size_t)(vkb + i) * 128 + vdb);
#pragma unroll
    for (int dd = 0; dd < 4; dd++) {
      int row = vdb + dd;
      u16x8 pk;
#pragma unroll
      for (int i = 0; i < 8; i++) pk[i] = vr[i][dd];
      *(u16x8*)((char*)&Vs[0][0] + row * 128 + (((tid & 7) ^ (row & 7)) << 4)) = pk;
    }
  }

  for (int kt = 0; kt < 32; kt++) {
    const int cur = kt & 1;
    __syncthreads();

    u16x4 vr[8];
    const bool have_next = (kt + 1) < 32;
    if (have_next) {
      const unsigned short* Kt = Kbase + (kt + 1) * 64 * 128;
      const unsigned short* Vt = Vbase + (kt + 1) * 64 * 128;
#pragma unroll
      for (int i = 0; i < 4; i++) {
        int row = w * 16 + i * 4 + krow_i;
        gload16(Kt + (size_t)row * 128 + ((kslot ^ (row & 15)) << 3),
                &Ks[cur ^ 1][(w * 16 + i * 4) * 128]);
      }
#pragma unroll
      for (int i = 0; i < 8; i++) vr[i] = *(const u16x4*)(Vt + (size_t)(vkb + i) * 128 + vdb);
    }

    f32x4 s[2][4];
#pragma unroll
    for (int m = 0; m < 2; m++)
#pragma unroll
      for (int n = 0; n < 4; n++) s[m][n] = (f32x4)(0.0f);
    __builtin_amdgcn_s_setprio(1);
#pragma unroll
    for (int ks = 0; ks < 4; ks++) {
#pragma unroll
      for (int n = 0; n < 4; n++) {
        int brow = n * 16 + frow;
        bf16x8 bk = *(const bf16x8*)(&Ks[cur][0] + brow * 128 + (((ks * 4 + fk) ^ (brow & 15)) << 3));
#pragma unroll
        for (int m = 0; m < 2; m++)
          s[m][n] = __builtin_amdgcn_mfma_f32_16x16x32_bf16(qf[m][ks], bk, s[m][n], 0, 0, 0);
      }
    }
    __builtin_amdgcn_s_setprio(0);

#pragma unroll
    for (int m = 0; m < 2; m++) {
#pragma unroll
      for (int j = 0; j < 4; j++) {
        float mx = fmaxf(fmaxf(s[m][0][j], s[m][1][j]), fmaxf(s[m][2][j], s[m][3][j]));
        mx = rowmax16(mx);
        float mo = m_r[m][j];
        if (!__all(mx - mo <= THR)) {
          float mnew = fmaxf(mo, mx);
          float f = __builtin_amdgcn_exp2f((mo - mnew) * SC);
          m_r[m][j] = mnew;
          l_r[m][j] *= f;
#pragma unroll
          for (int n = 0; n < 8; n++) o[m][n][j] *= f;
        }
        float mm = m_r[m][j];
        float psum = 0.f;
#pragma unroll
        for (int n = 0; n < 4; n++) {
          float p = __builtin_amdgcn_exp2f((s[m][n][j] - mm) * SC);
          s[m][n][j] = p;
          psum += p;
        }
        l_r[m][j] += rowsum16(psum);
      }
    }

#pragma unroll
    for (int m = 0; m < 2; m++) {
#pragma unroll
      for (int j = 0; j < 4; j++) {
        int row = w * 32 + m * 16 + (lane >> 4) * 4 + j;
        int swz = row & 7;
#pragma unroll
        for (int n = 0; n < 4; n++) {
          int col = (lane & 15) + 16 * n;
          *(unsigned short*)((char*)Ps + row * 128 + (((col >> 3) ^ swz) << 4) + (col & 7) * 2) =
              f2bf(s[m][n][j]);
        }
      }
    }

    __builtin_amdgcn_s_setprio(1);
#pragma unroll
    for (int ks = 0; ks < 2; ks++) {
      bf16x8 ap[2];
#pragma unroll
      for (int m = 0; m < 2; m++) {
        int arow = w * 32 + m * 16 + frow;
        ap[m] = *(const bf16x8*)((char*)Ps + arow * 128 + (((ks * 4 + fk) ^ (arow & 7)) << 4));
      }
#pragma unroll
      for (int n = 0; n < 8; n++) {
        int vrow = n * 16 + frow;
        bf16x8 bv = *(const bf16x8*)((char*)&Vs[cur][0] + vrow * 128 + (((ks * 4 + fk) ^ (vrow & 7)) << 4));
#pragma unroll
        for (int m = 0; m < 2; m++)
          o[m][n] = __builtin_amdgcn_mfma_f32_16x16x32_bf16(ap[m], bv, o[m][n], 0, 0, 0);
      }
    }
    __builtin_amdgcn_s_setprio(0);

    if (have_next) {
#pragma unroll
      for (int dd = 0; dd < 4; dd++) {
        int row = vdb + dd;
        u16x8 pk;
#pragma unroll
        for (int i = 0; i < 8; i++) pk[i] = vr[i][dd];
        *(u16x8*)((char*)&Vs[cur ^ 1][0] + row * 128 + (((tid & 7) ^ (row & 7)) << 4)) = pk;
      }
    }
  }

  const bool evenlane = (lane & 1) == 0;
#pragma unroll
  for (int m = 0; m < 2; m++) {
    float inv[4];
#pragma unroll
    for (int j = 0; j < 4; j++) inv[j] = 1.0f / l_r[m][j];
#pragma unroll
    for (int n = 0; n < 8; n += 2) {
#pragma unroll
      for (int j = 0; j < 4; j++) {
        float v0 = o[m][n][j] * inv[j], v1 = o[m][n + 1][j] * inv[j];
        float p0 = __shfl_xor(v0, 1);
        float p1 = __shfl_xor(v1, 1);
        int tq = qtile * 128 + w * 32 + m * 16 + (lane >> 4) * 4 + j;
        int col = evenlane ? (n * 16 + (lane & 15)) : ((n + 1) * 16 + (lane & 15) - 1);
        unsigned int wv = evenlane ? pack2(v0, p0) : pack2(p1, v1);
        *(unsigned int*)(attout + (size_t)(b * 2048 + tq) * 2048 + h * 128 + col) = wv;
      }
    }
  }
}

// ---------------------------------------------------------------------------
// Fallback kernel 3 (round-1): output projection with in-kernel fp32 W pack.
// ---------------------------------------------------------------------------
__global__ __launch_bounds__(256) void out_gemm(
    const unsigned short* __restrict__ Ab, const float* __restrict__ W,
    const float* __restrict__ bias, float* __restrict__ Out)
{
  __shared__ unsigned short As[128 * 32];
  __shared__ unsigned short Bs[128 * 32];

  const int tid = threadIdx.x;
  const int lane = tid & 63;
  const int wave = tid >> 6;
  const int wm = wave >> 1, wn = wave & 1;
  const int bm = blockIdx.x >> 4, bn = blockIdx.x & 15;

  const int srow = tid >> 1;
  const int shalf = tid & 1;
  const unsigned short* Ap = Ab + (size_t)(bm * 128 + srow) * 2048 + shalf * 16;
  const float* Wp = W + (size_t)(bn * 128 + srow) * 2048 + shalf * 16;
  const int ssw = (srow >> 1) & 3;
  const int aoff0 = srow * 32 + (((shalf * 2 + 0) ^ ssw) << 3);
  const int aoff1 = srow * 32 + (((shalf * 2 + 1) ^ ssw) << 3);

  const int frow = lane & 15;
  const int fk = lane >> 4;

  f32x4 acc[4][4];
#pragma unroll
  for (int m = 0; m < 4; m++)
#pragma unroll
    for (int n = 0; n < 4; n++) acc[m][n] = (f32x4)(0.0f);

  for (int kk = 0; kk < 2048; kk += 32) {
    u32x4 a0 = *(const u32x4*)(Ap + kk);
    u32x4 a1 = *(const u32x4*)(Ap + kk + 8);
    f32x4 b0 = *(const f32x4*)(Wp + kk);
    f32x4 b1 = *(const f32x4*)(Wp + kk + 4);
    f32x4 b2 = *(const f32x4*)(Wp + kk + 8);
    f32x4 b3 = *(const f32x4*)(Wp + kk + 12);
    __syncthreads();
    *(u32x4*)(As + aoff0) = a0;
    *(u32x4*)(As + aoff1) = a1;
    *(u32x4*)(Bs + aoff0) = pack8(b0, b1);
    *(u32x4*)(Bs + aoff1) = pack8(b2, b3);
    __syncthreads();
    bf16x8 af[4], bfr[4];
#pragma unroll
    for (int m = 0; m < 4; m++) {
      int r = wm * 64 + m * 16 + frow;
      af[m] = *(const bf16x8*)(As + r * 32 + ((fk ^ ((r >> 1) & 3)) << 3));
    }
#pragma unroll
    for (int n = 0; n < 4; n++) {
      int r = wn * 64 + n * 16 + frow;
      bfr[n] = *(const bf16x8*)(Bs + r * 32 + ((fk ^ ((r >> 1) & 3)) << 3));
    }
#pragma unroll
    for (int m = 0; m < 4; m++)
#pragma unroll
      for (int n = 0; n < 4; n++)
        acc[m][n] = __builtin_amdgcn_mfma_f32_16x16x32_bf16(af[m], bfr[n], acc[m][n], 0, 0, 0);
  }

  float bv[4];
#pragma unroll
  for (int n = 0; n < 4; n++) bv[n] = bias[bn * 128 + wn * 64 + n * 16 + (lane & 15)];
  const bool evenlane = (lane & 1) == 0;
#pragma unroll
  for (int m = 0; m < 4; m++) {
    int rowg = bm * 128 + wm * 64 + m * 16 + (lane >> 4) * 4;
#pragma unroll
    for (int n = 0; n < 4; n += 2) {
#pragma unroll
      for (int j = 0; j < 4; j++) {
        float v0 = acc[m][n][j] + bv[n];
        float v1 = acc[m][n + 1][j] + bv[n + 1];
        float p0 = __shfl_xor(v0, 1);
        float p1 = __shfl_xor(v1, 1);
        int row = rowg + j;
        int colbase = bn * 128 + wn * 64;
        int col = evenlane ? (colbase + n * 16 + (lane & 15))
                           : (colbase + (n + 1) * 16 + (lane & 15) - 1);
        f32x2 wv;
        if (evenlane) { wv[0] = v0; wv[1] = p0; }
        else          { wv[0] = p1; wv[1] = v1; }
        *(f32x2*)(Out + (size_t)row * 2048 + col) = wv;
      }
    }
  }
}

// ---------------------------------------------------------------------------
extern "C" void kernel_launch(void* const* d_in, const int* in_sizes, int n_in,
                              void* d_out, int out_size, void* d_ws, size_t ws_size,
                              hipStream_t stream)
{
  // setup_inputs order: k, q, v, Wk, Wq, Wv, Wo, bo
  const float* k  = (const float*)d_in[0];
  const float* q  = (const float*)d_in[1];
  const float* v  = (const float*)d_in[2];
  const float* Wk = (const float*)d_in[3];
  const float* Wq = (const float*)d_in[4];
  const float* Wv = (const float*)d_in[5];
  const float* Wo = (const float*)d_in[6];
  const float* bo = (const float*)d_in[7];
  float* out = (float*)d_out;

  const size_t HSZ = (size_t)4 * 16 * 2048 * 128;   // 16,777,216 elems = 32 MiB

  if (ws_size >= (size_t)224 << 20) {
    // Fast path: Abf[0,96MiB) | Wbf[96,128) | Qw/Kw/Vw[128,224). attout reuses Abf.
    unsigned short* Abf = (unsigned short*)d_ws;
    unsigned short* Wbf = Abf + 3 * HSZ;
    unsigned short* Qw  = Wbf + 4 * 4194304;
    unsigned short* Kw  = Qw + HSZ;
    unsigned short* Vw  = Kw + HSZ;
    unsigned short* Aw  = Abf;

    convA<<<dim3(8192, 1, 3), 256, 0, stream>>>(q, k, v, Abf);
    convW<<<dim3(2048, 1, 4), 256, 0, stream>>>(Wq, Wk, Wv, Wo, Wbf);
    qkv_gemm_bf<<<dim3(256, 1, 3), 512, 0, stream>>>(Abf, Wbf, Qw, Kw, Vw);
    attn<<<dim3(1024), 256, 0, stream>>>(Qw, Kw, Vw, Aw);
    out_gemm_bf<<<dim3(256), 512, 0, stream>>>(Aw, Wbf + 3 * 4194304, bo, out);
  } else {
    // Fallback (128 MiB)
    unsigned short* Qw = (unsigned short*)d_ws;
    unsigned short* Kw = Qw + HSZ;
    unsigned short* Vw = Kw + HSZ;
    unsigned short* Aw = Vw + HSZ;
    qkv_gemm<<<dim3(1024, 1, 3), 256, 0, stream>>>(q, k, v, Wq, Wk, Wv, Qw, Kw, Vw);
    attn<<<dim3(1024), 256, 0, stream>>>(Qw, Kw, Vw, Aw);
    out_gemm<<<dim3(1024), 256, 0, stream>>>(Aw, Wo, bo, out);
  }
}

// Round 7
// 555.972 us; speedup vs baseline: 2.3234x; 1.0177x over previous
//
#include <hip/hip_runtime.h>

// MHA: out = softmax((qWq^T)(kWk^T)^T/sqrt(128)) (vWv^T) Wo^T + bo
// B=4 T=2048 E=2048 H=16 D=128. All GEMMs via bf16 MFMA (fp32 accum).
// GEMMs: 256x256 tile, BK=64, 8-phase counted-vmcnt schedule (T2+T3+T4+T5).
// V is produced TRANSPOSED [b,h,d,t] so attn stages it like K (no reg transpose).

typedef __attribute__((ext_vector_type(4))) float f32x4;
typedef __attribute__((ext_vector_type(2))) float f32x2;
typedef __attribute__((ext_vector_type(8))) __bf16 bf16x8;
typedef __attribute__((ext_vector_type(4))) unsigned int u32x4;
typedef __attribute__((ext_vector_type(2))) unsigned int u32x2;

#define DEVI static __device__ __forceinline__

DEVI unsigned short f2bf(float f) {            // RNE fp32 -> bf16
  union { float f; unsigned u; } x; x.f = f;
  unsigned u = x.u;
  return (unsigned short)((u + 0x7fffu + ((u >> 16) & 1u)) >> 16);
}
DEVI unsigned int pack2(float lo, float hi) {
  return (unsigned int)f2bf(lo) | ((unsigned int)f2bf(hi) << 16);
}
DEVI u32x4 pack8(const f32x4 a, const f32x4 b) {
  u32x4 r;
  r[0] = pack2(a[0], a[1]); r[1] = pack2(a[2], a[3]);
  r[2] = pack2(b[0], b[1]); r[3] = pack2(b[2], b[3]);
  return r;
}
DEVI void gload16(const unsigned short* g, unsigned short* l) {
  __builtin_amdgcn_global_load_lds(
      (const __attribute__((address_space(1))) unsigned int*)g,
      (__attribute__((address_space(3))) unsigned int*)l, 16, 0, 0);
}

// DPP cross-lane (VALU-rate)
template <int CTRL> DEVI float dppf(float x) {
  return __builtin_bit_cast(float, __builtin_amdgcn_update_dpp(
      __builtin_bit_cast(int, x), __builtin_bit_cast(int, x), CTRL, 0xF, 0xF, true));
}
DEVI float rowmax16(float x) {   // row_ror:1,2,4,8 fold within 16-lane row
  x = fmaxf(x, dppf<0x121>(x));
  x = fmaxf(x, dppf<0x122>(x));
  x = fmaxf(x, dppf<0x124>(x));
  x = fmaxf(x, dppf<0x128>(x));
  return x;
}
DEVI float rowsum16(float x) {
  x += dppf<0x121>(x);
  x += dppf<0x122>(x);
  x += dppf<0x124>(x);
  x += dppf<0x128>(x);
  return x;
}

// ---------------------------------------------------------------------------
// fp32 -> bf16 convert passes
// ---------------------------------------------------------------------------
__global__ __launch_bounds__(256) void convA(
    const float* __restrict__ q, const float* __restrict__ k,
    const float* __restrict__ v, unsigned short* __restrict__ dst)
{
  const int z = blockIdx.z;
  const float* src = z == 0 ? q : (z == 1 ? k : v);
  unsigned short* d = dst + (size_t)z * 16777216;
  size_t i = ((size_t)blockIdx.x * 256 + threadIdx.x) * 8;
  f32x4 a = *(const f32x4*)(src + i);
  f32x4 b = *(const f32x4*)(src + i + 4);
  *(u32x4*)(d + i) = pack8(a, b);
}

__global__ __launch_bounds__(256) void convW(
    const float* __restrict__ w0, const float* __restrict__ w1,
    const float* __restrict__ w2, const float* __restrict__ w3,
    unsigned short* __restrict__ dst)
{
  const int z = blockIdx.z;
  const float* src = z == 0 ? w0 : (z == 1 ? w1 : (z == 2 ? w2 : w3));
  unsigned short* d = dst + (size_t)z * 4194304;
  size_t i = ((size_t)blockIdx.x * 256 + threadIdx.x) * 8;
  f32x4 a = *(const f32x4*)(src + i);
  f32x4 b = *(const f32x4*)(src + i + 4);
  *(u32x4*)(d + i) = pack8(a, b);
}

// ---------------------------------------------------------------------------
// 256x256 8-phase GEMM mainloop (round-6, verified). K=2048, BK=64, 8 waves.
// ---------------------------------------------------------------------------
#define STG2(gp, lp, tile) do { \
    gload16((gp) + (size_t)(tile) * 64,            (lp)); \
    gload16((gp) + (size_t)(tile) * 64 + 8 * 2048, (lp) + 8 * 64); \
  } while (0)
#define LDA8(bufoff, ksbit) { \
    _Pragma("unroll") for (int m = 0; m < 8; m++) \
      a[m] = *(const bf16x8*)(As + (bufoff) + (aoff[m] ^ (ksbit))); }
#define LDB2(bufoff, ksbit, n0) { \
    b0 = *(const bf16x8*)(Bs + (bufoff) + (boff[n0] ^ (ksbit))); \
    b1 = *(const bf16x8*)(Bs + (bufoff) + (boff[(n0) + 1] ^ (ksbit))); }
#define MM2(n0) { \
    __builtin_amdgcn_s_setprio(1); \
    _Pragma("unroll") for (int m = 0; m < 8; m++) { \
      acc[m][n0] = __builtin_amdgcn_mfma_f32_16x16x32_bf16(a[m], b0, acc[m][n0], 0, 0, 0); \
      acc[m][(n0) + 1] = __builtin_amdgcn_mfma_f32_16x16x32_bf16(a[m], b1, acc[m][(n0) + 1], 0, 0, 0); \
    } \
    __builtin_amdgcn_s_setprio(0); }
#define BARX() { __builtin_amdgcn_sched_barrier(0); __builtin_amdgcn_s_barrier(); }
#define WVM(n) asm volatile("s_waitcnt vmcnt(" #n ")" ::: "memory");

DEVI void gemm256_bf16(const unsigned short* __restrict__ A,
                       const unsigned short* __restrict__ Bm,
                       unsigned short* As, unsigned short* Bs,
                       int bm, int bn, int tid, f32x4 (&acc)[8][4])
{
  const int lane = tid & 63, w = tid >> 6;
  const int wm = w >> 2, wn = w & 3;
  const int sr = lane >> 3;
  const int sc = (lane & 7) ^ sr;
  const unsigned short* gA0 = A  + (size_t)(bm * 256 +   0 + w * 16 + sr) * 2048 + sc * 8;
  const unsigned short* gA1 = A  + (size_t)(bm * 256 + 128 + w * 16 + sr) * 2048 + sc * 8;
  const unsigned short* gB0 = Bm + (size_t)(bn * 256 +   0 + w * 16 + sr) * 2048 + sc * 8;
  const unsigned short* gB1 = Bm + (size_t)(bn * 256 + 128 + w * 16 + sr) * 2048 + sc * 8;
  unsigned short* lA00 = As +         (  0 + w * 16) * 64;
  unsigned short* lA01 = As +         (128 + w * 16) * 64;
  unsigned short* lA10 = As + 16384 + (  0 + w * 16) * 64;
  unsigned short* lA11 = As + 16384 + (128 + w * 16) * 64;
  unsigned short* lB00 = Bs +         (  0 + w * 16) * 64;
  unsigned short* lB01 = Bs +         (128 + w * 16) * 64;
  unsigned short* lB10 = Bs + 16384 + (  0 + w * 16) * 64;
  unsigned short* lB11 = Bs + 16384 + (128 + w * 16) * 64;

  const int fr = lane & 15, fk = lane >> 4;
  const int swz = (fk ^ (lane & 7)) << 3;
  int aoff[8], boff[4];
#pragma unroll
  for (int m = 0; m < 8; m++) aoff[m] = (wm * 128 + m * 16 + fr) * 64 + swz;
#pragma unroll
  for (int n = 0; n < 4; n++) boff[n] = (wn * 64 + n * 16 + fr) * 64 + swz;

  bf16x8 a[8], b0, b1;

  STG2(gA0, lA00, 0); STG2(gA1, lA01, 0); STG2(gB0, lB00, 0); STG2(gB1, lB01, 0);
  STG2(gA0, lA10, 1);
  WVM(2) BARX()

  for (int t = 0; t < 30; t += 2) {
    LDA8(0, 0) LDB2(0, 0, 0) STG2(gA1, lA11, t + 1);
    BARX() MM2(0) BARX()
    LDB2(0, 0, 2) STG2(gB0, lB10, t + 1);
    BARX() MM2(2) BARX()
    LDA8(0, 32) LDB2(0, 32, 0) STG2(gB1, lB11, t + 1);
    BARX() MM2(0) BARX()
    LDB2(0, 32, 2) STG2(gA0, lA00, t + 2);
    BARX() MM2(2) WVM(2) BARX()
    LDA8(16384, 0) LDB2(16384, 0, 0) STG2(gA1, lA01, t + 2);
    BARX() MM2(0) BARX()
    LDB2(16384, 0, 2) STG2(gB0, lB00, t + 2);
    BARX() MM2(2) BARX()
    LDA8(16384, 32) LDB2(16384, 32, 0) STG2(gB1, lB01, t + 2);
    BARX() MM2(0) BARX()
    LDB2(16384, 32, 2) STG2(gA0, lA10, t + 3);
    BARX() MM2(2) WVM(2) BARX()
  }
  LDA8(0, 0) LDB2(0, 0, 0) STG2(gA1, lA11, 31);
  BARX() MM2(0) BARX()
  LDB2(0, 0, 2) STG2(gB0, lB10, 31);
  BARX() MM2(2) BARX()
  LDA8(0, 32) LDB2(0, 32, 0) STG2(gB1, lB11, 31);
  BARX() MM2(0) BARX()
  LDB2(0, 32, 2)
  BARX() MM2(2) WVM(0) BARX()
  LDA8(16384, 0) LDB2(16384, 0, 0)
  BARX() MM2(0) BARX()
  LDB2(16384, 0, 2)
  BARX() MM2(2) BARX()
  LDA8(16384, 32) LDB2(16384, 32, 0)
  BARX() MM2(0) BARX()
  LDB2(16384, 32, 2)
  BARX() MM2(2)
}

DEVI int xcd_swz256(int bid) { return ((bid & 7) << 5) | (bid >> 3); }

// ---------------------------------------------------------------------------
// Kernel 1: QKV projection. Q,K out [B,H,T,D]; V out TRANSPOSED [B,H,D,T].
// ---------------------------------------------------------------------------
__global__ __launch_bounds__(512, 2) void qkv_gemm_bf(
    const unsigned short* __restrict__ Abf, const unsigned short* __restrict__ Wbf,
    unsigned short* __restrict__ O0, unsigned short* __restrict__ O1,
    unsigned short* __restrict__ O2)
{
  __shared__ unsigned short As[2 * 256 * 64];
  __shared__ unsigned short Bs[2 * 256 * 64];
  const int z = blockIdx.z;
  const unsigned short* A = Abf + (size_t)z * 16777216;
  const unsigned short* W = Wbf + (size_t)z * 4194304;
  unsigned short* O = z == 0 ? O0 : (z == 1 ? O1 : O2);

  const int tid = threadIdx.x;
  const int lane = tid & 63, w = tid >> 6;
  const int wm = w >> 2, wn = w & 3;
  const int bs = xcd_swz256(blockIdx.x);
  const int bm = bs >> 3, bn = bs & 7;

  f32x4 acc[8][4];
#pragma unroll
  for (int m = 0; m < 8; m++)
#pragma unroll
    for (int n = 0; n < 4; n++) acc[m][n] = (f32x4)(0.0f);

  gemm256_bf16(A, W, As, Bs, bm, bn, tid, acc);

  if (z == 2) {
    // transposed V epilogue: j=0..3 are 4 consecutive t at fixed d -> 8B store
#pragma unroll
    for (int m = 0; m < 8; m++) {
      int rowg = bm * 256 + wm * 128 + m * 16 + (lane >> 4) * 4;
      int bb = rowg >> 11, t0 = rowg & 2047;
#pragma unroll
      for (int n = 0; n < 4; n++) {
        int col = bn * 256 + wn * 64 + n * 16 + (lane & 15);
        int hh = col >> 7, dd = col & 127;
        u32x2 wv;
        wv[0] = pack2(acc[m][n][0], acc[m][n][1]);
        wv[1] = pack2(acc[m][n][2], acc[m][n][3]);
        *(u32x2*)(O + (((size_t)(bb * 16 + hh) * 128 + dd) << 11) + t0) = wv;
      }
    }
    return;
  }

  const bool evenlane = (lane & 1) == 0;
#pragma unroll
  for (int m = 0; m < 8; m++) {
    int rowg = bm * 256 + wm * 128 + m * 16 + (lane >> 4) * 4;
#pragma unroll
    for (int n = 0; n < 4; n += 2) {
#pragma unroll
      for (int j = 0; j < 4; j++) {
        float v0 = acc[m][n][j], v1 = acc[m][n + 1][j];
        float p0 = __shfl_xor(v0, 1);
        float p1 = __shfl_xor(v1, 1);
        int row = rowg + j;
        int b = row >> 11, t = row & 2047;
        int colbase = bn * 256 + wn * 64;
        int col = evenlane ? (colbase + n * 16 + (lane & 15))
                           : (colbase + (n + 1) * 16 + (lane & 15) - 1);
        unsigned int wv = evenlane ? pack2(v0, p0) : pack2(p1, v1);
        int h = col >> 7, d = col & 127;
        *(unsigned int*)(O + (((size_t)(b * 16 + h) * 2048 + t) << 7) + d) = wv;
      }
    }
  }
}

// ---------------------------------------------------------------------------
// Kernel 3: output projection from bf16 attout + bf16 Wo. fp32 out + bias.
// ---------------------------------------------------------------------------
__global__ __launch_bounds__(512, 2) void out_gemm_bf(
    const unsigned short* __restrict__ Ab, const unsigned short* __restrict__ Wb,
    const float* __restrict__ bias, float* __restrict__ Out)
{
  __shared__ unsigned short As[2 * 256 * 64];
  __shared__ unsigned short Bs[2 * 256 * 64];
  const int tid = threadIdx.x;
  const int lane = tid & 63, w = tid >> 6;
  const int wm = w >> 2, wn = w & 3;
  const int bs = xcd_swz256(blockIdx.x);
  const int bm = bs >> 3, bn = bs & 7;

  f32x4 acc[8][4];
#pragma unroll
  for (int m = 0; m < 8; m++)
#pragma unroll
    for (int n = 0; n < 4; n++) acc[m][n] = (f32x4)(0.0f);

  gemm256_bf16(Ab, Wb, As, Bs, bm, bn, tid, acc);

  float bv[4];
#pragma unroll
  for (int n = 0; n < 4; n++) bv[n] = bias[bn * 256 + wn * 64 + n * 16 + (lane & 15)];
  const bool evenlane = (lane & 1) == 0;
#pragma unroll
  for (int m = 0; m < 8; m++) {
    int rowg = bm * 256 + wm * 128 + m * 16 + (lane >> 4) * 4;
#pragma unroll
    for (int n = 0; n < 4; n += 2) {
#pragma unroll
      for (int j = 0; j < 4; j++) {
        float v0 = acc[m][n][j] + bv[n];
        float v1 = acc[m][n + 1][j] + bv[n + 1];
        float p0 = __shfl_xor(v0, 1);
        float p1 = __shfl_xor(v1, 1);
        int row = rowg + j;
        int colbase = bn * 256 + wn * 64;
        int col = evenlane ? (colbase + n * 16 + (lane & 15))
                           : (colbase + (n + 1) * 16 + (lane & 15) - 1);
        f32x2 wv;
        if (evenlane) { wv[0] = v0; wv[1] = p0; }
        else          { wv[0] = p1; wv[1] = v1; }
        *(f32x2*)(Out + (size_t)row * 2048 + col) = wv;
      }
    }
  }
}

// ---------------------------------------------------------------------------
// Fallback kernel 1: fused QKV with in-kernel pack; V out transposed [B,H,D,T].
// ---------------------------------------------------------------------------
__global__ __launch_bounds__(256) void qkv_gemm(
    const float* __restrict__ A0, const float* __restrict__ A1, const float* __restrict__ A2,
    const float* __restrict__ W0, const float* __restrict__ W1, const float* __restrict__ W2,
    unsigned short* __restrict__ O0, unsigned short* __restrict__ O1, unsigned short* __restrict__ O2)
{
  __shared__ unsigned short As[128 * 32];
  __shared__ unsigned short Bs[128 * 32];
  const int z = blockIdx.z;
  const float* A = z == 0 ? A0 : (z == 1 ? A1 : A2);
  const float* W = z == 0 ? W0 : (z == 1 ? W1 : W2);
  unsigned short* O = z == 0 ? O0 : (z == 1 ? O1 : O2);

  const int tid = threadIdx.x;
  const int lane = tid & 63;
  const int wave = tid >> 6;
  const int wm = wave >> 1, wn = wave & 1;
  const int bm = blockIdx.x >> 4, bn = blockIdx.x & 15;

  const int srow = tid >> 1;
  const int shalf = tid & 1;
  const float* Ap = A + (size_t)(bm * 128 + srow) * 2048 + shalf * 16;
  const float* Wp = W + (size_t)(bn * 128 + srow) * 2048 + shalf * 16;
  const int ssw = (srow >> 1) & 3;
  const int aoff0 = srow * 32 + (((shalf * 2 + 0) ^ ssw) << 3);
  const int aoff1 = srow * 32 + (((shalf * 2 + 1) ^ ssw) << 3);

  const int frow = lane & 15;
  const int fk = lane >> 4;

  f32x4 acc[4][4];
#pragma unroll
  for (int m = 0; m < 4; m++)
#pragma unroll
    for (int n = 0; n < 4; n++) acc[m][n] = (f32x4)(0.0f);

  for (int kk = 0; kk < 2048; kk += 32) {
    f32x4 a0 = *(const f32x4*)(Ap + kk);
    f32x4 a1 = *(const f32x4*)(Ap + kk + 4);
    f32x4 a2 = *(const f32x4*)(Ap + kk + 8);
    f32x4 a3 = *(const f32x4*)(Ap + kk + 12);
    f32x4 b0 = *(const f32x4*)(Wp + kk);
    f32x4 b1 = *(const f32x4*)(Wp + kk + 4);
    f32x4 b2 = *(const f32x4*)(Wp + kk + 8);
    f32x4 b3 = *(const f32x4*)(Wp + kk + 12);
    __syncthreads();
    *(u32x4*)(As + aoff0) = pack8(a0, a1);
    *(u32x4*)(As + aoff1) = pack8(a2, a3);
    *(u32x4*)(Bs + aoff0) = pack8(b0, b1);
    *(u32x4*)(Bs + aoff1) = pack8(b2, b3);
    __syncthreads();
    bf16x8 af[4], bfr[4];
#pragma unroll
    for (int m = 0; m < 4; m++) {
      int r = wm * 64 + m * 16 + frow;
      af[m] = *(const bf16x8*)(As + r * 32 + ((fk ^ ((r >> 1) & 3)) << 3));
    }
#pragma unroll
    for (int n = 0; n < 4; n++) {
      int r = wn * 64 + n * 16 + frow;
      bfr[n] = *(const bf16x8*)(Bs + r * 32 + ((fk ^ ((r >> 1) & 3)) << 3));
    }
#pragma unroll
    for (int m = 0; m < 4; m++)
#pragma unroll
      for (int n = 0; n < 4; n++)
        acc[m][n] = __builtin_amdgcn_mfma_f32_16x16x32_bf16(af[m], bfr[n], acc[m][n], 0, 0, 0);
  }

  if (z == 2) {
#pragma unroll
    for (int m = 0; m < 4; m++) {
      int rowg = bm * 128 + wm * 64 + m * 16 + (lane >> 4) * 4;
      int bb = rowg >> 11, t0 = rowg & 2047;
#pragma unroll
      for (int n = 0; n < 4; n++) {
        int col = bn * 128 + wn * 64 + n * 16 + (lane & 15);
        int hh = col >> 7, dd = col & 127;
        u32x2 wv;
        wv[0] = pack2(acc[m][n][0], acc[m][n][1]);
        wv[1] = pack2(acc[m][n][2], acc[m][n][3]);
        *(u32x2*)(O + (((size_t)(bb * 16 + hh) * 128 + dd) << 11) + t0) = wv;
      }
    }
    return;
  }

  const bool evenlane = (lane & 1) == 0;
#pragma unroll
  for (int m = 0; m < 4; m++) {
    int rowg = bm * 128 + wm * 64 + m * 16 + (lane >> 4) * 4;
#pragma unroll
    for (int n = 0; n < 4; n += 2) {
#pragma unroll
      for (int j = 0; j < 4; j++) {
        float v0 = acc[m][n][j], v1 = acc[m][n + 1][j];
        float p0 = __shfl_xor(v0, 1);
        float p1 = __shfl_xor(v1, 1);
        int row = rowg + j;
        int b = row >> 11, t = row & 2047;
        int colbase = bn * 128 + wn * 64;
        int col = evenlane ? (colbase + n * 16 + (lane & 15))
                           : (colbase + (n + 1) * 16 + (lane & 15) - 1);
        unsigned int wv = evenlane ? pack2(v0, p0) : pack2(p1, v1);
        int h = col >> 7, d = col & 127;
        *(unsigned int*)(O + (((size_t)(b * 16 + h) * 2048 + t) << 7) + d) = wv;
      }
    }
  }
}

// ---------------------------------------------------------------------------
// Kernel 2: flash attention v4. V^T staged via global_load_lds (like K);
// P-pack via quad_perm DPP + v_cvt_pk_bf16_f32, even lanes write u32.
// ---------------------------------------------------------------------------
__global__ __launch_bounds__(256, 2) void attn(
    const unsigned short* __restrict__ Qw, const unsigned short* __restrict__ Kw,
    const unsigned short* __restrict__ VwT, unsigned short* __restrict__ attout)
{
  __shared__ unsigned short Ks[2][64 * 128];   // [key][d], slot swizzle s^(row&15)
  __shared__ unsigned short Vs[2][128 * 64];   // V^T [d][key], slot swizzle s^(row&7)
  __shared__ unsigned short Ps[128 * 64];      // P [q][key], slot swizzle s^(row&7)

  const int bid = blockIdx.x;
  const int work = ((bid & 7) << 7) | (bid >> 3);
  const int bh = work >> 4;
  const int qtile = work & 15;
  const int b = bh >> 4, h = bh & 15;
  const unsigned short* Qbase = Qw + (size_t)bh * 2048 * 128 + qtile * 128 * 128;
  const unsigned short* Kbase = Kw + (size_t)bh * 2048 * 128;
  const unsigned short* VbaseT = VwT + (size_t)bh * 2048 * 128;  // [d][t]
  const int tid = threadIdx.x, lane = tid & 63, w = tid >> 6;
  const int frow = lane & 15, fk = lane >> 4;

  bf16x8 qf[2][4];
#pragma unroll
  for (int m = 0; m < 2; m++)
#pragma unroll
    for (int ks = 0; ks < 4; ks++)
      qf[m][ks] = *(const bf16x8*)(Qbase + (size_t)(w * 32 + m * 16 + frow) * 128 + ks * 32 + fk * 8);

  const int krow_i = lane >> 4;              // K: row-in-issue
  const int kslot = lane & 15;
  const int vrow_i = lane >> 3;              // V: row-in-issue (8 rows/issue)
  const int vslot = (lane & 7) ^ vrow_i;     // pre-swizzled V chunk

  f32x4 o[2][8];
#pragma unroll
  for (int m = 0; m < 2; m++)
#pragma unroll
    for (int n = 0; n < 8; n++) o[m][n] = (f32x4)(0.0f);
  float m_r[2][4], l_r[2][4];
#pragma unroll
  for (int m = 0; m < 2; m++)
#pragma unroll
    for (int j = 0; j < 4; j++) { m_r[m][j] = -INFINITY; l_r[m][j] = 0.f; }
  const float SC = 0.12751721769f;   // log2(e)/sqrt(128)
  const float THR = 90.5f;           // defer-max threshold

  // ---- prologue: stage tile 0
  {
#pragma unroll
    for (int i = 0; i < 4; i++) {
      int row = w * 16 + i * 4 + krow_i;
      gload16(Kbase + (size_t)row * 128 + ((kslot ^ (row & 15)) << 3),
              &Ks[0][(w * 16 + i * 4) * 128]);
    }
#pragma unroll
    for (int i = 0; i < 4; i++) {
      int d = w * 32 + i * 8 + vrow_i;
      gload16(VbaseT + (size_t)d * 2048 + vslot * 8,
              &Vs[0][(w * 32 + i * 8) * 64]);
    }
  }

  for (int kt = 0; kt < 32; kt++) {
    const int cur = kt & 1;
    __syncthreads();   // buf[cur] staged; prior reads of buf[cur^1] done

    const bool have_next = (kt + 1) < 32;
    if (have_next) {
      const unsigned short* Kt = Kbase + (kt + 1) * 64 * 128;
#pragma unroll
      for (int i = 0; i < 4; i++) {
        int row = w * 16 + i * 4 + krow_i;
        gload16(Kt + (size_t)row * 128 + ((kslot ^ (row & 15)) << 3),
                &Ks[cur ^ 1][(w * 16 + i * 4) * 128]);
      }
#pragma unroll
      for (int i = 0; i < 4; i++) {
        int d = w * 32 + i * 8 + vrow_i;
        gload16(VbaseT + (size_t)d * 2048 + (kt + 1) * 64 + vslot * 8,
                &Vs[cur ^ 1][(w * 32 + i * 8) * 64]);
      }
    }

    // ---- S = Q K^T
    f32x4 s[2][4];
#pragma unroll
    for (int m = 0; m < 2; m++)
#pragma unroll
      for (int n = 0; n < 4; n++) s[m][n] = (f32x4)(0.0f);
    __builtin_amdgcn_s_setprio(1);
#pragma unroll
    for (int ks = 0; ks < 4; ks++) {
#pragma unroll
      for (int n = 0; n < 4; n++) {
        int brow = n * 16 + frow;
        bf16x8 bk = *(const bf16x8*)(&Ks[cur][0] + brow * 128 + (((ks * 4 + fk) ^ (brow & 15)) << 3));
#pragma unroll
        for (int m = 0; m < 2; m++)
          s[m][n] = __builtin_amdgcn_mfma_f32_16x16x32_bf16(qf[m][ks], bk, s[m][n], 0, 0, 0);
      }
    }
    __builtin_amdgcn_s_setprio(0);

    // ---- online softmax + P pack/write
#pragma unroll
    for (int m = 0; m < 2; m++) {
#pragma unroll
      for (int j = 0; j < 4; j++) {
        float mx = fmaxf(fmaxf(s[m][0][j], s[m][1][j]), fmaxf(s[m][2][j], s[m][3][j]));
        mx = rowmax16(mx);
        float mo = m_r[m][j];
        if (!__all(mx - mo <= THR)) {
          float mnew = fmaxf(mo, mx);
          float f = __builtin_amdgcn_exp2f((mo - mnew) * SC);
          m_r[m][j] = mnew;
          l_r[m][j] *= f;
#pragma unroll
          for (int n = 0; n < 8; n++) o[m][n][j] *= f;
        }
        float mm = m_r[m][j];
        float psum = 0.f;
#pragma unroll
        for (int n = 0; n < 4; n++) {
          float p = __builtin_amdgcn_exp2f((s[m][n][j] - mm) * SC);
          s[m][n][j] = p;
          psum += p;
        }
        l_r[m][j] += rowsum16(psum);

        // pack cols pairwise: partner via quad_perm [1,0,3,2]; even lanes store
        int row = w * 32 + m * 16 + (lane >> 4) * 4 + j;
        int swzp = row & 7;
        unsigned prv[4];
#pragma unroll
        for (int n = 0; n < 4; n++) {
          float p = s[m][n][j];
          float ph = dppf<0xB1>(p);
          unsigned pr;
          asm("v_cvt_pk_bf16_f32 %0, %1, %2" : "=v"(pr) : "v"(p), "v"(ph));
          prv[n] = pr;
        }
        if (!(lane & 1)) {
#pragma unroll
          for (int n = 0; n < 4; n++) {
            int col = frow + 16 * n;   // even
            *(unsigned*)((char*)Ps + row * 128 + (((col >> 3) ^ swzp) << 4) + (col & 7) * 2) = prv[n];
          }
        }
      }
    }

    // ---- O += P V
    __builtin_amdgcn_s_setprio(1);
#pragma unroll
    for (int ks = 0; ks < 2; ks++) {
      bf16x8 ap[2];
#pragma unroll
      for (int m = 0; m < 2; m++) {
        int arow = w * 32 + m * 16 + frow;
        ap[m] = *(const bf16x8*)((char*)Ps + arow * 128 + (((ks * 4 + fk) ^ (arow & 7)) << 4));
      }
#pragma unroll
      for (int n = 0; n < 8; n++) {
        int vrow = n * 16 + frow;
        bf16x8 bv = *(const bf16x8*)((char*)&Vs[cur][0] + vrow * 128 + (((ks * 4 + fk) ^ (vrow & 7)) << 4));
#pragma unroll
        for (int m = 0; m < 2; m++)
          o[m][n] = __builtin_amdgcn_mfma_f32_16x16x32_bf16(ap[m], bv, o[m][n], 0, 0, 0);
      }
    }
    __builtin_amdgcn_s_setprio(0);
  }

  // ---- epilogue
  const bool evenlane = (lane & 1) == 0;
#pragma unroll
  for (int m = 0; m < 2; m++) {
    float inv[4];
#pragma unroll
    for (int j = 0; j < 4; j++) inv[j] = 1.0f / l_r[m][j];
#pragma unroll
    for (int n = 0; n < 8; n += 2) {
#pragma unroll
      for (int j = 0; j < 4; j++) {
        float v0 = o[m][n][j] * inv[j], v1 = o[m][n + 1][j] * inv[j];
        float p0 = __shfl_xor(v0, 1);
        float p1 = __shfl_xor(v1, 1);
        int tq = qtile * 128 + w * 32 + m * 16 + (lane >> 4) * 4 + j;
        int col = evenlane ? (n * 16 + (lane & 15)) : ((n + 1) * 16 + (lane & 15) - 1);
        unsigned int wv = evenlane ? pack2(v0, p0) : pack2(p1, v1);
        *(unsigned int*)(attout + (size_t)(b * 2048 + tq) * 2048 + h * 128 + col) = wv;
      }
    }
  }
}

// ---------------------------------------------------------------------------
// Fallback kernel 3 (round-1): output projection with in-kernel fp32 W pack.
// ---------------------------------------------------------------------------
__global__ __launch_bounds__(256) void out_gemm(
    const unsigned short* __restrict__ Ab, const float* __restrict__ W,
    const float* __restrict__ bias, float* __restrict__ Out)
{
  __shared__ unsigned short As[128 * 32];
  __shared__ unsigned short Bs[128 * 32];

  const int tid = threadIdx.x;
  const int lane = tid & 63;
  const int wave = tid >> 6;
  const int wm = wave >> 1, wn = wave & 1;
  const int bm = blockIdx.x >> 4, bn = blockIdx.x & 15;

  const int srow = tid >> 1;
  const int shalf = tid & 1;
  const unsigned short* Ap = Ab + (size_t)(bm * 128 + srow) * 2048 + shalf * 16;
  const float* Wp = W + (size_t)(bn * 128 + srow) * 2048 + shalf * 16;
  const int ssw = (srow >> 1) & 3;
  const int aoff0 = srow * 32 + (((shalf * 2 + 0) ^ ssw) << 3);
  const int aoff1 = srow * 32 + (((shalf * 2 + 1) ^ ssw) << 3);

  const int frow = lane & 15;
  const int fk = lane >> 4;

  f32x4 acc[4][4];
#pragma unroll
  for (int m = 0; m < 4; m++)
#pragma unroll
    for (int n = 0; n < 4; n++) acc[m][n] = (f32x4)(0.0f);

  for (int kk = 0; kk < 2048; kk += 32) {
    u32x4 a0 = *(const u32x4*)(Ap + kk);
    u32x4 a1 = *(const u32x4*)(Ap + kk + 8);
    f32x4 b0 = *(const f32x4*)(Wp + kk);
    f32x4 b1 = *(const f32x4*)(Wp + kk + 4);
    f32x4 b2 = *(const f32x4*)(Wp + kk + 8);
    f32x4 b3 = *(const f32x4*)(Wp + kk + 12);
    __syncthreads();
    *(u32x4*)(As + aoff0) = a0;
    *(u32x4*)(As + aoff1) = a1;
    *(u32x4*)(Bs + aoff0) = pack8(b0, b1);
    *(u32x4*)(Bs + aoff1) = pack8(b2, b3);
    __syncthreads();
    bf16x8 af[4], bfr[4];
#pragma unroll
    for (int m = 0; m < 4; m++) {
      int r = wm * 64 + m * 16 + frow;
      af[m] = *(const bf16x8*)(As + r * 32 + ((fk ^ ((r >> 1) & 3)) << 3));
    }
#pragma unroll
    for (int n = 0; n < 4; n++) {
      int r = wn * 64 + n * 16 + frow;
      bfr[n] = *(const bf16x8*)(Bs + r * 32 + ((fk ^ ((r >> 1) & 3)) << 3));
    }
#pragma unroll
    for (int m = 0; m < 4; m++)
#pragma unroll
      for (int n = 0; n < 4; n++)
        acc[m][n] = __builtin_amdgcn_mfma_f32_16x16x32_bf16(af[m], bfr[n], acc[m][n], 0, 0, 0);
  }

  float bv[4];
#pragma unroll
  for (int n = 0; n < 4; n++) bv[n] = bias[bn * 128 + wn * 64 + n * 16 + (lane & 15)];
  const bool evenlane = (lane & 1) == 0;
#pragma unroll
  for (int m = 0; m < 4; m++) {
    int rowg = bm * 128 + wm * 64 + m * 16 + (lane >> 4) * 4;
#pragma unroll
    for (int n = 0; n < 4; n += 2) {
#pragma unroll
      for (int j = 0; j < 4; j++) {
        float v0 = acc[m][n][j] + bv[n];
        float v1 = acc[m][n + 1][j] + bv[n + 1];
        float p0 = __shfl_xor(v0, 1);
        float p1 = __shfl_xor(v1, 1);
        int row = rowg + j;
        int colbase = bn * 128 + wn * 64;
        int col = evenlane ? (colbase + n * 16 + (lane & 15))
                           : (colbase + (n + 1) * 16 + (lane & 15) - 1);
        f32x2 wv;
        if (evenlane) { wv[0] = v0; wv[1] = p0; }
        else          { wv[0] = p1; wv[1] = v1; }
        *(f32x2*)(Out + (size_t)row * 2048 + col) = wv;
      }
    }
  }
}

// ---------------------------------------------------------------------------
extern "C" void kernel_launch(void* const* d_in, const int* in_sizes, int n_in,
                              void* d_out, int out_size, void* d_ws, size_t ws_size,
                              hipStream_t stream)
{
  // setup_inputs order: k, q, v, Wk, Wq, Wv, Wo, bo
  const float* k  = (const float*)d_in[0];
  const float* q  = (const float*)d_in[1];
  const float* v  = (const float*)d_in[2];
  const float* Wk = (const float*)d_in[3];
  const float* Wq = (const float*)d_in[4];
  const float* Wv = (const float*)d_in[5];
  const float* Wo = (const float*)d_in[6];
  const float* bo = (const float*)d_in[7];
  float* out = (float*)d_out;

  const size_t HSZ = (size_t)4 * 16 * 2048 * 128;   // 32 MiB (bf16 elems)

  if (ws_size >= (size_t)224 << 20) {
    unsigned short* Abf = (unsigned short*)d_ws;
    unsigned short* Wbf = Abf + 3 * HSZ;
    unsigned short* Qw  = Wbf + 4 * 4194304;
    unsigned short* Kw  = Qw + HSZ;
    unsigned short* Vw  = Kw + HSZ;       // V stored TRANSPOSED [b,h,d,t]
    unsigned short* Aw  = Abf;

    convA<<<dim3(8192, 1, 3), 256, 0, stream>>>(q, k, v, Abf);
    convW<<<dim3(2048, 1, 4), 256, 0, stream>>>(Wq, Wk, Wv, Wo, Wbf);
    qkv_gemm_bf<<<dim3(256, 1, 3), 512, 0, stream>>>(Abf, Wbf, Qw, Kw, Vw);
    attn<<<dim3(1024), 256, 0, stream>>>(Qw, Kw, Vw, Aw);
    out_gemm_bf<<<dim3(256), 512, 0, stream>>>(Aw, Wbf + 3 * 4194304, bo, out);
  } else {
    unsigned short* Qw = (unsigned short*)d_ws;
    unsigned short* Kw = Qw + HSZ;
    unsigned short* Vw = Kw + HSZ;        // transposed V here too
    unsigned short* Aw = Vw + HSZ;
    qkv_gemm<<<dim3(1024, 1, 3), 256, 0, stream>>>(q, k, v, Wq, Wk, Wv, Qw, Kw, Vw);
    attn<<<dim3(1024), 256, 0, stream>>>(Qw, Kw, Vw, Aw);
    out_gemm<<<dim3(1024), 256, 0, stream>>>(Aw, Wo, bo, out);
  }
}

// Round 8
// 524.777 us; speedup vs baseline: 2.4615x; 1.0594x over previous
//
#include <hip/hip_runtime.h>

// MHA: out = softmax((qWq^T)(kWk^T)^T/sqrt(128)) (vWv^T) Wo^T + bo
// B=4 T=2048 E=2048 H=16 D=128. All GEMMs via bf16 MFMA (fp32 accum).
// GEMMs: 256x256 tile, BK=64, 8-phase counted-vmcnt schedule (T2+T3+T4+T5).
// V produced TRANSPOSED [b,h,d,t]; Q produced PRE-SCALED by log2(e)/sqrt(128)
// so attn softmax runs in log2-space (exp2(s-m), no per-element multiply).

typedef __attribute__((ext_vector_type(4))) float f32x4;
typedef __attribute__((ext_vector_type(2))) float f32x2;
typedef __attribute__((ext_vector_type(8))) __bf16 bf16x8;
typedef __attribute__((ext_vector_type(4))) unsigned int u32x4;
typedef __attribute__((ext_vector_type(2))) unsigned int u32x2;

#define DEVI static __device__ __forceinline__

#define SCQ 0.12751721769f   // log2(e)/sqrt(128)

DEVI unsigned short f2bf(float f) {            // RNE fp32 -> bf16
  union { float f; unsigned u; } x; x.f = f;
  unsigned u = x.u;
  return (unsigned short)((u + 0x7fffu + ((u >> 16) & 1u)) >> 16);
}
DEVI unsigned int pack2(float lo, float hi) {
  return (unsigned int)f2bf(lo) | ((unsigned int)f2bf(hi) << 16);
}
DEVI u32x4 pack8(const f32x4 a, const f32x4 b) {
  u32x4 r;
  r[0] = pack2(a[0], a[1]); r[1] = pack2(a[2], a[3]);
  r[2] = pack2(b[0], b[1]); r[3] = pack2(b[2], b[3]);
  return r;
}
DEVI void gload16(const unsigned short* g, unsigned short* l) {
  __builtin_amdgcn_global_load_lds(
      (const __attribute__((address_space(1))) unsigned int*)g,
      (__attribute__((address_space(3))) unsigned int*)l, 16, 0, 0);
}

// DPP cross-lane (VALU-rate)
template <int CTRL> DEVI float dppf(float x) {
  return __builtin_bit_cast(float, __builtin_amdgcn_update_dpp(
      __builtin_bit_cast(int, x), __builtin_bit_cast(int, x), CTRL, 0xF, 0xF, true));
}
DEVI float rowmax16(float x) {   // row_ror:1,2,4,8 fold within 16-lane row
  x = fmaxf(x, dppf<0x121>(x));
  x = fmaxf(x, dppf<0x122>(x));
  x = fmaxf(x, dppf<0x124>(x));
  x = fmaxf(x, dppf<0x128>(x));
  return x;
}
DEVI float rowsum16(float x) {
  x += dppf<0x121>(x);
  x += dppf<0x122>(x);
  x += dppf<0x124>(x);
  x += dppf<0x128>(x);
  return x;
}

// ---------------------------------------------------------------------------
// fp32 -> bf16 convert passes (q pre-scaled by SCQ)
// ---------------------------------------------------------------------------
__global__ __launch_bounds__(256) void convA(
    const float* __restrict__ q, const float* __restrict__ k,
    const float* __restrict__ v, unsigned short* __restrict__ dst)
{
  const int z = blockIdx.z;
  const float* src = z == 0 ? q : (z == 1 ? k : v);
  const float scl = z == 0 ? SCQ : 1.0f;
  unsigned short* d = dst + (size_t)z * 16777216;
  size_t i = ((size_t)blockIdx.x * 256 + threadIdx.x) * 8;
  f32x4 a = *(const f32x4*)(src + i) * scl;
  f32x4 b = *(const f32x4*)(src + i + 4) * scl;
  *(u32x4*)(d + i) = pack8(a, b);
}

__global__ __launch_bounds__(256) void convW(
    const float* __restrict__ w0, const float* __restrict__ w1,
    const float* __restrict__ w2, const float* __restrict__ w3,
    unsigned short* __restrict__ dst)
{
  const int z = blockIdx.z;
  const float* src = z == 0 ? w0 : (z == 1 ? w1 : (z == 2 ? w2 : w3));
  unsigned short* d = dst + (size_t)z * 4194304;
  size_t i = ((size_t)blockIdx.x * 256 + threadIdx.x) * 8;
  f32x4 a = *(const f32x4*)(src + i);
  f32x4 b = *(const f32x4*)(src + i + 4);
  *(u32x4*)(d + i) = pack8(a, b);
}

// ---------------------------------------------------------------------------
// 256x256 8-phase GEMM mainloop (round-6, verified). K=2048, BK=64, 8 waves.
// ---------------------------------------------------------------------------
#define STG2(gp, lp, tile) do { \
    gload16((gp) + (size_t)(tile) * 64,            (lp)); \
    gload16((gp) + (size_t)(tile) * 64 + 8 * 2048, (lp) + 8 * 64); \
  } while (0)
#define LDA8(bufoff, ksbit) { \
    _Pragma("unroll") for (int m = 0; m < 8; m++) \
      a[m] = *(const bf16x8*)(As + (bufoff) + (aoff[m] ^ (ksbit))); }
#define LDB2(bufoff, ksbit, n0) { \
    b0 = *(const bf16x8*)(Bs + (bufoff) + (boff[n0] ^ (ksbit))); \
    b1 = *(const bf16x8*)(Bs + (bufoff) + (boff[(n0) + 1] ^ (ksbit))); }
#define MM2(n0) { \
    __builtin_amdgcn_s_setprio(1); \
    _Pragma("unroll") for (int m = 0; m < 8; m++) { \
      acc[m][n0] = __builtin_amdgcn_mfma_f32_16x16x32_bf16(a[m], b0, acc[m][n0], 0, 0, 0); \
      acc[m][(n0) + 1] = __builtin_amdgcn_mfma_f32_16x16x32_bf16(a[m], b1, acc[m][(n0) + 1], 0, 0, 0); \
    } \
    __builtin_amdgcn_s_setprio(0); }
#define BARX() { __builtin_amdgcn_sched_barrier(0); __builtin_amdgcn_s_barrier(); }
#define WVM(n) asm volatile("s_waitcnt vmcnt(" #n ")" ::: "memory");

DEVI void gemm256_bf16(const unsigned short* __restrict__ A,
                       const unsigned short* __restrict__ Bm,
                       unsigned short* As, unsigned short* Bs,
                       int bm, int bn, int tid, f32x4 (&acc)[8][4])
{
  const int lane = tid & 63, w = tid >> 6;
  const int wm = w >> 2, wn = w & 3;
  const int sr = lane >> 3;
  const int sc = (lane & 7) ^ sr;
  const unsigned short* gA0 = A  + (size_t)(bm * 256 +   0 + w * 16 + sr) * 2048 + sc * 8;
  const unsigned short* gA1 = A  + (size_t)(bm * 256 + 128 + w * 16 + sr) * 2048 + sc * 8;
  const unsigned short* gB0 = Bm + (size_t)(bn * 256 +   0 + w * 16 + sr) * 2048 + sc * 8;
  const unsigned short* gB1 = Bm + (size_t)(bn * 256 + 128 + w * 16 + sr) * 2048 + sc * 8;
  unsigned short* lA00 = As +         (  0 + w * 16) * 64;
  unsigned short* lA01 = As +         (128 + w * 16) * 64;
  unsigned short* lA10 = As + 16384 + (  0 + w * 16) * 64;
  unsigned short* lA11 = As + 16384 + (128 + w * 16) * 64;
  unsigned short* lB00 = Bs +         (  0 + w * 16) * 64;
  unsigned short* lB01 = Bs +         (128 + w * 16) * 64;
  unsigned short* lB10 = Bs + 16384 + (  0 + w * 16) * 64;
  unsigned short* lB11 = Bs + 16384 + (128 + w * 16) * 64;

  const int fr = lane & 15, fk = lane >> 4;
  const int swz = (fk ^ (lane & 7)) << 3;
  int aoff[8], boff[4];
#pragma unroll
  for (int m = 0; m < 8; m++) aoff[m] = (wm * 128 + m * 16 + fr) * 64 + swz;
#pragma unroll
  for (int n = 0; n < 4; n++) boff[n] = (wn * 64 + n * 16 + fr) * 64 + swz;

  bf16x8 a[8], b0, b1;

  STG2(gA0, lA00, 0); STG2(gA1, lA01, 0); STG2(gB0, lB00, 0); STG2(gB1, lB01, 0);
  STG2(gA0, lA10, 1);
  WVM(2) BARX()

  for (int t = 0; t < 30; t += 2) {
    LDA8(0, 0) LDB2(0, 0, 0) STG2(gA1, lA11, t + 1);
    BARX() MM2(0) BARX()
    LDB2(0, 0, 2) STG2(gB0, lB10, t + 1);
    BARX() MM2(2) BARX()
    LDA8(0, 32) LDB2(0, 32, 0) STG2(gB1, lB11, t + 1);
    BARX() MM2(0) BARX()
    LDB2(0, 32, 2) STG2(gA0, lA00, t + 2);
    BARX() MM2(2) WVM(2) BARX()
    LDA8(16384, 0) LDB2(16384, 0, 0) STG2(gA1, lA01, t + 2);
    BARX() MM2(0) BARX()
    LDB2(16384, 0, 2) STG2(gB0, lB00, t + 2);
    BARX() MM2(2) BARX()
    LDA8(16384, 32) LDB2(16384, 32, 0) STG2(gB1, lB01, t + 2);
    BARX() MM2(0) BARX()
    LDB2(16384, 32, 2) STG2(gA0, lA10, t + 3);
    BARX() MM2(2) WVM(2) BARX()
  }
  LDA8(0, 0) LDB2(0, 0, 0) STG2(gA1, lA11, 31);
  BARX() MM2(0) BARX()
  LDB2(0, 0, 2) STG2(gB0, lB10, 31);
  BARX() MM2(2) BARX()
  LDA8(0, 32) LDB2(0, 32, 0) STG2(gB1, lB11, 31);
  BARX() MM2(0) BARX()
  LDB2(0, 32, 2)
  BARX() MM2(2) WVM(0) BARX()
  LDA8(16384, 0) LDB2(16384, 0, 0)
  BARX() MM2(0) BARX()
  LDB2(16384, 0, 2)
  BARX() MM2(2) BARX()
  LDA8(16384, 32) LDB2(16384, 32, 0)
  BARX() MM2(0) BARX()
  LDB2(16384, 32, 2)
  BARX() MM2(2)
}

DEVI int xcd_swz256(int bid) { return ((bid & 7) << 5) | (bid >> 3); }

// ---------------------------------------------------------------------------
// Kernel 1: QKV projection. Q,K out [B,H,T,D] (Q pre-scaled via convA);
// V out TRANSPOSED [B,H,D,T].
// ---------------------------------------------------------------------------
__global__ __launch_bounds__(512, 2) void qkv_gemm_bf(
    const unsigned short* __restrict__ Abf, const unsigned short* __restrict__ Wbf,
    unsigned short* __restrict__ O0, unsigned short* __restrict__ O1,
    unsigned short* __restrict__ O2)
{
  __shared__ unsigned short As[2 * 256 * 64];
  __shared__ unsigned short Bs[2 * 256 * 64];
  const int z = blockIdx.z;
  const unsigned short* A = Abf + (size_t)z * 16777216;
  const unsigned short* W = Wbf + (size_t)z * 4194304;
  unsigned short* O = z == 0 ? O0 : (z == 1 ? O1 : O2);

  const int tid = threadIdx.x;
  const int lane = tid & 63, w = tid >> 6;
  const int wm = w >> 2, wn = w & 3;
  const int bs = xcd_swz256(blockIdx.x);
  const int bm = bs >> 3, bn = bs & 7;

  f32x4 acc[8][4];
#pragma unroll
  for (int m = 0; m < 8; m++)
#pragma unroll
    for (int n = 0; n < 4; n++) acc[m][n] = (f32x4)(0.0f);

  gemm256_bf16(A, W, As, Bs, bm, bn, tid, acc);

  if (z == 2) {
    // transposed V epilogue: j=0..3 are 4 consecutive t at fixed d -> 8B store
#pragma unroll
    for (int m = 0; m < 8; m++) {
      int rowg = bm * 256 + wm * 128 + m * 16 + (lane >> 4) * 4;
      int bb = rowg >> 11, t0 = rowg & 2047;
#pragma unroll
      for (int n = 0; n < 4; n++) {
        int col = bn * 256 + wn * 64 + n * 16 + (lane & 15);
        int hh = col >> 7, dd = col & 127;
        u32x2 wv;
        wv[0] = pack2(acc[m][n][0], acc[m][n][1]);
        wv[1] = pack2(acc[m][n][2], acc[m][n][3]);
        *(u32x2*)(O + (((size_t)(bb * 16 + hh) * 128 + dd) << 11) + t0) = wv;
      }
    }
    return;
  }

  const bool evenlane = (lane & 1) == 0;
#pragma unroll
  for (int m = 0; m < 8; m++) {
    int rowg = bm * 256 + wm * 128 + m * 16 + (lane >> 4) * 4;
#pragma unroll
    for (int n = 0; n < 4; n += 2) {
#pragma unroll
      for (int j = 0; j < 4; j++) {
        float v0 = acc[m][n][j], v1 = acc[m][n + 1][j];
        float p0 = __shfl_xor(v0, 1);
        float p1 = __shfl_xor(v1, 1);
        int row = rowg + j;
        int b = row >> 11, t = row & 2047;
        int colbase = bn * 256 + wn * 64;
        int col = evenlane ? (colbase + n * 16 + (lane & 15))
                           : (colbase + (n + 1) * 16 + (lane & 15) - 1);
        unsigned int wv = evenlane ? pack2(v0, p0) : pack2(p1, v1);
        int h = col >> 7, d = col & 127;
        *(unsigned int*)(O + (((size_t)(b * 16 + h) * 2048 + t) << 7) + d) = wv;
      }
    }
  }
}

// ---------------------------------------------------------------------------
// Kernel 3: output projection from bf16 attout + bf16 Wo. fp32 out + bias.
// ---------------------------------------------------------------------------
__global__ __launch_bounds__(512, 2) void out_gemm_bf(
    const unsigned short* __restrict__ Ab, const unsigned short* __restrict__ Wb,
    const float* __restrict__ bias, float* __restrict__ Out)
{
  __shared__ unsigned short As[2 * 256 * 64];
  __shared__ unsigned short Bs[2 * 256 * 64];
  const int tid = threadIdx.x;
  const int lane = tid & 63, w = tid >> 6;
  const int wm = w >> 2, wn = w & 3;
  const int bs = xcd_swz256(blockIdx.x);
  const int bm = bs >> 3, bn = bs & 7;

  f32x4 acc[8][4];
#pragma unroll
  for (int m = 0; m < 8; m++)
#pragma unroll
    for (int n = 0; n < 4; n++) acc[m][n] = (f32x4)(0.0f);

  gemm256_bf16(Ab, Wb, As, Bs, bm, bn, tid, acc);

  float bv[4];
#pragma unroll
  for (int n = 0; n < 4; n++) bv[n] = bias[bn * 256 + wn * 64 + n * 16 + (lane & 15)];
  const bool evenlane = (lane & 1) == 0;
#pragma unroll
  for (int m = 0; m < 8; m++) {
    int rowg = bm * 256 + wm * 128 + m * 16 + (lane >> 4) * 4;
#pragma unroll
    for (int n = 0; n < 4; n += 2) {
#pragma unroll
      for (int j = 0; j < 4; j++) {
        float v0 = acc[m][n][j] + bv[n];
        float v1 = acc[m][n + 1][j] + bv[n + 1];
        float p0 = __shfl_xor(v0, 1);
        float p1 = __shfl_xor(v1, 1);
        int row = rowg + j;
        int colbase = bn * 256 + wn * 64;
        int col = evenlane ? (colbase + n * 16 + (lane & 15))
                           : (colbase + (n + 1) * 16 + (lane & 15) - 1);
        f32x2 wv;
        if (evenlane) { wv[0] = v0; wv[1] = p0; }
        else          { wv[0] = p1; wv[1] = v1; }
        *(f32x2*)(Out + (size_t)row * 2048 + col) = wv;
      }
    }
  }
}

// ---------------------------------------------------------------------------
// Fallback kernel 1: fused QKV with in-kernel pack; Q epilogue-scaled by SCQ;
// V out transposed [B,H,D,T].
// ---------------------------------------------------------------------------
__global__ __launch_bounds__(256) void qkv_gemm(
    const float* __restrict__ A0, const float* __restrict__ A1, const float* __restrict__ A2,
    const float* __restrict__ W0, const float* __restrict__ W1, const float* __restrict__ W2,
    unsigned short* __restrict__ O0, unsigned short* __restrict__ O1, unsigned short* __restrict__ O2)
{
  __shared__ unsigned short As[128 * 32];
  __shared__ unsigned short Bs[128 * 32];
  const int z = blockIdx.z;
  const float* A = z == 0 ? A0 : (z == 1 ? A1 : A2);
  const float* W = z == 0 ? W0 : (z == 1 ? W1 : W2);
  unsigned short* O = z == 0 ? O0 : (z == 1 ? O1 : O2);

  const int tid = threadIdx.x;
  const int lane = tid & 63;
  const int wave = tid >> 6;
  const int wm = wave >> 1, wn = wave & 1;
  const int bm = blockIdx.x >> 4, bn = blockIdx.x & 15;

  const int srow = tid >> 1;
  const int shalf = tid & 1;
  const float* Ap = A + (size_t)(bm * 128 + srow) * 2048 + shalf * 16;
  const float* Wp = W + (size_t)(bn * 128 + srow) * 2048 + shalf * 16;
  const int ssw = (srow >> 1) & 3;
  const int aoff0 = srow * 32 + (((shalf * 2 + 0) ^ ssw) << 3);
  const int aoff1 = srow * 32 + (((shalf * 2 + 1) ^ ssw) << 3);

  const int frow = lane & 15;
  const int fk = lane >> 4;

  f32x4 acc[4][4];
#pragma unroll
  for (int m = 0; m < 4; m++)
#pragma unroll
    for (int n = 0; n < 4; n++) acc[m][n] = (f32x4)(0.0f);

  for (int kk = 0; kk < 2048; kk += 32) {
    f32x4 a0 = *(const f32x4*)(Ap + kk);
    f32x4 a1 = *(const f32x4*)(Ap + kk + 4);
    f32x4 a2 = *(const f32x4*)(Ap + kk + 8);
    f32x4 a3 = *(const f32x4*)(Ap + kk + 12);
    f32x4 b0 = *(const f32x4*)(Wp + kk);
    f32x4 b1 = *(const f32x4*)(Wp + kk + 4);
    f32x4 b2 = *(const f32x4*)(Wp + kk + 8);
    f32x4 b3 = *(const f32x4*)(Wp + kk + 12);
    __syncthreads();
    *(u32x4*)(As + aoff0) = pack8(a0, a1);
    *(u32x4*)(As + aoff1) = pack8(a2, a3);
    *(u32x4*)(Bs + aoff0) = pack8(b0, b1);
    *(u32x4*)(Bs + aoff1) = pack8(b2, b3);
    __syncthreads();
    bf16x8 af[4], bfr[4];
#pragma unroll
    for (int m = 0; m < 4; m++) {
      int r = wm * 64 + m * 16 + frow;
      af[m] = *(const bf16x8*)(As + r * 32 + ((fk ^ ((r >> 1) & 3)) << 3));
    }
#pragma unroll
    for (int n = 0; n < 4; n++) {
      int r = wn * 64 + n * 16 + frow;
      bfr[n] = *(const bf16x8*)(Bs + r * 32 + ((fk ^ ((r >> 1) & 3)) << 3));
    }
#pragma unroll
    for (int m = 0; m < 4; m++)
#pragma unroll
      for (int n = 0; n < 4; n++)
        acc[m][n] = __builtin_amdgcn_mfma_f32_16x16x32_bf16(af[m], bfr[n], acc[m][n], 0, 0, 0);
  }

  if (z == 2) {
#pragma unroll
    for (int m = 0; m < 4; m++) {
      int rowg = bm * 128 + wm * 64 + m * 16 + (lane >> 4) * 4;
      int bb = rowg >> 11, t0 = rowg & 2047;
#pragma unroll
      for (int n = 0; n < 4; n++) {
        int col = bn * 128 + wn * 64 + n * 16 + (lane & 15);
        int hh = col >> 7, dd = col & 127;
        u32x2 wv;
        wv[0] = pack2(acc[m][n][0], acc[m][n][1]);
        wv[1] = pack2(acc[m][n][2], acc[m][n][3]);
        *(u32x2*)(O + (((size_t)(bb * 16 + hh) * 128 + dd) << 11) + t0) = wv;
      }
    }
    return;
  }

  const float scl = (z == 0) ? SCQ : 1.0f;
  const bool evenlane = (lane & 1) == 0;
#pragma unroll
  for (int m = 0; m < 4; m++) {
    int rowg = bm * 128 + wm * 64 + m * 16 + (lane >> 4) * 4;
#pragma unroll
    for (int n = 0; n < 4; n += 2) {
#pragma unroll
      for (int j = 0; j < 4; j++) {
        float v0 = acc[m][n][j] * scl, v1 = acc[m][n + 1][j] * scl;
        float p0 = __shfl_xor(v0, 1);
        float p1 = __shfl_xor(v1, 1);
        int row = rowg + j;
        int b = row >> 11, t = row & 2047;
        int colbase = bn * 128 + wn * 64;
        int col = evenlane ? (colbase + n * 16 + (lane & 15))
                           : (colbase + (n + 1) * 16 + (lane & 15) - 1);
        unsigned int wv = evenlane ? pack2(v0, p0) : pack2(p1, v1);
        int h = col >> 7, d = col & 127;
        *(unsigned int*)(O + (((size_t)(b * 16 + h) * 2048 + t) << 7) + d) = wv;
      }
    }
  }
}

// ---------------------------------------------------------------------------
// Kernel 2: flash attention v5. Log2-space softmax (Q pre-scaled), local-max
// defer check, per-lane partial l (epilogue reduce), zero-literal S init.
// ---------------------------------------------------------------------------
__global__ __launch_bounds__(256, 2) void attn(
    const unsigned short* __restrict__ Qw, const unsigned short* __restrict__ Kw,
    const unsigned short* __restrict__ VwT, unsigned short* __restrict__ attout)
{
  __shared__ unsigned short Ks[2][64 * 128];   // [key][d], slot swizzle s^(row&15)
  __shared__ unsigned short Vs[2][128 * 64];   // V^T [d][key], slot swizzle s^(row&7)
  __shared__ unsigned short Ps[128 * 64];      // P [q][key], slot swizzle s^(row&7)

  const int bid = blockIdx.x;
  const int work = ((bid & 7) << 7) | (bid >> 3);
  const int bh = work >> 4;
  const int qtile = work & 15;
  const int b = bh >> 4, h = bh & 15;
  const unsigned short* Qbase = Qw + (size_t)bh * 2048 * 128 + qtile * 128 * 128;
  const unsigned short* Kbase = Kw + (size_t)bh * 2048 * 128;
  const unsigned short* VbaseT = VwT + (size_t)bh * 2048 * 128;  // [d][t]
  const int tid = threadIdx.x, lane = tid & 63, w = tid >> 6;
  const int frow = lane & 15, fk = lane >> 4;

  bf16x8 qf[2][4];
#pragma unroll
  for (int m = 0; m < 2; m++)
#pragma unroll
    for (int ks = 0; ks < 4; ks++)
      qf[m][ks] = *(const bf16x8*)(Qbase + (size_t)(w * 32 + m * 16 + frow) * 128 + ks * 32 + fk * 8);

  const int krow_i = lane >> 4;              // K: row-in-issue
  const int kslot = lane & 15;
  const int vrow_i = lane >> 3;              // V: row-in-issue (8 rows/issue)
  const int vslot = (lane & 7) ^ vrow_i;     // pre-swizzled V chunk

  f32x4 o[2][8];
#pragma unroll
  for (int m = 0; m < 2; m++)
#pragma unroll
    for (int n = 0; n < 8; n++) o[m][n] = (f32x4)(0.0f);
  float m_r[2][4], l_p[2][4];                // l_p = per-lane partial sum
#pragma unroll
  for (int m = 0; m < 2; m++)
#pragma unroll
    for (int j = 0; j < 4; j++) { m_r[m][j] = -INFINITY; l_p[m][j] = 0.f; }
  const float THRL = 11.5f;                  // defer threshold, log2-space

  // ---- prologue: stage tile 0
  {
#pragma unroll
    for (int i = 0; i < 4; i++) {
      int row = w * 16 + i * 4 + krow_i;
      gload16(Kbase + (size_t)row * 128 + ((kslot ^ (row & 15)) << 3),
              &Ks[0][(w * 16 + i * 4) * 128]);
    }
#pragma unroll
    for (int i = 0; i < 4; i++) {
      int d = w * 32 + i * 8 + vrow_i;
      gload16(VbaseT + (size_t)d * 2048 + vslot * 8,
              &Vs[0][(w * 32 + i * 8) * 64]);
    }
  }

  for (int kt = 0; kt < 32; kt++) {
    const int cur = kt & 1;
    __syncthreads();   // buf[cur] staged; prior reads of buf[cur^1] done

    const bool have_next = (kt + 1) < 32;
    if (have_next) {
      const unsigned short* Kt = Kbase + (kt + 1) * 64 * 128;
#pragma unroll
      for (int i = 0; i < 4; i++) {
        int row = w * 16 + i * 4 + krow_i;
        gload16(Kt + (size_t)row * 128 + ((kslot ^ (row & 15)) << 3),
                &Ks[cur ^ 1][(w * 16 + i * 4) * 128]);
      }
#pragma unroll
      for (int i = 0; i < 4; i++) {
        int d = w * 32 + i * 8 + vrow_i;
        gload16(VbaseT + (size_t)d * 2048 + (kt + 1) * 64 + vslot * 8,
                &Vs[cur ^ 1][(w * 32 + i * 8) * 64]);
      }
    }

    // ---- S = Q K^T (log2-scaled; ks=0 uses literal-zero accumulator)
    f32x4 s[2][4];
    __builtin_amdgcn_s_setprio(1);
#pragma unroll
    for (int n = 0; n < 4; n++) {
      int brow = n * 16 + frow;
      bf16x8 bk = *(const bf16x8*)(&Ks[cur][0] + brow * 128 + ((fk ^ (brow & 15)) << 3));
#pragma unroll
      for (int m = 0; m < 2; m++)
        s[m][n] = __builtin_amdgcn_mfma_f32_16x16x32_bf16(qf[m][0], bk, (f32x4)(0.0f), 0, 0, 0);
    }
#pragma unroll
    for (int ks = 1; ks < 4; ks++) {
#pragma unroll
      for (int n = 0; n < 4; n++) {
        int brow = n * 16 + frow;
        bf16x8 bk = *(const bf16x8*)(&Ks[cur][0] + brow * 128 + (((ks * 4 + fk) ^ (brow & 15)) << 3));
#pragma unroll
        for (int m = 0; m < 2; m++)
          s[m][n] = __builtin_amdgcn_mfma_f32_16x16x32_bf16(qf[m][ks], bk, s[m][n], 0, 0, 0);
      }
    }
    __builtin_amdgcn_s_setprio(0);

    // ---- online softmax (log2-space) + P pack/write
#pragma unroll
    for (int m = 0; m < 2; m++) {
#pragma unroll
      for (int j = 0; j < 4; j++) {
        float mx = fmaxf(fmaxf(s[m][0][j], s[m][1][j]), fmaxf(s[m][2][j], s[m][3][j]));
        float mo = m_r[m][j];
        // local-max check: ballot ANDs across lanes, no cross-lane max needed
        if (!__all(mx - mo <= THRL)) {
          float mnew = fmaxf(mo, rowmax16(mx));
          float f = __builtin_amdgcn_exp2f(mo - mnew);
          m_r[m][j] = mnew;
          l_p[m][j] *= f;
#pragma unroll
          for (int n = 0; n < 8; n++) o[m][n][j] *= f;
        }
        float mm = m_r[m][j];
        float ps = 0.f;
#pragma unroll
        for (int n = 0; n < 4; n++) {
          float p = __builtin_amdgcn_exp2f(s[m][n][j] - mm);
          s[m][n][j] = p;
          ps += p;
        }
        l_p[m][j] += ps;

        // pack cols pairwise: partner via quad_perm [1,0,3,2]; even lanes store
        int row = w * 32 + m * 16 + (lane >> 4) * 4 + j;
        int swzp = row & 7;
        unsigned prv[4];
#pragma unroll
        for (int n = 0; n < 4; n++) {
          float p = s[m][n][j];
          float ph = dppf<0xB1>(p);
          unsigned pr;
          asm("v_cvt_pk_bf16_f32 %0, %1, %2" : "=v"(pr) : "v"(p), "v"(ph));
          prv[n] = pr;
        }
        if (!(lane & 1)) {
#pragma unroll
          for (int n = 0; n < 4; n++) {
            int col = frow + 16 * n;   // even
            *(unsigned*)((char*)Ps + row * 128 + (((col >> 3) ^ swzp) << 4) + (col & 7) * 2) = prv[n];
          }
        }
      }
    }

    // ---- O += P V
    __builtin_amdgcn_s_setprio(1);
#pragma unroll
    for (int ks = 0; ks < 2; ks++) {
      bf16x8 ap[2];
#pragma unroll
      for (int m = 0; m < 2; m++) {
        int arow = w * 32 + m * 16 + frow;
        ap[m] = *(const bf16x8*)((char*)Ps + arow * 128 + (((ks * 4 + fk) ^ (arow & 7)) << 4));
      }
#pragma unroll
      for (int n = 0; n < 8; n++) {
        int vrow = n * 16 + frow;
        bf16x8 bv = *(const bf16x8*)((char*)&Vs[cur][0] + vrow * 128 + (((ks * 4 + fk) ^ (vrow & 7)) << 4));
#pragma unroll
        for (int m = 0; m < 2; m++)
          o[m][n] = __builtin_amdgcn_mfma_f32_16x16x32_bf16(ap[m], bv, o[m][n], 0, 0, 0);
      }
    }
    __builtin_amdgcn_s_setprio(0);
  }

  // ---- epilogue: cross-lane l reduce happens once here
  const bool evenlane = (lane & 1) == 0;
#pragma unroll
  for (int m = 0; m < 2; m++) {
    float inv[4];
#pragma unroll
    for (int j = 0; j < 4; j++) inv[j] = 1.0f / rowsum16(l_p[m][j]);
#pragma unroll
    for (int n = 0; n < 8; n += 2) {
#pragma unroll
      for (int j = 0; j < 4; j++) {
        float v0 = o[m][n][j] * inv[j], v1 = o[m][n + 1][j] * inv[j];
        float p0 = __shfl_xor(v0, 1);
        float p1 = __shfl_xor(v1, 1);
        int tq = qtile * 128 + w * 32 + m * 16 + (lane >> 4) * 4 + j;
        int col = evenlane ? (n * 16 + (lane & 15)) : ((n + 1) * 16 + (lane & 15) - 1);
        unsigned int wv = evenlane ? pack2(v0, p0) : pack2(p1, v1);
        *(unsigned int*)(attout + (size_t)(b * 2048 + tq) * 2048 + h * 128 + col) = wv;
      }
    }
  }
}

// ---------------------------------------------------------------------------
// Fallback kernel 3 (round-1): output projection with in-kernel fp32 W pack.
// ---------------------------------------------------------------------------
__global__ __launch_bounds__(256) void out_gemm(
    const unsigned short* __restrict__ Ab, const float* __restrict__ W,
    const float* __restrict__ bias, float* __restrict__ Out)
{
  __shared__ unsigned short As[128 * 32];
  __shared__ unsigned short Bs[128 * 32];

  const int tid = threadIdx.x;
  const int lane = tid & 63;
  const int wave = tid >> 6;
  const int wm = wave >> 1, wn = wave & 1;
  const int bm = blockIdx.x >> 4, bn = blockIdx.x & 15;

  const int srow = tid >> 1;
  const int shalf = tid & 1;
  const unsigned short* Ap = Ab + (size_t)(bm * 128 + srow) * 2048 + shalf * 16;
  const float* Wp = W + (size_t)(bn * 128 + srow) * 2048 + shalf * 16;
  const int ssw = (srow >> 1) & 3;
  const int aoff0 = srow * 32 + (((shalf * 2 + 0) ^ ssw) << 3);
  const int aoff1 = srow * 32 + (((shalf * 2 + 1) ^ ssw) << 3);

  const int frow = lane & 15;
  const int fk = lane >> 4;

  f32x4 acc[4][4];
#pragma unroll
  for (int m = 0; m < 4; m++)
#pragma unroll
    for (int n = 0; n < 4; n++) acc[m][n] = (f32x4)(0.0f);

  for (int kk = 0; kk < 2048; kk += 32) {
    u32x4 a0 = *(const u32x4*)(Ap + kk);
    u32x4 a1 = *(const u32x4*)(Ap + kk + 8);
    f32x4 b0 = *(const f32x4*)(Wp + kk);
    f32x4 b1 = *(const f32x4*)(Wp + kk + 4);
    f32x4 b2 = *(const f32x4*)(Wp + kk + 8);
    f32x4 b3 = *(const f32x4*)(Wp + kk + 12);
    __syncthreads();
    *(u32x4*)(As + aoff0) = a0;
    *(u32x4*)(As + aoff1) = a1;
    *(u32x4*)(Bs + aoff0) = pack8(b0, b1);
    *(u32x4*)(Bs + aoff1) = pack8(b2, b3);
    __syncthreads();
    bf16x8 af[4], bfr[4];
#pragma unroll
    for (int m = 0; m < 4; m++) {
      int r = wm * 64 + m * 16 + frow;
      af[m] = *(const bf16x8*)(As + r * 32 + ((fk ^ ((r >> 1) & 3)) << 3));
    }
#pragma unroll
    for (int n = 0; n < 4; n++) {
      int r = wn * 64 + n * 16 + frow;
      bfr[n] = *(const bf16x8*)(Bs + r * 32 + ((fk ^ ((r >> 1) & 3)) << 3));
    }
#pragma unroll
    for (int m = 0; m < 4; m++)
#pragma unroll
      for (int n = 0; n < 4; n++)
        acc[m][n] = __builtin_amdgcn_mfma_f32_16x16x32_bf16(af[m], bfr[n], acc[m][n], 0, 0, 0);
  }

  float bv[4];
#pragma unroll
  for (int n = 0; n < 4; n++) bv[n] = bias[bn * 128 + wn * 64 + n * 16 + (lane & 15)];
  const bool evenlane = (lane & 1) == 0;
#pragma unroll
  for (int m = 0; m < 4; m++) {
    int rowg = bm * 128 + wm * 64 + m * 16 + (lane >> 4) * 4;
#pragma unroll
    for (int n = 0; n < 4; n += 2) {
#pragma unroll
      for (int j = 0; j < 4; j++) {
        float v0 = acc[m][n][j] + bv[n];
        float v1 = acc[m][n + 1][j] + bv[n + 1];
        float p0 = __shfl_xor(v0, 1);
        float p1 = __shfl_xor(v1, 1);
        int row = rowg + j;
        int colbase = bn * 128 + wn * 64;
        int col = evenlane ? (colbase + n * 16 + (lane & 15))
                           : (colbase + (n + 1) * 16 + (lane & 15) - 1);
        f32x2 wv;
        if (evenlane) { wv[0] = v0; wv[1] = p0; }
        else          { wv[0] = p1; wv[1] = v1; }
        *(f32x2*)(Out + (size_t)row * 2048 + col) = wv;
      }
    }
  }
}

// ---------------------------------------------------------------------------
extern "C" void kernel_launch(void* const* d_in, const int* in_sizes, int n_in,
                              void* d_out, int out_size, void* d_ws, size_t ws_size,
                              hipStream_t stream)
{
  // setup_inputs order: k, q, v, Wk, Wq, Wv, Wo, bo
  const float* k  = (const float*)d_in[0];
  const float* q  = (const float*)d_in[1];
  const float* v  = (const float*)d_in[2];
  const float* Wk = (const float*)d_in[3];
  const float* Wq = (const float*)d_in[4];
  const float* Wv = (const float*)d_in[5];
  const float* Wo = (const float*)d_in[6];
  const float* bo = (const float*)d_in[7];
  float* out = (float*)d_out;

  const size_t HSZ = (size_t)4 * 16 * 2048 * 128;   // 32 MiB (bf16 elems)

  if (ws_size >= (size_t)224 << 20) {
    unsigned short* Abf = (unsigned short*)d_ws;
    unsigned short* Wbf = Abf + 3 * HSZ;
    unsigned short* Qw  = Wbf + 4 * 4194304;
    unsigned short* Kw  = Qw + HSZ;
    unsigned short* Vw  = Kw + HSZ;       // V stored TRANSPOSED [b,h,d,t]
    unsigned short* Aw  = Abf;

    convA<<<dim3(8192, 1, 3), 256, 0, stream>>>(q, k, v, Abf);
    convW<<<dim3(2048, 1, 4), 256, 0, stream>>>(Wq, Wk, Wv, Wo, Wbf);
    qkv_gemm_bf<<<dim3(256, 1, 3), 512, 0, stream>>>(Abf, Wbf, Qw, Kw, Vw);
    attn<<<dim3(1024), 256, 0, stream>>>(Qw, Kw, Vw, Aw);
    out_gemm_bf<<<dim3(256), 512, 0, stream>>>(Aw, Wbf + 3 * 4194304, bo, out);
  } else {
    unsigned short* Qw = (unsigned short*)d_ws;
    unsigned short* Kw = Qw + HSZ;
    unsigned short* Vw = Kw + HSZ;        // transposed V here too
    unsigned short* Aw = Vw + HSZ;
    qkv_gemm<<<dim3(1024, 1, 3), 256, 0, stream>>>(q, k, v, Wq, Wk, Wv, Qw, Kw, Vw);
    attn<<<dim3(1024), 256, 0, stream>>>(Qw, Kw, Vw, Aw);
    out_gemm<<<dim3(1024), 256, 0, stream>>>(Aw, Wo, bo, out);
  }
}